// Round 12
// baseline (269.832 us; speedup 1.0000x reference)
//
#include <hip/hip_runtime.h>
#include <cmath>

#define B_DIM 4096
#define O_DIM 2048
#define I_DIM 2048

typedef _Float16 f16x8 __attribute__((ext_vector_type(8)));
typedef float f32x4 __attribute__((ext_vector_type(4)));
typedef unsigned int uint;
typedef unsigned short ushort;

#define WSCALE   64.0f
#define WDESCALE 0.015625f
#define MBYTE    ((size_t)1024 * 1024)

// ws layout:
// L1h 0..16M | L1l 16..32M | Mh 32..40M | Wsh 40..48M | Wsl 48..56M
// tier A adds: Xh 56..72M | Xl 72..88M ; flag at 88M (A) or 56M (B)

// Swizzled LDS tile: [rows][16 dwords]; 16B slot s: phys = s ^ ((r>>1)&3).
__device__ __forceinline__ int TP(int r, int s) {
    return r * 16 + (((s ^ ((r >> 1) & 3))) << 2);
}

__device__ __forceinline__ float h2f(ushort u) {
    _Float16 h = __builtin_bit_cast(_Float16, u);
    return (float)h;
}

__device__ __forceinline__ void gload16(const uint* src, uint* lds) {
    __builtin_amdgcn_global_load_lds(
        (const __attribute__((address_space(1))) void*)src,
        (__attribute__((address_space(3))) void*)lds, 16, 0, 0);
}

__device__ __forceinline__ void split8(const float4 a, const float4 b,
                                       uint4& hi, uint4& lo) {
    auto h0 = __builtin_amdgcn_cvt_pkrtz(a.x, a.y);
    auto h1 = __builtin_amdgcn_cvt_pkrtz(a.z, a.w);
    auto h2 = __builtin_amdgcn_cvt_pkrtz(b.x, b.y);
    auto h3 = __builtin_amdgcn_cvt_pkrtz(b.z, b.w);
    auto l0 = __builtin_amdgcn_cvt_pkrtz(a.x - (float)h0[0], a.y - (float)h0[1]);
    auto l1 = __builtin_amdgcn_cvt_pkrtz(a.z - (float)h1[0], a.w - (float)h1[1]);
    auto l2 = __builtin_amdgcn_cvt_pkrtz(b.x - (float)h2[0], b.y - (float)h2[1]);
    auto l3 = __builtin_amdgcn_cvt_pkrtz(b.z - (float)h3[0], b.w - (float)h3[1]);
    hi.x = __builtin_bit_cast(uint, h0); hi.y = __builtin_bit_cast(uint, h1);
    hi.z = __builtin_bit_cast(uint, h2); hi.w = __builtin_bit_cast(uint, h3);
    lo.x = __builtin_bit_cast(uint, l0); lo.y = __builtin_bit_cast(uint, l1);
    lo.z = __builtin_bit_cast(uint, l2); lo.w = __builtin_bit_cast(uint, l3);
}

__device__ __forceinline__ float4 add4(const float4 a, const float4 b) {
    return make_float4(a.x + b.x, a.y + b.y, a.z + b.z, a.w + b.w);
}
__device__ __forceinline__ float4 mul64(const float4 a) {
    return make_float4(a.x * WSCALE, a.y * WSCALE, a.z * WSCALE, a.w * WSCALE);
}
__device__ __forceinline__ void unpack8(const uint4 h, const uint4 l,
                                        float4& f0, float4& f1) {
    f0.x = h2f((ushort)(h.x & 0xffff)) + h2f((ushort)(l.x & 0xffff));
    f0.y = h2f((ushort)(h.x >> 16))    + h2f((ushort)(l.x >> 16));
    f0.z = h2f((ushort)(h.y & 0xffff)) + h2f((ushort)(l.y & 0xffff));
    f0.w = h2f((ushort)(h.y >> 16))    + h2f((ushort)(l.y >> 16));
    f1.x = h2f((ushort)(h.z & 0xffff)) + h2f((ushort)(l.z & 0xffff));
    f1.y = h2f((ushort)(h.z >> 16))    + h2f((ushort)(l.z >> 16));
    f1.z = h2f((ushort)(h.w & 0xffff)) + h2f((ushort)(l.w & 0xffff));
    f1.w = h2f((ushort)(h.w >> 16))    + h2f((ushort)(l.w >> 16));
}

// ===========================================================================
// prep: fused zcheck + split(x) + split(Wsyn*64) + split_hi(WTm*64)
// ===========================================================================
__global__ __launch_bounds__(256)
void prep(const float* __restrict__ x, const float* __restrict__ Wsyn,
          const float* __restrict__ WTm,
          const float* __restrict__ u, const float* __restrict__ b,
          const float* __restrict__ s,
          ushort* __restrict__ Xh, ushort* __restrict__ Xl,
          ushort* __restrict__ Wsh, ushort* __restrict__ Wsl,
          ushort* __restrict__ Mhp, uint* __restrict__ flag, int doX) {
    const uint NX = (uint)((size_t)B_DIM * I_DIM / 8);
    const uint NW = (uint)((size_t)O_DIM * I_DIM / 8);
    const uint NZ = (uint)((size_t)B_DIM * O_DIM / 8);
    const uint nx = doX ? NX : 0;
    const uint total = nx + 2 * NW + NZ;
    const uint stride = gridDim.x * blockDim.x;
    bool nz = false;
    for (uint t = blockIdx.x * blockDim.x + threadIdx.x; t < total; t += stride) {
        if (t < nx) {
            const size_t i = (size_t)t * 8;
            uint4 h, l;
            split8(*(const float4*)(x + i), *(const float4*)(x + i + 4), h, l);
            *(uint4*)(Xh + i) = h; *(uint4*)(Xl + i) = l;
        } else if (t < nx + NW) {
            const size_t i = (size_t)(t - nx) * 8;
            uint4 h, l;
            split8(mul64(*(const float4*)(Wsyn + i)),
                   mul64(*(const float4*)(Wsyn + i + 4)), h, l);
            *(uint4*)(Wsh + i) = h; *(uint4*)(Wsl + i) = l;
        } else if (t < nx + 2 * NW) {
            const size_t i = (size_t)(t - nx - NW) * 8;
            const float4 a = mul64(*(const float4*)(WTm + i));
            const float4 c = mul64(*(const float4*)(WTm + i + 4));
            auto h0 = __builtin_amdgcn_cvt_pkrtz(a.x, a.y);
            auto h1 = __builtin_amdgcn_cvt_pkrtz(a.z, a.w);
            auto h2 = __builtin_amdgcn_cvt_pkrtz(c.x, c.y);
            auto h3 = __builtin_amdgcn_cvt_pkrtz(c.z, c.w);
            uint4 h;
            h.x = __builtin_bit_cast(uint, h0); h.y = __builtin_bit_cast(uint, h1);
            h.z = __builtin_bit_cast(uint, h2); h.w = __builtin_bit_cast(uint, h3);
            *(uint4*)(Mhp + i) = h;
        } else {
            const size_t i = (size_t)(t - nx - 2 * NW) * 8;
            const float4 a0 = *(const float4*)(u + i), a1 = *(const float4*)(u + i + 4);
            const float4 b0 = *(const float4*)(b + i), b1 = *(const float4*)(b + i + 4);
            const float4 c0 = *(const float4*)(s + i), c1 = *(const float4*)(s + i + 4);
            nz |= (a0.x != 0.f) | (a0.y != 0.f) | (a0.z != 0.f) | (a0.w != 0.f);
            nz |= (a1.x != 0.f) | (a1.y != 0.f) | (a1.z != 0.f) | (a1.w != 0.f);
            nz |= (b0.x != 0.f) | (b0.y != 0.f) | (b0.z != 0.f) | (b0.w != 0.f);
            nz |= (b1.x != 0.f) | (b1.y != 0.f) | (b1.z != 0.f) | (b1.w != 0.f);
            nz |= (c0.x != 0.f) | (c0.y != 0.f) | (c0.z != 0.f) | (c0.w != 0.f);
            nz |= (c1.x != 0.f) | (c1.y != 0.f) | (c1.z != 0.f) | (c1.w != 0.f);
        }
    }
    if (nz) atomicOr(flag, 1u);
}

// ===========================================================================
// GEMM1 tier A: 128x128 tile, 512 thr (8 waves, 64x32), 3-deep LDS pipeline
// with counted vmcnt (validated round 11, 966 TF).
// ===========================================================================
__global__ __launch_bounds__(512)
void gemm1_c(const ushort* __restrict__ Xh, const ushort* __restrict__ Xl,
             const ushort* __restrict__ Wh, const ushort* __restrict__ Wl,
             const float* __restrict__ bias,
             ushort* __restrict__ Lh, ushort* __restrict__ Ll) {
    __shared__ uint S[3][8192];   // 96 KB

    const int tid = threadIdx.x;
    const int lane = tid & 63;
    const int wid = tid >> 6;
    const int wm = wid >> 2;
    const int wn = wid & 3;

    int sid = blockIdx.x;
    sid = (sid & 7) * 64 + (sid >> 3);
    const int bx = sid & 15, by = sid >> 4;
    const int row0 = by * 128, col0 = bx * 128;

    const uint* src[4];
    int dbase[4];
#pragma unroll
    for (int i = 0; i < 4; i++) {
        const int ch = wid * 4 + i;
        const int p = ch >> 3, c = ch & 7;
        const int g = c * 64 + lane;
        const int r = g >> 2, q = (g & 3) ^ ((r >> 1) & 3);
        dbase[i] = p * 2048 + c * 256;
        const ushort* plane = (p == 0) ? Xh : (p == 1) ? Xl : (p == 2) ? Wh : Wl;
        const int grow = (p < 2) ? (row0 + r) : (col0 + r);
        src[i] = (const uint*)plane + (size_t)grow * 1024 + q * 4;
    }

    f32x4 acc[4][2];
#pragma unroll
    for (int i = 0; i < 4; i++)
#pragma unroll
        for (int j = 0; j < 2; j++)
#pragma unroll
            for (int r = 0; r < 4; r++) acc[i][j][r] = 0.0f;

    const int fr = lane & 15;
    const int sl = lane >> 4;
    const int NT = I_DIM / 32;

#pragma unroll
    for (int i = 0; i < 4; i++) gload16(src[i], &S[0][dbase[i]]);
#pragma unroll
    for (int i = 0; i < 4; i++) gload16(src[i] + 16, &S[1][dbase[i]]);

    for (int t = 0; t < NT; t++) {
        if (t + 1 < NT) {
            asm volatile("s_waitcnt vmcnt(4)" ::: "memory");
        } else {
            asm volatile("s_waitcnt vmcnt(0)" ::: "memory");
        }
        asm volatile("s_barrier" ::: "memory");
        if (t + 2 < NT) {
            const int ko = (t + 2) * 16;
            uint* Sd = &S[(t + 2) % 3][0];
#pragma unroll
            for (int i = 0; i < 4; i++) gload16(src[i] + ko, &Sd[dbase[i]]);
        }
        const uint* Sc = &S[t % 3][0];
        f16x8 ah_[4], al_[4], bh_[2], bl_[2];
#pragma unroll
        for (int mi = 0; mi < 4; mi++) {
            const int r = wm * 64 + mi * 16 + fr;
            ah_[mi] = *(const f16x8*)&Sc[TP(r, sl)];
            al_[mi] = *(const f16x8*)&Sc[2048 + TP(r, sl)];
        }
#pragma unroll
        for (int ni = 0; ni < 2; ni++) {
            const int r = wn * 32 + ni * 16 + fr;
            bh_[ni] = *(const f16x8*)&Sc[4096 + TP(r, sl)];
            bl_[ni] = *(const f16x8*)&Sc[6144 + TP(r, sl)];
        }
#pragma unroll
        for (int mi = 0; mi < 4; mi++)
#pragma unroll
            for (int ni = 0; ni < 2; ni++) {
                acc[mi][ni] = __builtin_amdgcn_mfma_f32_16x16x32_f16(ah_[mi], bh_[ni], acc[mi][ni], 0, 0, 0);
                acc[mi][ni] = __builtin_amdgcn_mfma_f32_16x16x32_f16(ah_[mi], bl_[ni], acc[mi][ni], 0, 0, 0);
                acc[mi][ni] = __builtin_amdgcn_mfma_f32_16x16x32_f16(al_[mi], bh_[ni], acc[mi][ni], 0, 0, 0);
            }
    }

#pragma unroll
    for (int ni = 0; ni < 2; ni++) {
        const int col = col0 + wn * 32 + ni * 16 + fr;
        const float bv = bias[col];
#pragma unroll
        for (int mi = 0; mi < 4; mi++) {
            const int rb = row0 + wm * 64 + mi * 16 + ((lane >> 4) << 2);
            float e[4];
#pragma unroll
            for (int r = 0; r < 4; r++) e[r] = acc[mi][ni][r] * WDESCALE + bv;
            auto hp0 = __builtin_amdgcn_cvt_pkrtz(e[0], e[1]);
            auto hp1 = __builtin_amdgcn_cvt_pkrtz(e[2], e[3]);
            auto lp0 = __builtin_amdgcn_cvt_pkrtz(e[0] - (float)hp0[0], e[1] - (float)hp0[1]);
            auto lp1 = __builtin_amdgcn_cvt_pkrtz(e[2] - (float)hp1[0], e[3] - (float)hp1[1]);
            const uint uh0 = __builtin_bit_cast(uint, hp0);
            const uint uh1 = __builtin_bit_cast(uint, hp1);
            const uint ul0 = __builtin_bit_cast(uint, lp0);
            const uint ul1 = __builtin_bit_cast(uint, lp1);
            Lh[(size_t)(rb + 0) * O_DIM + col] = (ushort)(uh0 & 0xffff);
            Lh[(size_t)(rb + 1) * O_DIM + col] = (ushort)(uh0 >> 16);
            Lh[(size_t)(rb + 2) * O_DIM + col] = (ushort)(uh1 & 0xffff);
            Lh[(size_t)(rb + 3) * O_DIM + col] = (ushort)(uh1 >> 16);
            Ll[(size_t)(rb + 0) * O_DIM + col] = (ushort)(ul0 & 0xffff);
            Ll[(size_t)(rb + 1) * O_DIM + col] = (ushort)(ul0 >> 16);
            Ll[(size_t)(rb + 2) * O_DIM + col] = (ushort)(ul1 & 0xffff);
            Ll[(size_t)(rb + 3) * O_DIM + col] = (ushort)(ul1 >> 16);
        }
    }
}

// ===========================================================================
// GEMM1 tier B: Wsyn pre-split (gload16), X split in-loop (unchanged).
// ===========================================================================
__global__ __launch_bounds__(256)
void gemm1_b(const float* __restrict__ X,
             const ushort* __restrict__ Wh, const ushort* __restrict__ Wl,
             const float* __restrict__ bias,
             ushort* __restrict__ Lh, ushort* __restrict__ Ll) {
    __shared__ uint S[8192];

    const int tid = threadIdx.x;
    const int lane = tid & 63;
    const int wid = tid >> 6;
    const int wm = wid >> 1, wn = wid & 1;

    int sid = blockIdx.x;
    sid = (sid & 7) * 64 + (sid >> 3);
    const int bx = sid & 15, by = sid >> 4;
    const int row0 = by * 128, col0 = bx * 128;

    const int sr = tid >> 1;
    const int kh = (tid & 1) * 16;
    const int s0 = (tid & 1) * 2;
    const float* pA = X + (size_t)(row0 + sr) * I_DIM + kh;

    int r0, q0, r1, q1;
    {
        const int g0 = (wid * 2 + 0) * 64 + lane;
        const int g1 = (wid * 2 + 1) * 64 + lane;
        r0 = g0 >> 2; q0 = (g0 & 3) ^ ((r0 >> 1) & 3);
        r1 = g1 >> 2; q1 = (g1 & 3) ^ ((r1 >> 1) & 3);
    }
    const uint* sWh0 = (const uint*)Wh + (size_t)(col0 + r0) * 1024 + q0 * 4;
    const uint* sWh1 = (const uint*)Wh + (size_t)(col0 + r1) * 1024 + q1 * 4;
    const uint* sWl0 = (const uint*)Wl + (size_t)(col0 + r0) * 1024 + q0 * 4;
    const uint* sWl1 = (const uint*)Wl + (size_t)(col0 + r1) * 1024 + q1 * 4;
    const int c0 = (wid * 2 + 0) << 8;
    const int c1 = (wid * 2 + 1) << 8;

    f32x4 acc[4][4];
#pragma unroll
    for (int i = 0; i < 4; i++)
#pragma unroll
        for (int j = 0; j < 4; j++)
#pragma unroll
            for (int r = 0; r < 4; r++) acc[i][j][r] = 0.0f;

    const int fr = lane & 15;
    const int sl = lane >> 4;
    const int NT = I_DIM / 32;

    float4 a0 = *(const float4*)(pA + 0), a1 = *(const float4*)(pA + 4);
    float4 a2 = *(const float4*)(pA + 8), a3 = *(const float4*)(pA + 12);
    uint4 xh0, xl0, xh1, xl1;
    split8(a0, a1, xh0, xl0);
    split8(a2, a3, xh1, xl1);

    for (int t = 0; t < NT; t++) {
        __syncthreads();
        *(uint4*)&S[TP(sr, s0)] = xh0;         *(uint4*)&S[TP(sr, s0 + 1)] = xh1;
        *(uint4*)&S[2048 + TP(sr, s0)] = xl0;  *(uint4*)&S[2048 + TP(sr, s0 + 1)] = xl1;
        const int ko = t * 16;
        gload16(sWh0 + ko, &S[4096 + c0]);  gload16(sWh1 + ko, &S[4096 + c1]);
        gload16(sWl0 + ko, &S[6144 + c0]);  gload16(sWl1 + ko, &S[6144 + c1]);
        __syncthreads();
        if (t + 1 < NT) {
            const float* nA = pA + (t + 1) * 32;
            a0 = *(const float4*)(nA + 0); a1 = *(const float4*)(nA + 4);
            a2 = *(const float4*)(nA + 8); a3 = *(const float4*)(nA + 12);
        }
        f16x8 ah_[4], al_[4], bh_[4], bl_[4];
#pragma unroll
        for (int mi = 0; mi < 4; mi++) {
            const int r = wm * 64 + mi * 16 + fr;
            ah_[mi] = *(const f16x8*)&S[TP(r, sl)];
            al_[mi] = *(const f16x8*)&S[2048 + TP(r, sl)];
        }
#pragma unroll
        for (int ni = 0; ni < 4; ni++) {
            const int r = wn * 64 + ni * 16 + fr;
            bh_[ni] = *(const f16x8*)&S[4096 + TP(r, sl)];
            bl_[ni] = *(const f16x8*)&S[6144 + TP(r, sl)];
        }
#pragma unroll
        for (int mi = 0; mi < 4; mi++)
#pragma unroll
            for (int ni = 0; ni < 4; ni++) {
                acc[mi][ni] = __builtin_amdgcn_mfma_f32_16x16x32_f16(ah_[mi], bh_[ni], acc[mi][ni], 0, 0, 0);
                acc[mi][ni] = __builtin_amdgcn_mfma_f32_16x16x32_f16(ah_[mi], bl_[ni], acc[mi][ni], 0, 0, 0);
                acc[mi][ni] = __builtin_amdgcn_mfma_f32_16x16x32_f16(al_[mi], bh_[ni], acc[mi][ni], 0, 0, 0);
            }
        if (t + 1 < NT) {
            split8(a0, a1, xh0, xl0);
            split8(a2, a3, xh1, xl1);
        }
    }

    const int fr2 = lane & 15;
#pragma unroll
    for (int ni = 0; ni < 4; ni++) {
        const int col = col0 + wn * 64 + ni * 16 + fr2;
        const float bv = bias[col];
#pragma unroll
        for (int mi = 0; mi < 4; mi++) {
            const int rb = row0 + wm * 64 + mi * 16 + ((lane >> 4) << 2);
            float e[4];
#pragma unroll
            for (int r = 0; r < 4; r++) e[r] = acc[mi][ni][r] * WDESCALE + bv;
            auto hp0 = __builtin_amdgcn_cvt_pkrtz(e[0], e[1]);
            auto hp1 = __builtin_amdgcn_cvt_pkrtz(e[2], e[3]);
            auto lp0 = __builtin_amdgcn_cvt_pkrtz(e[0] - (float)hp0[0], e[1] - (float)hp0[1]);
            auto lp1 = __builtin_amdgcn_cvt_pkrtz(e[2] - (float)hp1[0], e[3] - (float)hp1[1]);
            const uint uh0 = __builtin_bit_cast(uint, hp0);
            const uint uh1 = __builtin_bit_cast(uint, hp1);
            const uint ul0 = __builtin_bit_cast(uint, lp0);
            const uint ul1 = __builtin_bit_cast(uint, lp1);
            Lh[(size_t)(rb + 0) * O_DIM + col] = (ushort)(uh0 & 0xffff);
            Lh[(size_t)(rb + 1) * O_DIM + col] = (ushort)(uh0 >> 16);
            Lh[(size_t)(rb + 2) * O_DIM + col] = (ushort)(uh1 & 0xffff);
            Lh[(size_t)(rb + 3) * O_DIM + col] = (ushort)(uh1 >> 16);
            Ll[(size_t)(rb + 0) * O_DIM + col] = (ushort)(ul0 & 0xffff);
            Ll[(size_t)(rb + 1) * O_DIM + col] = (ushort)(ul0 >> 16);
            Ll[(size_t)(rb + 2) * O_DIM + col] = (ushort)(ul1 & 0xffff);
            Ll[(size_t)(rb + 3) * O_DIM + col] = (ushort)(ul1 >> 16);
        }
    }
}

// ===========================================================================
// Stage-2 FAST: 128x64 tile, 4 waves, NOW 3-deep counted-vmcnt pipeline
// (gemm1_c's validated protocol; 3 gload16/thread/tile, wait vmcnt(3)).
// LDS 3 x 12KB = 36 KB -> 4 blocks/CU. Epilogue unchanged (LDS transpose).
// ===========================================================================
__global__ __launch_bounds__(256)
void stage2_fast(const ushort* __restrict__ Lhp, const ushort* __restrict__ Llp,
                 const ushort* __restrict__ Mhp,
                 const float* __restrict__ bTm, float* __restrict__ out,
                 const uint* __restrict__ flag,
                 uint* __restrict__ cnt, uint* __restrict__ list, uint cap) {
    if (*flag != 0) return;

    // per buf 3072 dwords: Lh tile [0,2048) (128x32 f16), Mh tile [2048,3072)
    __shared__ uint S[3][3072];   // 36 KB

    const int tid = threadIdx.x;
    const int lane = tid & 63;
    const int wid = tid >> 6;
    const int wm = wid >> 1, wn = wid & 1;

    int sid = blockIdx.x;
    sid = (sid & 7) * 128 + (sid >> 3);   // XCD swizzle (1024 % 8 == 0)
    const int bx = sid & 31, by = sid >> 5;
    const int row0 = by * 128, col0 = bx * 64;

    const uint* src[3];
    int base[3];
#pragma unroll
    for (int i = 0; i < 3; i++) {
        const int ch = wid * 3 + i;
        base[i] = ch << 8;
        if (ch < 8) {
            const int g = ch * 64 + lane;
            const int r = g >> 2, q = (g & 3) ^ ((r >> 1) & 3);
            src[i] = (const uint*)Lhp + (size_t)(row0 + r) * 1024 + q * 4;
        } else {
            const int g = (ch - 8) * 64 + lane;
            const int r = g >> 2, q = (g & 3) ^ ((r >> 1) & 3);
            src[i] = (const uint*)Mhp + (size_t)(col0 + r) * 1024 + q * 4;
        }
    }

    f32x4 acc[4][2];
#pragma unroll
    for (int i = 0; i < 4; i++)
#pragma unroll
        for (int j = 0; j < 2; j++)
#pragma unroll
            for (int r = 0; r < 4; r++) acc[i][j][r] = 0.0f;

    const int fr = lane & 15;
    const int sl = lane >> 4;
    const int NT = O_DIM / 32;

    // prologue: 2 tiles in flight (6 outstanding loads/thread)
#pragma unroll
    for (int i = 0; i < 3; i++) gload16(src[i], &S[0][base[i]]);
#pragma unroll
    for (int i = 0; i < 3; i++) gload16(src[i] + 16, &S[1][base[i]]);

    for (int t = 0; t < NT; t++) {
        if (t + 1 < NT) {
            asm volatile("s_waitcnt vmcnt(3)" ::: "memory");
        } else {
            asm volatile("s_waitcnt vmcnt(0)" ::: "memory");
        }
        asm volatile("s_barrier" ::: "memory");
        if (t + 2 < NT) {
            const int ko = (t + 2) * 16;
            uint* Sd = &S[(t + 2) % 3][0];
#pragma unroll
            for (int i = 0; i < 3; i++) gload16(src[i] + ko, &Sd[base[i]]);
        }
        const uint* Sc = &S[t % 3][0];
        f16x8 lh_[4], mh_[2];
#pragma unroll
        for (int mi = 0; mi < 4; mi++)
            lh_[mi] = *(const f16x8*)&Sc[TP(wm * 64 + mi * 16 + fr, sl)];
#pragma unroll
        for (int ni = 0; ni < 2; ni++)
            mh_[ni] = *(const f16x8*)&Sc[2048 + TP(wn * 32 + ni * 16 + fr, sl)];
#pragma unroll
        for (int mi = 0; mi < 4; mi++)
#pragma unroll
            for (int ni = 0; ni < 2; ni++)
                acc[mi][ni] = __builtin_amdgcn_mfma_f32_16x16x32_f16(lh_[mi], mh_[ni], acc[mi][ni], 0, 0, 0);
    }
    __syncthreads();   // all compute done before S is reused as f32 scratch

    // ---- Epilogue: LDS-transposed, vectorized (validated formula) ----
    float* Sf = (float*)&S[0][0];    // 128 x 64 f32 = 32 KB (fits in 36 KB)
    float bmv[2];
#pragma unroll
    for (int ni = 0; ni < 2; ni++)
        bmv[ni] = bTm[col0 + wn * 32 + ni * 16 + fr];

#pragma unroll
    for (int ni = 0; ni < 2; ni++) {
#pragma unroll
        for (int mi = 0; mi < 4; mi++) {
            const int rbL = wm * 64 + mi * 16 + ((lane >> 4) << 2);
#pragma unroll
            for (int r = 0; r < 4; r++) {
                const int row = rbL + r;
                const int cm = wn * 32 + ni * 16 + fr;
                const int phys = (cm + ((row >> 2) & 3) * 16 + (row & 3) * 4) & 63;
                Sf[row * 64 + phys] = acc[mi][ni][r] * WDESCALE + bmv[ni];
            }
        }
    }
    __syncthreads();
    const int erow = tid >> 1;
    const int ecg  = tid & 1;
    const int rsw = ((erow >> 2) & 3) * 16 + (erow & 3) * 4;
    float z[32];
#pragma unroll
    for (int j = 0; j < 8; j++) {
        const int phys = (ecg * 32 + j * 4 + rsw) & 63;
        *(float4*)&z[j * 4] = *(const float4*)&Sf[erow * 64 + phys];
    }
    const int colBase = col0 + ecg * 32;
    const size_t idx0 = (size_t)(row0 + erow) * O_DIM + colBase;
    uint4 lh4[4], ll4[4];
#pragma unroll
    for (int j = 0; j < 4; j++) {
        lh4[j] = ((const uint4*)(Lhp + idx0))[j];
        ll4[j] = ((const uint4*)(Llp + idx0))[j];
    }
    float ov[32];
#pragma unroll
    for (int m = 0; m < 32; m++) {
        const uint hu = ((const uint*)lh4)[m >> 1];
        const uint lu = ((const uint*)ll4)[m >> 1];
        const ushort hs = (m & 1) ? (ushort)(hu >> 16) : (ushort)(hu & 0xffff);
        const ushort ls = (m & 1) ? (ushort)(lu >> 16) : (ushort)(lu & 0xffff);
        const float l1 = h2f(hs) + h2f(ls);
        const float zm = z[m];
        const float ea = expf(-zm);
        const float d = l1 * (1.0f + ea) - 0.01f;
        ov[m] = d > 0.0f ? 1.0f : 0.0f;
        const float tol = 2e-4f + 1e-4f * ea * (1.0f + fabsf(l1));
        if (fabsf(d) < tol) {
            const uint pos = atomicAdd(cnt, 1u);
            if (pos < cap) list[pos] = (uint)(idx0 + m);
        }
    }
#pragma unroll
    for (int j = 0; j < 8; j++)
        *(float4*)(out + idx0 + j * 4) = *(const float4*)&ov[j * 4];
}

// ===========================================================================
// Stage-2 SLOW path (general inputs) — unchanged.
// ===========================================================================
__global__ __launch_bounds__(512)
void stage2_slow(const ushort* __restrict__ Lhp, const ushort* __restrict__ Llp,
                 const float* __restrict__ u_t, const float* __restrict__ b_t,
                 const float* __restrict__ spk,
                 const float* __restrict__ WTm, const float* __restrict__ bTm,
                 const float* __restrict__ WTa, const float* __restrict__ bTa,
                 float* __restrict__ out, const uint* __restrict__ flag,
                 uint* __restrict__ cnt, uint* __restrict__ list, uint cap) {
    if (*flag == 0) return;

    __shared__ uint A1h[128][20], A1l[128][20], A2h[128][20], A2l[128][20];
    __shared__ uint Mh[128][20],  Ml[128][20],  Gh[128][20],  Gl[128][20];

    const int tid = threadIdx.x;
    const int lane = tid & 63;
    const int wid = tid >> 6;
    const int wm = wid >> 2;
    const int wn = wid & 3;

    int sid = blockIdx.x;
    sid = (sid & 7) * 64 + (sid >> 3);
    const int bx = sid & 15, by = sid >> 4;
    const int row0 = by * 128, col0 = bx * 128;

    const int srow = tid >> 2;
    const int skb = (tid & 3) * 8;
    const int swc = (tid & 3) * 4;

    const size_t aoff = (size_t)(row0 + srow) * O_DIM + skb;
    const float* pU = u_t + aoff;
    const float* pT = b_t + aoff;
    const float* pM = WTm + (size_t)(col0 + srow) * O_DIM + skb;
    const float* pG = WTa + (size_t)(col0 + srow) * O_DIM + skb;

    f32x4 accM[4][2], accA[4][2];
#pragma unroll
    for (int i = 0; i < 4; i++)
#pragma unroll
        for (int j = 0; j < 2; j++)
#pragma unroll
            for (int r = 0; r < 4; r++) { accM[i][j][r] = 0.0f; accA[i][j][r] = 0.0f; }

    float4 lq0, lq1;
    {
        const uint4 LH = *(const uint4*)(Lhp + aoff);
        const uint4 LL = *(const uint4*)(Llp + aoff);
        unpack8(LH, LL, lq0, lq1);
    }
    float4 uq0 = *(const float4*)(pU + 0), uq1 = *(const float4*)(pU + 4);
    float4 tq0 = *(const float4*)(pT + 0), tq1 = *(const float4*)(pT + 4);
    float4 mq0 = *(const float4*)(pM + 0), mq1 = *(const float4*)(pM + 4);
    float4 gq0 = *(const float4*)(pG + 0), gq1 = *(const float4*)(pG + 4);

    const int fr = lane & 15;
    const int kq = (lane >> 4) * 4;

    for (int t = 0; t < O_DIM / 32; t++) {
        uint4 A1hi, A1lo, A2hi, A2lo, Mhi, Mlo, Ghi, Glo;
        split8(add4(lq0, uq0), add4(lq1, uq1), A1hi, A1lo);
        split8(add4(lq0, tq0), add4(lq1, tq1), A2hi, A2lo);
        split8(mul64(mq0), mul64(mq1), Mhi, Mlo);
        split8(mul64(gq0), mul64(gq1), Ghi, Glo);
        __syncthreads();
        *(uint4*)&A1h[srow][swc] = A1hi;  *(uint4*)&A1l[srow][swc] = A1lo;
        *(uint4*)&A2h[srow][swc] = A2hi;  *(uint4*)&A2l[srow][swc] = A2lo;
        *(uint4*)&Mh[srow][swc]  = Mhi;   *(uint4*)&Ml[srow][swc]  = Mlo;
        *(uint4*)&Gh[srow][swc]  = Ghi;   *(uint4*)&Gl[srow][swc]  = Glo;
        __syncthreads();
        if (t + 1 < O_DIM / 32) {
            const int o = (t + 1) * 32;
            const uint4 LH = *(const uint4*)(Lhp + aoff + o);
            const uint4 LL = *(const uint4*)(Llp + aoff + o);
            unpack8(LH, LL, lq0, lq1);
            uq0 = *(const float4*)(pU + o);  uq1 = *(const float4*)(pU + o + 4);
            tq0 = *(const float4*)(pT + o);  tq1 = *(const float4*)(pT + o + 4);
            mq0 = *(const float4*)(pM + o);  mq1 = *(const float4*)(pM + o + 4);
            gq0 = *(const float4*)(pG + o);  gq1 = *(const float4*)(pG + o + 4);
        }
        {
            f16x8 ah_[4], al_[4], bh_[2], bl_[2];
#pragma unroll
            for (int mi = 0; mi < 4; mi++) {
                const int r = wm * 64 + mi * 16 + fr;
                ah_[mi] = *(const f16x8*)&A1h[r][kq];
                al_[mi] = *(const f16x8*)&A1l[r][kq];
            }
#pragma unroll
            for (int ni = 0; ni < 2; ni++) {
                const int r = wn * 32 + ni * 16 + fr;
                bh_[ni] = *(const f16x8*)&Mh[r][kq];
                bl_[ni] = *(const f16x8*)&Ml[r][kq];
            }
#pragma unroll
            for (int mi = 0; mi < 4; mi++)
#pragma unroll
                for (int ni = 0; ni < 2; ni++) {
                    accM[mi][ni] = __builtin_amdgcn_mfma_f32_16x16x32_f16(ah_[mi], bh_[ni], accM[mi][ni], 0, 0, 0);
                    accM[mi][ni] = __builtin_amdgcn_mfma_f32_16x16x32_f16(ah_[mi], bl_[ni], accM[mi][ni], 0, 0, 0);
                    accM[mi][ni] = __builtin_amdgcn_mfma_f32_16x16x32_f16(al_[mi], bh_[ni], accM[mi][ni], 0, 0, 0);
                }
        }
        {
            f16x8 ah_[4], al_[4], bh_[2], bl_[2];
#pragma unroll
            for (int mi = 0; mi < 4; mi++) {
                const int r = wm * 64 + mi * 16 + fr;
                ah_[mi] = *(const f16x8*)&A2h[r][kq];
                al_[mi] = *(const f16x8*)&A2l[r][kq];
            }
#pragma unroll
            for (int ni = 0; ni < 2; ni++) {
                const int r = wn * 32 + ni * 16 + fr;
                bh_[ni] = *(const f16x8*)&Gh[r][kq];
                bl_[ni] = *(const f16x8*)&Gl[r][kq];
            }
#pragma unroll
            for (int mi = 0; mi < 4; mi++)
#pragma unroll
                for (int ni = 0; ni < 2; ni++) {
                    accA[mi][ni] = __builtin_amdgcn_mfma_f32_16x16x32_f16(ah_[mi], bh_[ni], accA[mi][ni], 0, 0, 0);
                    accA[mi][ni] = __builtin_amdgcn_mfma_f32_16x16x32_f16(ah_[mi], bl_[ni], accA[mi][ni], 0, 0, 0);
                    accA[mi][ni] = __builtin_amdgcn_mfma_f32_16x16x32_f16(al_[mi], bh_[ni], accA[mi][ni], 0, 0, 0);
                }
        }
    }

#pragma unroll
    for (int ni = 0; ni < 2; ni++) {
        const int col = col0 + wn * 32 + ni * 16 + fr;
        const float bm = bTm[col], bg = bTa[col];
#pragma unroll
        for (int mi = 0; mi < 4; mi++) {
            const int rb = row0 + wm * 64 + mi * 16 + ((lane >> 4) << 2);
#pragma unroll
            for (int r = 0; r < 4; r++) {
                const size_t idx = (size_t)(rb + r) * O_DIM + col;
                const float zm = accM[mi][ni][r] * WDESCALE + bm;
                const float za = accA[mi][ni][r] * WDESCALE + bg;
                const float ut = u_t[idx], bt = b_t[idx];
                const float sp = spk[idx];
                const float l1 = h2f(Lhp[idx]) + h2f(Llp[idx]);
                const float ea  = expf(-zm);
                const float rho = 1.0f / (1.0f + expf(-za));
                const float bn  = sp + rho * (bt - sp);
                const float thr = 0.01f + 1.8f * bn;
                const float un  = ut + (l1 - ut) * (1.0f + ea);
                const float d   = un - thr;
                out[idx] = d > 0.0f ? 1.0f : 0.0f;
                const float tol = 2e-4f + 1e-4f * ea * (1.0f + fabsf(l1 - ut))
                                + 2e-4f * fabsf(bt - sp);
                if (fabsf(d) < tol) {
                    const uint pos = atomicAdd(cnt, 1u);
                    if (pos < cap) list[pos] = (uint)idx;
                }
            }
        }
    }
}

// ===========================================================================
__global__ __launch_bounds__(256)
void lsnn_fixup(const ushort* __restrict__ Lhp, const ushort* __restrict__ Llp,
                const float* __restrict__ X, const float* __restrict__ Wsyn,
                const float* __restrict__ bsyn,
                const float* __restrict__ u_t, const float* __restrict__ b_t,
                const float* __restrict__ spk,
                const float* __restrict__ WTm, const float* __restrict__ bTm,
                const float* __restrict__ WTa, const float* __restrict__ bTa,
                const uint* __restrict__ cnt, const uint* __restrict__ list,
                uint cap, float* __restrict__ out) {
    const uint nc = *cnt;
    const uint n = nc < cap ? nc : cap;
    const int lane = threadIdx.x & 63;
    const uint wid = (blockIdx.x * blockDim.x + threadIdx.x) >> 6;
    const uint nw = (gridDim.x * blockDim.x) >> 6;

    for (uint e = wid; e < n; e += nw) {
        const uint idx = list[e];
        const int b = idx >> 11;
        const int o = idx & (O_DIM - 1);

        double l1 = 0.0, zm = 0.0, za = 0.0;
        const float* xr = X + (size_t)b * I_DIM;
        const float* wr = Wsyn + (size_t)o * I_DIM;
        for (int k = lane; k < I_DIM; k += 64)
            l1 = fma((double)xr[k], (double)wr[k], l1);

        const ushort* lhr = Lhp + (size_t)b * O_DIM;
        const ushort* llr = Llp + (size_t)b * O_DIM;
        const float* ur = u_t + (size_t)b * O_DIM;
        const float* tr = b_t + (size_t)b * O_DIM;
        const float* mr = WTm + (size_t)o * O_DIM;
        const float* ar = WTa + (size_t)o * O_DIM;
        for (int k = lane; k < O_DIM; k += 64) {
            const double l = (double)(h2f(lhr[k]) + h2f(llr[k]));
            zm = fma(l + (double)ur[k], (double)mr[k], zm);
            za = fma(l + (double)tr[k], (double)ar[k], za);
        }
#pragma unroll
        for (int off = 32; off > 0; off >>= 1) {
            l1 += __shfl_down(l1, off);
            zm += __shfl_down(zm, off);
            za += __shfl_down(za, off);
        }
        if (lane == 0) {
            l1 += (double)bsyn[o];
            zm += (double)bTm[o];
            za += (double)bTa[o];
            const double inv_alpha = 1.0 + exp(-zm);
            const double rho = 1.0 / (1.0 + exp(-za));
            const double bt = (double)b_t[idx];
            const double sp = (double)spk[idx];
            const double ut = (double)u_t[idx];
            const double b_new = sp + rho * (bt - sp);
            const double thr = 0.01 + 1.8 * b_new;
            const double u_new = ut + (l1 - ut) * inv_alpha;
            out[idx] = (u_new - thr > 0.0) ? 1.0f : 0.0f;
        }
    }
}

// ===========================================================================
extern "C" void kernel_launch(void* const* d_in, const int* in_sizes, int n_in,
                              void* d_out, int out_size, void* d_ws, size_t ws_size,
                              hipStream_t stream) {
    const float* x    = (const float*)d_in[0];
    const float* u_t  = (const float*)d_in[1];
    const float* b_t  = (const float*)d_in[2];
    const float* spk  = (const float*)d_in[3];
    const float* Wsyn = (const float*)d_in[4];
    const float* bsyn = (const float*)d_in[5];
    const float* WTm  = (const float*)d_in[6];
    const float* bTm  = (const float*)d_in[7];
    const float* WTa  = (const float*)d_in[8];
    const float* bTa  = (const float*)d_in[9];
    float* out = (float*)d_out;

    char* ws = (char*)d_ws;
    ushort* Lhp = (ushort*)(ws + 0 * MBYTE);
    ushort* Llp = (ushort*)(ws + 16 * MBYTE);
    ushort* Mhp = (ushort*)(ws + 32 * MBYTE);
    ushort* Wsh = (ushort*)(ws + 40 * MBYTE);
    ushort* Wsl = (ushort*)(ws + 48 * MBYTE);

    const bool tierA = ws_size >= 91 * MBYTE;
    const size_t flag_off = tierA ? 88 * MBYTE : 56 * MBYTE;
    if (ws_size < flag_off + (1u << 16)) return;

    ushort* Xh = (ushort*)(ws + 56 * MBYTE);
    ushort* Xl = (ushort*)(ws + 72 * MBYTE);
    uint* flag = (uint*)(ws + flag_off);
    uint* cnt  = (uint*)(ws + flag_off + 4);
    uint* list = (uint*)(ws + flag_off + 256);
    const uint cap = (uint)((ws_size - flag_off - 256) / sizeof(uint));

    (void)hipMemsetAsync(ws + flag_off, 0, 8, stream);
    prep<<<dim3(2048), dim3(256), 0, stream>>>(x, Wsyn, WTm, u_t, b_t, spk,
                                               Xh, Xl, Wsh, Wsl, Mhp, flag,
                                               tierA ? 1 : 0);
    if (tierA) {
        gemm1_c<<<dim3(512), dim3(512), 0, stream>>>(Xh, Xl, Wsh, Wsl, bsyn, Lhp, Llp);
    } else {
        gemm1_b<<<dim3(256), dim3(256), 0, stream>>>(x, Wsh, Wsl, bsyn, Lhp, Llp);
    }
    stage2_fast<<<dim3(1024), dim3(256), 0, stream>>>(Lhp, Llp, Mhp, bTm,
                                                      out, flag, cnt, list, cap);
    stage2_slow<<<dim3(512), dim3(512), 0, stream>>>(Lhp, Llp, u_t, b_t, spk,
                                                     WTm, bTm, WTa, bTa,
                                                     out, flag, cnt, list, cap);
    lsnn_fixup<<<dim3(256), dim3(256), 0, stream>>>(Lhp, Llp, x, Wsyn, bsyn,
                                                    u_t, b_t, spk,
                                                    WTm, bTm, WTa, bTa,
                                                    cnt, list, cap, out);
}

// Round 13
// 258.824 us; speedup vs baseline: 1.0425x; 1.0425x over previous
//
#include <hip/hip_runtime.h>
#include <cmath>

#define B_DIM 4096
#define O_DIM 2048
#define I_DIM 2048

typedef _Float16 f16x8 __attribute__((ext_vector_type(8)));
typedef float f32x4 __attribute__((ext_vector_type(4)));
typedef unsigned int uint;
typedef unsigned short ushort;

#define WSCALE   64.0f
#define WDESCALE 0.015625f
#define MBYTE    ((size_t)1024 * 1024)

// ws layout:
// L1h 0..16M | L1l 16..32M | Mh 32..40M | Wsh 40..48M | Wsl 48..56M
// tier A adds: Xh 56..72M | Xl 72..88M ; flag at 88M (A) or 56M (B)

// Swizzled LDS tile: [rows][16 dwords]; 16B slot s: phys = s ^ ((r>>1)&3).
__device__ __forceinline__ int TP(int r, int s) {
    return r * 16 + (((s ^ ((r >> 1) & 3))) << 2);
}

__device__ __forceinline__ float h2f(ushort u) {
    _Float16 h = __builtin_bit_cast(_Float16, u);
    return (float)h;
}

__device__ __forceinline__ void gload16(const uint* src, uint* lds) {
    __builtin_amdgcn_global_load_lds(
        (const __attribute__((address_space(1))) void*)src,
        (__attribute__((address_space(3))) void*)lds, 16, 0, 0);
}

__device__ __forceinline__ void split8(const float4 a, const float4 b,
                                       uint4& hi, uint4& lo) {
    auto h0 = __builtin_amdgcn_cvt_pkrtz(a.x, a.y);
    auto h1 = __builtin_amdgcn_cvt_pkrtz(a.z, a.w);
    auto h2 = __builtin_amdgcn_cvt_pkrtz(b.x, b.y);
    auto h3 = __builtin_amdgcn_cvt_pkrtz(b.z, b.w);
    auto l0 = __builtin_amdgcn_cvt_pkrtz(a.x - (float)h0[0], a.y - (float)h0[1]);
    auto l1 = __builtin_amdgcn_cvt_pkrtz(a.z - (float)h1[0], a.w - (float)h1[1]);
    auto l2 = __builtin_amdgcn_cvt_pkrtz(b.x - (float)h2[0], b.y - (float)h2[1]);
    auto l3 = __builtin_amdgcn_cvt_pkrtz(b.z - (float)h3[0], b.w - (float)h3[1]);
    hi.x = __builtin_bit_cast(uint, h0); hi.y = __builtin_bit_cast(uint, h1);
    hi.z = __builtin_bit_cast(uint, h2); hi.w = __builtin_bit_cast(uint, h3);
    lo.x = __builtin_bit_cast(uint, l0); lo.y = __builtin_bit_cast(uint, l1);
    lo.z = __builtin_bit_cast(uint, l2); lo.w = __builtin_bit_cast(uint, l3);
}

__device__ __forceinline__ float4 add4(const float4 a, const float4 b) {
    return make_float4(a.x + b.x, a.y + b.y, a.z + b.z, a.w + b.w);
}
__device__ __forceinline__ float4 mul64(const float4 a) {
    return make_float4(a.x * WSCALE, a.y * WSCALE, a.z * WSCALE, a.w * WSCALE);
}
__device__ __forceinline__ void unpack8(const uint4 h, const uint4 l,
                                        float4& f0, float4& f1) {
    f0.x = h2f((ushort)(h.x & 0xffff)) + h2f((ushort)(l.x & 0xffff));
    f0.y = h2f((ushort)(h.x >> 16))    + h2f((ushort)(l.x >> 16));
    f0.z = h2f((ushort)(h.y & 0xffff)) + h2f((ushort)(l.y & 0xffff));
    f0.w = h2f((ushort)(h.y >> 16))    + h2f((ushort)(l.y >> 16));
    f1.x = h2f((ushort)(h.z & 0xffff)) + h2f((ushort)(l.z & 0xffff));
    f1.y = h2f((ushort)(h.z >> 16))    + h2f((ushort)(l.z >> 16));
    f1.z = h2f((ushort)(h.w & 0xffff)) + h2f((ushort)(l.w & 0xffff));
    f1.w = h2f((ushort)(h.w >> 16))    + h2f((ushort)(l.w >> 16));
}

// ===========================================================================
// prep: fused zcheck + split(x) + split(Wsyn*64) + split_hi(WTm*64)
// ===========================================================================
__global__ __launch_bounds__(256)
void prep(const float* __restrict__ x, const float* __restrict__ Wsyn,
          const float* __restrict__ WTm,
          const float* __restrict__ u, const float* __restrict__ b,
          const float* __restrict__ s,
          ushort* __restrict__ Xh, ushort* __restrict__ Xl,
          ushort* __restrict__ Wsh, ushort* __restrict__ Wsl,
          ushort* __restrict__ Mhp, uint* __restrict__ flag, int doX) {
    const uint NX = (uint)((size_t)B_DIM * I_DIM / 8);
    const uint NW = (uint)((size_t)O_DIM * I_DIM / 8);
    const uint NZ = (uint)((size_t)B_DIM * O_DIM / 8);
    const uint nx = doX ? NX : 0;
    const uint total = nx + 2 * NW + NZ;
    const uint stride = gridDim.x * blockDim.x;
    bool nz = false;
    for (uint t = blockIdx.x * blockDim.x + threadIdx.x; t < total; t += stride) {
        if (t < nx) {
            const size_t i = (size_t)t * 8;
            uint4 h, l;
            split8(*(const float4*)(x + i), *(const float4*)(x + i + 4), h, l);
            *(uint4*)(Xh + i) = h; *(uint4*)(Xl + i) = l;
        } else if (t < nx + NW) {
            const size_t i = (size_t)(t - nx) * 8;
            uint4 h, l;
            split8(mul64(*(const float4*)(Wsyn + i)),
                   mul64(*(const float4*)(Wsyn + i + 4)), h, l);
            *(uint4*)(Wsh + i) = h; *(uint4*)(Wsl + i) = l;
        } else if (t < nx + 2 * NW) {
            const size_t i = (size_t)(t - nx - NW) * 8;
            const float4 a = mul64(*(const float4*)(WTm + i));
            const float4 c = mul64(*(const float4*)(WTm + i + 4));
            auto h0 = __builtin_amdgcn_cvt_pkrtz(a.x, a.y);
            auto h1 = __builtin_amdgcn_cvt_pkrtz(a.z, a.w);
            auto h2 = __builtin_amdgcn_cvt_pkrtz(c.x, c.y);
            auto h3 = __builtin_amdgcn_cvt_pkrtz(c.z, c.w);
            uint4 h;
            h.x = __builtin_bit_cast(uint, h0); h.y = __builtin_bit_cast(uint, h1);
            h.z = __builtin_bit_cast(uint, h2); h.w = __builtin_bit_cast(uint, h3);
            *(uint4*)(Mhp + i) = h;
        } else {
            const size_t i = (size_t)(t - nx - 2 * NW) * 8;
            const float4 a0 = *(const float4*)(u + i), a1 = *(const float4*)(u + i + 4);
            const float4 b0 = *(const float4*)(b + i), b1 = *(const float4*)(b + i + 4);
            const float4 c0 = *(const float4*)(s + i), c1 = *(const float4*)(s + i + 4);
            nz |= (a0.x != 0.f) | (a0.y != 0.f) | (a0.z != 0.f) | (a0.w != 0.f);
            nz |= (a1.x != 0.f) | (a1.y != 0.f) | (a1.z != 0.f) | (a1.w != 0.f);
            nz |= (b0.x != 0.f) | (b0.y != 0.f) | (b0.z != 0.f) | (b0.w != 0.f);
            nz |= (b1.x != 0.f) | (b1.y != 0.f) | (b1.z != 0.f) | (b1.w != 0.f);
            nz |= (c0.x != 0.f) | (c0.y != 0.f) | (c0.z != 0.f) | (c0.w != 0.f);
            nz |= (c1.x != 0.f) | (c1.y != 0.f) | (c1.z != 0.f) | (c1.w != 0.f);
        }
    }
    if (nz) atomicOr(flag, 1u);
}

// ===========================================================================
// GEMM1 tier A: 128x128 tile, 512 thr (8 waves, 64x32), 3-deep LDS pipeline
// with counted vmcnt (validated round 11, 966 TF).
// ===========================================================================
__global__ __launch_bounds__(512)
void gemm1_c(const ushort* __restrict__ Xh, const ushort* __restrict__ Xl,
             const ushort* __restrict__ Wh, const ushort* __restrict__ Wl,
             const float* __restrict__ bias,
             ushort* __restrict__ Lh, ushort* __restrict__ Ll) {
    __shared__ uint S[3][8192];   // 96 KB

    const int tid = threadIdx.x;
    const int lane = tid & 63;
    const int wid = tid >> 6;
    const int wm = wid >> 2;
    const int wn = wid & 3;

    int sid = blockIdx.x;
    sid = (sid & 7) * 64 + (sid >> 3);
    const int bx = sid & 15, by = sid >> 4;
    const int row0 = by * 128, col0 = bx * 128;

    const uint* src[4];
    int dbase[4];
#pragma unroll
    for (int i = 0; i < 4; i++) {
        const int ch = wid * 4 + i;
        const int p = ch >> 3, c = ch & 7;
        const int g = c * 64 + lane;
        const int r = g >> 2, q = (g & 3) ^ ((r >> 1) & 3);
        dbase[i] = p * 2048 + c * 256;
        const ushort* plane = (p == 0) ? Xh : (p == 1) ? Xl : (p == 2) ? Wh : Wl;
        const int grow = (p < 2) ? (row0 + r) : (col0 + r);
        src[i] = (const uint*)plane + (size_t)grow * 1024 + q * 4;
    }

    f32x4 acc[4][2];
#pragma unroll
    for (int i = 0; i < 4; i++)
#pragma unroll
        for (int j = 0; j < 2; j++)
#pragma unroll
            for (int r = 0; r < 4; r++) acc[i][j][r] = 0.0f;

    const int fr = lane & 15;
    const int sl = lane >> 4;
    const int NT = I_DIM / 32;

#pragma unroll
    for (int i = 0; i < 4; i++) gload16(src[i], &S[0][dbase[i]]);
#pragma unroll
    for (int i = 0; i < 4; i++) gload16(src[i] + 16, &S[1][dbase[i]]);

    for (int t = 0; t < NT; t++) {
        if (t + 1 < NT) {
            asm volatile("s_waitcnt vmcnt(4)" ::: "memory");
        } else {
            asm volatile("s_waitcnt vmcnt(0)" ::: "memory");
        }
        asm volatile("s_barrier" ::: "memory");
        if (t + 2 < NT) {
            const int ko = (t + 2) * 16;
            uint* Sd = &S[(t + 2) % 3][0];
#pragma unroll
            for (int i = 0; i < 4; i++) gload16(src[i] + ko, &Sd[dbase[i]]);
        }
        const uint* Sc = &S[t % 3][0];
        f16x8 ah_[4], al_[4], bh_[2], bl_[2];
#pragma unroll
        for (int mi = 0; mi < 4; mi++) {
            const int r = wm * 64 + mi * 16 + fr;
            ah_[mi] = *(const f16x8*)&Sc[TP(r, sl)];
            al_[mi] = *(const f16x8*)&Sc[2048 + TP(r, sl)];
        }
#pragma unroll
        for (int ni = 0; ni < 2; ni++) {
            const int r = wn * 32 + ni * 16 + fr;
            bh_[ni] = *(const f16x8*)&Sc[4096 + TP(r, sl)];
            bl_[ni] = *(const f16x8*)&Sc[6144 + TP(r, sl)];
        }
#pragma unroll
        for (int mi = 0; mi < 4; mi++)
#pragma unroll
            for (int ni = 0; ni < 2; ni++) {
                acc[mi][ni] = __builtin_amdgcn_mfma_f32_16x16x32_f16(ah_[mi], bh_[ni], acc[mi][ni], 0, 0, 0);
                acc[mi][ni] = __builtin_amdgcn_mfma_f32_16x16x32_f16(ah_[mi], bl_[ni], acc[mi][ni], 0, 0, 0);
                acc[mi][ni] = __builtin_amdgcn_mfma_f32_16x16x32_f16(al_[mi], bh_[ni], acc[mi][ni], 0, 0, 0);
            }
    }

#pragma unroll
    for (int ni = 0; ni < 2; ni++) {
        const int col = col0 + wn * 32 + ni * 16 + fr;
        const float bv = bias[col];
#pragma unroll
        for (int mi = 0; mi < 4; mi++) {
            const int rb = row0 + wm * 64 + mi * 16 + ((lane >> 4) << 2);
            float e[4];
#pragma unroll
            for (int r = 0; r < 4; r++) e[r] = acc[mi][ni][r] * WDESCALE + bv;
            auto hp0 = __builtin_amdgcn_cvt_pkrtz(e[0], e[1]);
            auto hp1 = __builtin_amdgcn_cvt_pkrtz(e[2], e[3]);
            auto lp0 = __builtin_amdgcn_cvt_pkrtz(e[0] - (float)hp0[0], e[1] - (float)hp0[1]);
            auto lp1 = __builtin_amdgcn_cvt_pkrtz(e[2] - (float)hp1[0], e[3] - (float)hp1[1]);
            const uint uh0 = __builtin_bit_cast(uint, hp0);
            const uint uh1 = __builtin_bit_cast(uint, hp1);
            const uint ul0 = __builtin_bit_cast(uint, lp0);
            const uint ul1 = __builtin_bit_cast(uint, lp1);
            Lh[(size_t)(rb + 0) * O_DIM + col] = (ushort)(uh0 & 0xffff);
            Lh[(size_t)(rb + 1) * O_DIM + col] = (ushort)(uh0 >> 16);
            Lh[(size_t)(rb + 2) * O_DIM + col] = (ushort)(uh1 & 0xffff);
            Lh[(size_t)(rb + 3) * O_DIM + col] = (ushort)(uh1 >> 16);
            Ll[(size_t)(rb + 0) * O_DIM + col] = (ushort)(ul0 & 0xffff);
            Ll[(size_t)(rb + 1) * O_DIM + col] = (ushort)(ul0 >> 16);
            Ll[(size_t)(rb + 2) * O_DIM + col] = (ushort)(ul1 & 0xffff);
            Ll[(size_t)(rb + 3) * O_DIM + col] = (ushort)(ul1 >> 16);
        }
    }
}

// ===========================================================================
// GEMM1 tier B: Wsyn pre-split (gload16), X split in-loop (unchanged).
// ===========================================================================
__global__ __launch_bounds__(256)
void gemm1_b(const float* __restrict__ X,
             const ushort* __restrict__ Wh, const ushort* __restrict__ Wl,
             const float* __restrict__ bias,
             ushort* __restrict__ Lh, ushort* __restrict__ Ll) {
    __shared__ uint S[8192];

    const int tid = threadIdx.x;
    const int lane = tid & 63;
    const int wid = tid >> 6;
    const int wm = wid >> 1, wn = wid & 1;

    int sid = blockIdx.x;
    sid = (sid & 7) * 64 + (sid >> 3);
    const int bx = sid & 15, by = sid >> 4;
    const int row0 = by * 128, col0 = bx * 128;

    const int sr = tid >> 1;
    const int kh = (tid & 1) * 16;
    const int s0 = (tid & 1) * 2;
    const float* pA = X + (size_t)(row0 + sr) * I_DIM + kh;

    int r0, q0, r1, q1;
    {
        const int g0 = (wid * 2 + 0) * 64 + lane;
        const int g1 = (wid * 2 + 1) * 64 + lane;
        r0 = g0 >> 2; q0 = (g0 & 3) ^ ((r0 >> 1) & 3);
        r1 = g1 >> 2; q1 = (g1 & 3) ^ ((r1 >> 1) & 3);
    }
    const uint* sWh0 = (const uint*)Wh + (size_t)(col0 + r0) * 1024 + q0 * 4;
    const uint* sWh1 = (const uint*)Wh + (size_t)(col0 + r1) * 1024 + q1 * 4;
    const uint* sWl0 = (const uint*)Wl + (size_t)(col0 + r0) * 1024 + q0 * 4;
    const uint* sWl1 = (const uint*)Wl + (size_t)(col0 + r1) * 1024 + q1 * 4;
    const int c0 = (wid * 2 + 0) << 8;
    const int c1 = (wid * 2 + 1) << 8;

    f32x4 acc[4][4];
#pragma unroll
    for (int i = 0; i < 4; i++)
#pragma unroll
        for (int j = 0; j < 4; j++)
#pragma unroll
            for (int r = 0; r < 4; r++) acc[i][j][r] = 0.0f;

    const int fr = lane & 15;
    const int sl = lane >> 4;
    const int NT = I_DIM / 32;

    float4 a0 = *(const float4*)(pA + 0), a1 = *(const float4*)(pA + 4);
    float4 a2 = *(const float4*)(pA + 8), a3 = *(const float4*)(pA + 12);
    uint4 xh0, xl0, xh1, xl1;
    split8(a0, a1, xh0, xl0);
    split8(a2, a3, xh1, xl1);

    for (int t = 0; t < NT; t++) {
        __syncthreads();
        *(uint4*)&S[TP(sr, s0)] = xh0;         *(uint4*)&S[TP(sr, s0 + 1)] = xh1;
        *(uint4*)&S[2048 + TP(sr, s0)] = xl0;  *(uint4*)&S[2048 + TP(sr, s0 + 1)] = xl1;
        const int ko = t * 16;
        gload16(sWh0 + ko, &S[4096 + c0]);  gload16(sWh1 + ko, &S[4096 + c1]);
        gload16(sWl0 + ko, &S[6144 + c0]);  gload16(sWl1 + ko, &S[6144 + c1]);
        __syncthreads();
        if (t + 1 < NT) {
            const float* nA = pA + (t + 1) * 32;
            a0 = *(const float4*)(nA + 0); a1 = *(const float4*)(nA + 4);
            a2 = *(const float4*)(nA + 8); a3 = *(const float4*)(nA + 12);
        }
        f16x8 ah_[4], al_[4], bh_[4], bl_[4];
#pragma unroll
        for (int mi = 0; mi < 4; mi++) {
            const int r = wm * 64 + mi * 16 + fr;
            ah_[mi] = *(const f16x8*)&S[TP(r, sl)];
            al_[mi] = *(const f16x8*)&S[2048 + TP(r, sl)];
        }
#pragma unroll
        for (int ni = 0; ni < 4; ni++) {
            const int r = wn * 64 + ni * 16 + fr;
            bh_[ni] = *(const f16x8*)&S[4096 + TP(r, sl)];
            bl_[ni] = *(const f16x8*)&S[6144 + TP(r, sl)];
        }
#pragma unroll
        for (int mi = 0; mi < 4; mi++)
#pragma unroll
            for (int ni = 0; ni < 4; ni++) {
                acc[mi][ni] = __builtin_amdgcn_mfma_f32_16x16x32_f16(ah_[mi], bh_[ni], acc[mi][ni], 0, 0, 0);
                acc[mi][ni] = __builtin_amdgcn_mfma_f32_16x16x32_f16(ah_[mi], bl_[ni], acc[mi][ni], 0, 0, 0);
                acc[mi][ni] = __builtin_amdgcn_mfma_f32_16x16x32_f16(al_[mi], bh_[ni], acc[mi][ni], 0, 0, 0);
            }
        if (t + 1 < NT) {
            split8(a0, a1, xh0, xl0);
            split8(a2, a3, xh1, xl1);
        }
    }

    const int fr2 = lane & 15;
#pragma unroll
    for (int ni = 0; ni < 4; ni++) {
        const int col = col0 + wn * 64 + ni * 16 + fr2;
        const float bv = bias[col];
#pragma unroll
        for (int mi = 0; mi < 4; mi++) {
            const int rb = row0 + wm * 64 + mi * 16 + ((lane >> 4) << 2);
            float e[4];
#pragma unroll
            for (int r = 0; r < 4; r++) e[r] = acc[mi][ni][r] * WDESCALE + bv;
            auto hp0 = __builtin_amdgcn_cvt_pkrtz(e[0], e[1]);
            auto hp1 = __builtin_amdgcn_cvt_pkrtz(e[2], e[3]);
            auto lp0 = __builtin_amdgcn_cvt_pkrtz(e[0] - (float)hp0[0], e[1] - (float)hp0[1]);
            auto lp1 = __builtin_amdgcn_cvt_pkrtz(e[2] - (float)hp1[0], e[3] - (float)hp1[1]);
            const uint uh0 = __builtin_bit_cast(uint, hp0);
            const uint uh1 = __builtin_bit_cast(uint, hp1);
            const uint ul0 = __builtin_bit_cast(uint, lp0);
            const uint ul1 = __builtin_bit_cast(uint, lp1);
            Lh[(size_t)(rb + 0) * O_DIM + col] = (ushort)(uh0 & 0xffff);
            Lh[(size_t)(rb + 1) * O_DIM + col] = (ushort)(uh0 >> 16);
            Lh[(size_t)(rb + 2) * O_DIM + col] = (ushort)(uh1 & 0xffff);
            Lh[(size_t)(rb + 3) * O_DIM + col] = (ushort)(uh1 >> 16);
            Ll[(size_t)(rb + 0) * O_DIM + col] = (ushort)(ul0 & 0xffff);
            Ll[(size_t)(rb + 1) * O_DIM + col] = (ushort)(ul0 >> 16);
            Ll[(size_t)(rb + 2) * O_DIM + col] = (ushort)(ul1 & 0xffff);
            Ll[(size_t)(rb + 3) * O_DIM + col] = (ushort)(ul1 >> 16);
        }
    }
}

// ===========================================================================
// Stage-2 FAST: 128x128 tile (round-9 geometry), 4 waves of 64x64,
// 3-deep counted-vmcnt pipeline (gemm1_c protocol). LDS 48 KB -> 3 blocks/CU.
// Two-pass LDS-transposed epilogue (round-9 validated).
// ===========================================================================
__global__ __launch_bounds__(256)
void stage2_fast(const ushort* __restrict__ Lhp, const ushort* __restrict__ Llp,
                 const ushort* __restrict__ Mhp,
                 const float* __restrict__ bTm, float* __restrict__ out,
                 const uint* __restrict__ flag,
                 uint* __restrict__ cnt, uint* __restrict__ list, uint cap) {
    if (*flag != 0) return;

    // per buf 4096 dwords: Lh tile [0,2048), Mh tile [2048,4096)
    __shared__ uint S[3][4096];   // 48 KB

    const int tid = threadIdx.x;
    const int lane = tid & 63;
    const int wid = tid >> 6;
    const int wm = wid >> 1, wn = wid & 1;

    int sid = blockIdx.x;
    sid = (sid & 7) * 64 + (sid >> 3);    // XCD swizzle (512 % 8 == 0)
    const int bx = sid & 15, by = sid >> 4;
    const int row0 = by * 128, col0 = bx * 128;

    // 4 src pointers/thread (round-9 mapping, pre-swizzled)
    const uint* srcL0; const uint* srcL1; const uint* srcM0; const uint* srcM1;
    {
        const int g0 = (wid * 2 + 0) * 64 + lane;
        const int g1 = (wid * 2 + 1) * 64 + lane;
        const int r0 = g0 >> 2, q0 = (g0 & 3) ^ ((r0 >> 1) & 3);
        const int r1 = g1 >> 2, q1 = (g1 & 3) ^ ((r1 >> 1) & 3);
        srcL0 = (const uint*)Lhp + (size_t)(row0 + r0) * 1024 + q0 * 4;
        srcL1 = (const uint*)Lhp + (size_t)(row0 + r1) * 1024 + q1 * 4;
        srcM0 = (const uint*)Mhp + (size_t)(col0 + r0) * 1024 + q0 * 4;
        srcM1 = (const uint*)Mhp + (size_t)(col0 + r1) * 1024 + q1 * 4;
    }
    const int c0 = (wid * 2 + 0) << 8;
    const int c1 = (wid * 2 + 1) << 8;

    f32x4 acc[4][4];
#pragma unroll
    for (int i = 0; i < 4; i++)
#pragma unroll
        for (int j = 0; j < 4; j++)
#pragma unroll
            for (int r = 0; r < 4; r++) acc[i][j][r] = 0.0f;

    const int fr = lane & 15;
    const int sl = lane >> 4;
    const int NT = O_DIM / 32;

    // prologue: 2 tiles in flight (8 outstanding loads/thread)
    gload16(srcL0, &S[0][c0]);         gload16(srcL1, &S[0][c1]);
    gload16(srcM0, &S[0][2048 + c0]);  gload16(srcM1, &S[0][2048 + c1]);
    gload16(srcL0 + 16, &S[1][c0]);        gload16(srcL1 + 16, &S[1][c1]);
    gload16(srcM0 + 16, &S[1][2048 + c0]); gload16(srcM1 + 16, &S[1][2048 + c1]);

    for (int t = 0; t < NT; t++) {
        if (t + 1 < NT) {
            asm volatile("s_waitcnt vmcnt(4)" ::: "memory");
        } else {
            asm volatile("s_waitcnt vmcnt(0)" ::: "memory");
        }
        asm volatile("s_barrier" ::: "memory");
        if (t + 2 < NT) {
            const int ko = (t + 2) * 16;
            uint* Sd = &S[(t + 2) % 3][0];
            gload16(srcL0 + ko, &Sd[c0]);         gload16(srcL1 + ko, &Sd[c1]);
            gload16(srcM0 + ko, &Sd[2048 + c0]);  gload16(srcM1 + ko, &Sd[2048 + c1]);
        }
        const uint* Sc = &S[t % 3][0];
        f16x8 lh_[4], mh_[4];
#pragma unroll
        for (int mi = 0; mi < 4; mi++)
            lh_[mi] = *(const f16x8*)&Sc[TP(wm * 64 + mi * 16 + fr, sl)];
#pragma unroll
        for (int ni = 0; ni < 4; ni++)
            mh_[ni] = *(const f16x8*)&Sc[2048 + TP(wn * 64 + ni * 16 + fr, sl)];
#pragma unroll
        for (int mi = 0; mi < 4; mi++)
#pragma unroll
            for (int ni = 0; ni < 4; ni++)
                acc[mi][ni] = __builtin_amdgcn_mfma_f32_16x16x32_f16(lh_[mi], mh_[ni], acc[mi][ni], 0, 0, 0);
    }
    __syncthreads();   // all compute done before S is reused as f32 scratch

    // ---- Epilogue: two-pass LDS transpose (round-9 validated) ----
    float* Sf = (float*)&S[0][0];    // 128 x 64 f32 = 32 KB (fits in 48 KB)
    float bmv[4];
#pragma unroll
    for (int ni = 0; ni < 4; ni++)
        bmv[ni] = bTm[col0 + wn * 64 + ni * 16 + fr];

    const int erow = tid >> 1;        // 0..127
    const int ecg  = tid & 1;         // 0..1

#pragma unroll
    for (int h = 0; h < 2; h++) {
        if (h) __syncthreads();       // protect Sf from previous read phase
#pragma unroll
        for (int ni2 = 0; ni2 < 2; ni2++) {
            const int ni = h * 2 + ni2;
#pragma unroll
            for (int mi = 0; mi < 4; mi++) {
                const int rbL = wm * 64 + mi * 16 + ((lane >> 4) << 2);
#pragma unroll
                for (int r = 0; r < 4; r++) {
                    const int row = rbL + r;
                    const int cm = wn * 32 + ni2 * 16 + fr;
                    const int phys = (cm + ((row >> 2) & 3) * 16 + (row & 3) * 4) & 63;
                    Sf[row * 64 + phys] = acc[mi][ni][r] * WDESCALE + bmv[ni];
                }
            }
        }
        __syncthreads();
        const int rsw = ((erow >> 2) & 3) * 16 + (erow & 3) * 4;
        float z[32];
#pragma unroll
        for (int j = 0; j < 8; j++) {
            const int phys = (ecg * 32 + j * 4 + rsw) & 63;
            *(float4*)&z[j * 4] = *(const float4*)&Sf[erow * 64 + phys];
        }
        const int colBase = col0 + ecg * 64 + h * 32;
        const size_t idx0 = (size_t)(row0 + erow) * O_DIM + colBase;
        uint4 lh4[4], ll4[4];
#pragma unroll
        for (int j = 0; j < 4; j++) {
            lh4[j] = ((const uint4*)(Lhp + idx0))[j];
            ll4[j] = ((const uint4*)(Llp + idx0))[j];
        }
        float ov[32];
#pragma unroll
        for (int m = 0; m < 32; m++) {
            const uint hu = ((const uint*)lh4)[m >> 1];
            const uint lu = ((const uint*)ll4)[m >> 1];
            const ushort hs = (m & 1) ? (ushort)(hu >> 16) : (ushort)(hu & 0xffff);
            const ushort ls = (m & 1) ? (ushort)(lu >> 16) : (ushort)(lu & 0xffff);
            const float l1 = h2f(hs) + h2f(ls);
            const float zm = z[m];
            const float ea = expf(-zm);
            const float d = l1 * (1.0f + ea) - 0.01f;
            ov[m] = d > 0.0f ? 1.0f : 0.0f;
            const float tol = 2e-4f + 1e-4f * ea * (1.0f + fabsf(l1));
            if (fabsf(d) < tol) {
                const uint pos = atomicAdd(cnt, 1u);
                if (pos < cap) list[pos] = (uint)(idx0 + m);
            }
        }
#pragma unroll
        for (int j = 0; j < 8; j++)
            *(float4*)(out + idx0 + j * 4) = *(const float4*)&ov[j * 4];
    }
}

// ===========================================================================
// Stage-2 SLOW path (general inputs) — unchanged.
// ===========================================================================
__global__ __launch_bounds__(512)
void stage2_slow(const ushort* __restrict__ Lhp, const ushort* __restrict__ Llp,
                 const float* __restrict__ u_t, const float* __restrict__ b_t,
                 const float* __restrict__ spk,
                 const float* __restrict__ WTm, const float* __restrict__ bTm,
                 const float* __restrict__ WTa, const float* __restrict__ bTa,
                 float* __restrict__ out, const uint* __restrict__ flag,
                 uint* __restrict__ cnt, uint* __restrict__ list, uint cap) {
    if (*flag == 0) return;

    __shared__ uint A1h[128][20], A1l[128][20], A2h[128][20], A2l[128][20];
    __shared__ uint Mh[128][20],  Ml[128][20],  Gh[128][20],  Gl[128][20];

    const int tid = threadIdx.x;
    const int lane = tid & 63;
    const int wid = tid >> 6;
    const int wm = wid >> 2;
    const int wn = wid & 3;

    int sid = blockIdx.x;
    sid = (sid & 7) * 64 + (sid >> 3);
    const int bx = sid & 15, by = sid >> 4;
    const int row0 = by * 128, col0 = bx * 128;

    const int srow = tid >> 2;
    const int skb = (tid & 3) * 8;
    const int swc = (tid & 3) * 4;

    const size_t aoff = (size_t)(row0 + srow) * O_DIM + skb;
    const float* pU = u_t + aoff;
    const float* pT = b_t + aoff;
    const float* pM = WTm + (size_t)(col0 + srow) * O_DIM + skb;
    const float* pG = WTa + (size_t)(col0 + srow) * O_DIM + skb;

    f32x4 accM[4][2], accA[4][2];
#pragma unroll
    for (int i = 0; i < 4; i++)
#pragma unroll
        for (int j = 0; j < 2; j++)
#pragma unroll
            for (int r = 0; r < 4; r++) { accM[i][j][r] = 0.0f; accA[i][j][r] = 0.0f; }

    float4 lq0, lq1;
    {
        const uint4 LH = *(const uint4*)(Lhp + aoff);
        const uint4 LL = *(const uint4*)(Llp + aoff);
        unpack8(LH, LL, lq0, lq1);
    }
    float4 uq0 = *(const float4*)(pU + 0), uq1 = *(const float4*)(pU + 4);
    float4 tq0 = *(const float4*)(pT + 0), tq1 = *(const float4*)(pT + 4);
    float4 mq0 = *(const float4*)(pM + 0), mq1 = *(const float4*)(pM + 4);
    float4 gq0 = *(const float4*)(pG + 0), gq1 = *(const float4*)(pG + 4);

    const int fr = lane & 15;
    const int kq = (lane >> 4) * 4;

    for (int t = 0; t < O_DIM / 32; t++) {
        uint4 A1hi, A1lo, A2hi, A2lo, Mhi, Mlo, Ghi, Glo;
        split8(add4(lq0, uq0), add4(lq1, uq1), A1hi, A1lo);
        split8(add4(lq0, tq0), add4(lq1, tq1), A2hi, A2lo);
        split8(mul64(mq0), mul64(mq1), Mhi, Mlo);
        split8(mul64(gq0), mul64(gq1), Ghi, Glo);
        __syncthreads();
        *(uint4*)&A1h[srow][swc] = A1hi;  *(uint4*)&A1l[srow][swc] = A1lo;
        *(uint4*)&A2h[srow][swc] = A2hi;  *(uint4*)&A2l[srow][swc] = A2lo;
        *(uint4*)&Mh[srow][swc]  = Mhi;   *(uint4*)&Ml[srow][swc]  = Mlo;
        *(uint4*)&Gh[srow][swc]  = Ghi;   *(uint4*)&Gl[srow][swc]  = Glo;
        __syncthreads();
        if (t + 1 < O_DIM / 32) {
            const int o = (t + 1) * 32;
            const uint4 LH = *(const uint4*)(Lhp + aoff + o);
            const uint4 LL = *(const uint4*)(Llp + aoff + o);
            unpack8(LH, LL, lq0, lq1);
            uq0 = *(const float4*)(pU + o);  uq1 = *(const float4*)(pU + o + 4);
            tq0 = *(const float4*)(pT + o);  tq1 = *(const float4*)(pT + o + 4);
            mq0 = *(const float4*)(pM + o);  mq1 = *(const float4*)(pM + o + 4);
            gq0 = *(const float4*)(pG + o);  gq1 = *(const float4*)(pG + o + 4);
        }
        {
            f16x8 ah_[4], al_[4], bh_[2], bl_[2];
#pragma unroll
            for (int mi = 0; mi < 4; mi++) {
                const int r = wm * 64 + mi * 16 + fr;
                ah_[mi] = *(const f16x8*)&A1h[r][kq];
                al_[mi] = *(const f16x8*)&A1l[r][kq];
            }
#pragma unroll
            for (int ni = 0; ni < 2; ni++) {
                const int r = wn * 32 + ni * 16 + fr;
                bh_[ni] = *(const f16x8*)&Mh[r][kq];
                bl_[ni] = *(const f16x8*)&Ml[r][kq];
            }
#pragma unroll
            for (int mi = 0; mi < 4; mi++)
#pragma unroll
                for (int ni = 0; ni < 2; ni++) {
                    accM[mi][ni] = __builtin_amdgcn_mfma_f32_16x16x32_f16(ah_[mi], bh_[ni], accM[mi][ni], 0, 0, 0);
                    accM[mi][ni] = __builtin_amdgcn_mfma_f32_16x16x32_f16(ah_[mi], bl_[ni], accM[mi][ni], 0, 0, 0);
                    accM[mi][ni] = __builtin_amdgcn_mfma_f32_16x16x32_f16(al_[mi], bh_[ni], accM[mi][ni], 0, 0, 0);
                }
        }
        {
            f16x8 ah_[4], al_[4], bh_[2], bl_[2];
#pragma unroll
            for (int mi = 0; mi < 4; mi++) {
                const int r = wm * 64 + mi * 16 + fr;
                ah_[mi] = *(const f16x8*)&A2h[r][kq];
                al_[mi] = *(const f16x8*)&A2l[r][kq];
            }
#pragma unroll
            for (int ni = 0; ni < 2; ni++) {
                const int r = wn * 32 + ni * 16 + fr;
                bh_[ni] = *(const f16x8*)&Gh[r][kq];
                bl_[ni] = *(const f16x8*)&Gl[r][kq];
            }
#pragma unroll
            for (int mi = 0; mi < 4; mi++)
#pragma unroll
                for (int ni = 0; ni < 2; ni++) {
                    accA[mi][ni] = __builtin_amdgcn_mfma_f32_16x16x32_f16(ah_[mi], bh_[ni], accA[mi][ni], 0, 0, 0);
                    accA[mi][ni] = __builtin_amdgcn_mfma_f32_16x16x32_f16(ah_[mi], bl_[ni], accA[mi][ni], 0, 0, 0);
                    accA[mi][ni] = __builtin_amdgcn_mfma_f32_16x16x32_f16(al_[mi], bh_[ni], accA[mi][ni], 0, 0, 0);
                }
        }
    }

#pragma unroll
    for (int ni = 0; ni < 2; ni++) {
        const int col = col0 + wn * 32 + ni * 16 + fr;
        const float bm = bTm[col], bg = bTa[col];
#pragma unroll
        for (int mi = 0; mi < 4; mi++) {
            const int rb = row0 + wm * 64 + mi * 16 + ((lane >> 4) << 2);
#pragma unroll
            for (int r = 0; r < 4; r++) {
                const size_t idx = (size_t)(rb + r) * O_DIM + col;
                const float zm = accM[mi][ni][r] * WDESCALE + bm;
                const float za = accA[mi][ni][r] * WDESCALE + bg;
                const float ut = u_t[idx], bt = b_t[idx];
                const float sp = spk[idx];
                const float l1 = h2f(Lhp[idx]) + h2f(Llp[idx]);
                const float ea  = expf(-zm);
                const float rho = 1.0f / (1.0f + expf(-za));
                const float bn  = sp + rho * (bt - sp);
                const float thr = 0.01f + 1.8f * bn;
                const float un  = ut + (l1 - ut) * (1.0f + ea);
                const float d   = un - thr;
                out[idx] = d > 0.0f ? 1.0f : 0.0f;
                const float tol = 2e-4f + 1e-4f * ea * (1.0f + fabsf(l1 - ut))
                                + 2e-4f * fabsf(bt - sp);
                if (fabsf(d) < tol) {
                    const uint pos = atomicAdd(cnt, 1u);
                    if (pos < cap) list[pos] = (uint)idx;
                }
            }
        }
    }
}

// ===========================================================================
__global__ __launch_bounds__(256)
void lsnn_fixup(const ushort* __restrict__ Lhp, const ushort* __restrict__ Llp,
                const float* __restrict__ X, const float* __restrict__ Wsyn,
                const float* __restrict__ bsyn,
                const float* __restrict__ u_t, const float* __restrict__ b_t,
                const float* __restrict__ spk,
                const float* __restrict__ WTm, const float* __restrict__ bTm,
                const float* __restrict__ WTa, const float* __restrict__ bTa,
                const uint* __restrict__ cnt, const uint* __restrict__ list,
                uint cap, float* __restrict__ out) {
    const uint nc = *cnt;
    const uint n = nc < cap ? nc : cap;
    const int lane = threadIdx.x & 63;
    const uint wid = (blockIdx.x * blockDim.x + threadIdx.x) >> 6;
    const uint nw = (gridDim.x * blockDim.x) >> 6;

    for (uint e = wid; e < n; e += nw) {
        const uint idx = list[e];
        const int b = idx >> 11;
        const int o = idx & (O_DIM - 1);

        double l1 = 0.0, zm = 0.0, za = 0.0;
        const float* xr = X + (size_t)b * I_DIM;
        const float* wr = Wsyn + (size_t)o * I_DIM;
        for (int k = lane; k < I_DIM; k += 64)
            l1 = fma((double)xr[k], (double)wr[k], l1);

        const ushort* lhr = Lhp + (size_t)b * O_DIM;
        const ushort* llr = Llp + (size_t)b * O_DIM;
        const float* ur = u_t + (size_t)b * O_DIM;
        const float* tr = b_t + (size_t)b * O_DIM;
        const float* mr = WTm + (size_t)o * O_DIM;
        const float* ar = WTa + (size_t)o * O_DIM;
        for (int k = lane; k < O_DIM; k += 64) {
            const double l = (double)(h2f(lhr[k]) + h2f(llr[k]));
            zm = fma(l + (double)ur[k], (double)mr[k], zm);
            za = fma(l + (double)tr[k], (double)ar[k], za);
        }
#pragma unroll
        for (int off = 32; off > 0; off >>= 1) {
            l1 += __shfl_down(l1, off);
            zm += __shfl_down(zm, off);
            za += __shfl_down(za, off);
        }
        if (lane == 0) {
            l1 += (double)bsyn[o];
            zm += (double)bTm[o];
            za += (double)bTa[o];
            const double inv_alpha = 1.0 + exp(-zm);
            const double rho = 1.0 / (1.0 + exp(-za));
            const double bt = (double)b_t[idx];
            const double sp = (double)spk[idx];
            const double ut = (double)u_t[idx];
            const double b_new = sp + rho * (bt - sp);
            const double thr = 0.01 + 1.8 * b_new;
            const double u_new = ut + (l1 - ut) * inv_alpha;
            out[idx] = (u_new - thr > 0.0) ? 1.0f : 0.0f;
        }
    }
}

// ===========================================================================
extern "C" void kernel_launch(void* const* d_in, const int* in_sizes, int n_in,
                              void* d_out, int out_size, void* d_ws, size_t ws_size,
                              hipStream_t stream) {
    const float* x    = (const float*)d_in[0];
    const float* u_t  = (const float*)d_in[1];
    const float* b_t  = (const float*)d_in[2];
    const float* spk  = (const float*)d_in[3];
    const float* Wsyn = (const float*)d_in[4];
    const float* bsyn = (const float*)d_in[5];
    const float* WTm  = (const float*)d_in[6];
    const float* bTm  = (const float*)d_in[7];
    const float* WTa  = (const float*)d_in[8];
    const float* bTa  = (const float*)d_in[9];
    float* out = (float*)d_out;

    char* ws = (char*)d_ws;
    ushort* Lhp = (ushort*)(ws + 0 * MBYTE);
    ushort* Llp = (ushort*)(ws + 16 * MBYTE);
    ushort* Mhp = (ushort*)(ws + 32 * MBYTE);
    ushort* Wsh = (ushort*)(ws + 40 * MBYTE);
    ushort* Wsl = (ushort*)(ws + 48 * MBYTE);

    const bool tierA = ws_size >= 91 * MBYTE;
    const size_t flag_off = tierA ? 88 * MBYTE : 56 * MBYTE;
    if (ws_size < flag_off + (1u << 16)) return;

    ushort* Xh = (ushort*)(ws + 56 * MBYTE);
    ushort* Xl = (ushort*)(ws + 72 * MBYTE);
    uint* flag = (uint*)(ws + flag_off);
    uint* cnt  = (uint*)(ws + flag_off + 4);
    uint* list = (uint*)(ws + flag_off + 256);
    const uint cap = (uint)((ws_size - flag_off - 256) / sizeof(uint));

    (void)hipMemsetAsync(ws + flag_off, 0, 8, stream);
    prep<<<dim3(2048), dim3(256), 0, stream>>>(x, Wsyn, WTm, u_t, b_t, spk,
                                               Xh, Xl, Wsh, Wsl, Mhp, flag,
                                               tierA ? 1 : 0);
    if (tierA) {
        gemm1_c<<<dim3(512), dim3(512), 0, stream>>>(Xh, Xl, Wsh, Wsl, bsyn, Lhp, Llp);
    } else {
        gemm1_b<<<dim3(256), dim3(256), 0, stream>>>(x, Wsh, Wsl, bsyn, Lhp, Llp);
    }
    stage2_fast<<<dim3(512), dim3(256), 0, stream>>>(Lhp, Llp, Mhp, bTm,
                                                     out, flag, cnt, list, cap);
    stage2_slow<<<dim3(512), dim3(512), 0, stream>>>(Lhp, Llp, u_t, b_t, spk,
                                                     WTm, bTm, WTa, bTa,
                                                     out, flag, cnt, list, cap);
    lsnn_fixup<<<dim3(256), dim3(256), 0, stream>>>(Lhp, Llp, x, Wsyn, bsyn,
                                                    u_t, b_t, spk,
                                                    WTm, bTm, WTa, bTa,
                                                    cnt, list, cap, out);
}

// Round 14
// 249.229 us; speedup vs baseline: 1.0827x; 1.0385x over previous
//
#include <hip/hip_runtime.h>
#include <cmath>

#define B_DIM 4096
#define O_DIM 2048
#define I_DIM 2048

typedef _Float16 f16x8 __attribute__((ext_vector_type(8)));
typedef float f32x4 __attribute__((ext_vector_type(4)));
typedef unsigned int uint;
typedef unsigned short ushort;

#define WSCALE   64.0f
#define WDESCALE 0.015625f
#define MBYTE    ((size_t)1024 * 1024)

// ws layout:
// L1h 0..16M | L1l 16..32M | Mh 32..40M | Wsh 40..48M | Wsl 48..56M
// tier A adds: Xh 56..72M | Xl 72..88M ; flag at 88M (A) or 56M (B)

// Swizzled LDS tile: [rows][16 dwords]; 16B slot s: phys = s ^ ((r>>1)&3).
__device__ __forceinline__ int TP(int r, int s) {
    return r * 16 + (((s ^ ((r >> 1) & 3))) << 2);
}

__device__ __forceinline__ float h2f(ushort u) {
    _Float16 h = __builtin_bit_cast(_Float16, u);
    return (float)h;
}

__device__ __forceinline__ void gload16(const uint* src, uint* lds) {
    __builtin_amdgcn_global_load_lds(
        (const __attribute__((address_space(1))) void*)src,
        (__attribute__((address_space(3))) void*)lds, 16, 0, 0);
}

__device__ __forceinline__ void split8(const float4 a, const float4 b,
                                       uint4& hi, uint4& lo) {
    auto h0 = __builtin_amdgcn_cvt_pkrtz(a.x, a.y);
    auto h1 = __builtin_amdgcn_cvt_pkrtz(a.z, a.w);
    auto h2 = __builtin_amdgcn_cvt_pkrtz(b.x, b.y);
    auto h3 = __builtin_amdgcn_cvt_pkrtz(b.z, b.w);
    auto l0 = __builtin_amdgcn_cvt_pkrtz(a.x - (float)h0[0], a.y - (float)h0[1]);
    auto l1 = __builtin_amdgcn_cvt_pkrtz(a.z - (float)h1[0], a.w - (float)h1[1]);
    auto l2 = __builtin_amdgcn_cvt_pkrtz(b.x - (float)h2[0], b.y - (float)h2[1]);
    auto l3 = __builtin_amdgcn_cvt_pkrtz(b.z - (float)h3[0], b.w - (float)h3[1]);
    hi.x = __builtin_bit_cast(uint, h0); hi.y = __builtin_bit_cast(uint, h1);
    hi.z = __builtin_bit_cast(uint, h2); hi.w = __builtin_bit_cast(uint, h3);
    lo.x = __builtin_bit_cast(uint, l0); lo.y = __builtin_bit_cast(uint, l1);
    lo.z = __builtin_bit_cast(uint, l2); lo.w = __builtin_bit_cast(uint, l3);
}

__device__ __forceinline__ float4 add4(const float4 a, const float4 b) {
    return make_float4(a.x + b.x, a.y + b.y, a.z + b.z, a.w + b.w);
}
__device__ __forceinline__ float4 mul64(const float4 a) {
    return make_float4(a.x * WSCALE, a.y * WSCALE, a.z * WSCALE, a.w * WSCALE);
}
__device__ __forceinline__ void unpack8(const uint4 h, const uint4 l,
                                        float4& f0, float4& f1) {
    f0.x = h2f((ushort)(h.x & 0xffff)) + h2f((ushort)(l.x & 0xffff));
    f0.y = h2f((ushort)(h.x >> 16))    + h2f((ushort)(l.x >> 16));
    f0.z = h2f((ushort)(h.y & 0xffff)) + h2f((ushort)(l.y & 0xffff));
    f0.w = h2f((ushort)(h.y >> 16))    + h2f((ushort)(l.y >> 16));
    f1.x = h2f((ushort)(h.z & 0xffff)) + h2f((ushort)(l.z & 0xffff));
    f1.y = h2f((ushort)(h.z >> 16))    + h2f((ushort)(l.z >> 16));
    f1.z = h2f((ushort)(h.w & 0xffff)) + h2f((ushort)(l.w & 0xffff));
    f1.w = h2f((ushort)(h.w >> 16))    + h2f((ushort)(l.w >> 16));
}

// ===========================================================================
// prep: fused zcheck + split(x) + split(Wsyn*64) + split_hi(WTm*64)
// ===========================================================================
__global__ __launch_bounds__(256)
void prep(const float* __restrict__ x, const float* __restrict__ Wsyn,
          const float* __restrict__ WTm,
          const float* __restrict__ u, const float* __restrict__ b,
          const float* __restrict__ s,
          ushort* __restrict__ Xh, ushort* __restrict__ Xl,
          ushort* __restrict__ Wsh, ushort* __restrict__ Wsl,
          ushort* __restrict__ Mhp, uint* __restrict__ flag, int doX) {
    const uint NX = (uint)((size_t)B_DIM * I_DIM / 8);
    const uint NW = (uint)((size_t)O_DIM * I_DIM / 8);
    const uint NZ = (uint)((size_t)B_DIM * O_DIM / 8);
    const uint nx = doX ? NX : 0;
    const uint total = nx + 2 * NW + NZ;
    const uint stride = gridDim.x * blockDim.x;
    bool nz = false;
    for (uint t = blockIdx.x * blockDim.x + threadIdx.x; t < total; t += stride) {
        if (t < nx) {
            const size_t i = (size_t)t * 8;
            uint4 h, l;
            split8(*(const float4*)(x + i), *(const float4*)(x + i + 4), h, l);
            *(uint4*)(Xh + i) = h; *(uint4*)(Xl + i) = l;
        } else if (t < nx + NW) {
            const size_t i = (size_t)(t - nx) * 8;
            uint4 h, l;
            split8(mul64(*(const float4*)(Wsyn + i)),
                   mul64(*(const float4*)(Wsyn + i + 4)), h, l);
            *(uint4*)(Wsh + i) = h; *(uint4*)(Wsl + i) = l;
        } else if (t < nx + 2 * NW) {
            const size_t i = (size_t)(t - nx - NW) * 8;
            const float4 a = mul64(*(const float4*)(WTm + i));
            const float4 c = mul64(*(const float4*)(WTm + i + 4));
            auto h0 = __builtin_amdgcn_cvt_pkrtz(a.x, a.y);
            auto h1 = __builtin_amdgcn_cvt_pkrtz(a.z, a.w);
            auto h2 = __builtin_amdgcn_cvt_pkrtz(c.x, c.y);
            auto h3 = __builtin_amdgcn_cvt_pkrtz(c.z, c.w);
            uint4 h;
            h.x = __builtin_bit_cast(uint, h0); h.y = __builtin_bit_cast(uint, h1);
            h.z = __builtin_bit_cast(uint, h2); h.w = __builtin_bit_cast(uint, h3);
            *(uint4*)(Mhp + i) = h;
        } else {
            const size_t i = (size_t)(t - nx - 2 * NW) * 8;
            const float4 a0 = *(const float4*)(u + i), a1 = *(const float4*)(u + i + 4);
            const float4 b0 = *(const float4*)(b + i), b1 = *(const float4*)(b + i + 4);
            const float4 c0 = *(const float4*)(s + i), c1 = *(const float4*)(s + i + 4);
            nz |= (a0.x != 0.f) | (a0.y != 0.f) | (a0.z != 0.f) | (a0.w != 0.f);
            nz |= (a1.x != 0.f) | (a1.y != 0.f) | (a1.z != 0.f) | (a1.w != 0.f);
            nz |= (b0.x != 0.f) | (b0.y != 0.f) | (b0.z != 0.f) | (b0.w != 0.f);
            nz |= (b1.x != 0.f) | (b1.y != 0.f) | (b1.z != 0.f) | (b1.w != 0.f);
            nz |= (c0.x != 0.f) | (c0.y != 0.f) | (c0.z != 0.f) | (c0.w != 0.f);
            nz |= (c1.x != 0.f) | (c1.y != 0.f) | (c1.z != 0.f) | (c1.w != 0.f);
        }
    }
    if (nz) atomicOr(flag, 1u);
}

// ===========================================================================
// GEMM1 tier A (gemm1_d): 128x256 tile, 1024 thr (16 waves, 64x32 each,
// 4 waves/SIMD), 3-deep LDS pipeline (144 KB) with counted vmcnt
// (gemm1_c's validated protocol; 3 gload16/thread/tile, wait vmcnt(3)).
// per buf 12288 dwords: Ah [0,2048) | Al [2048,4096) | Bh [4096,8192) |
// Bl [8192,12288).
// ===========================================================================
__global__ __launch_bounds__(1024)
void gemm1_d(const ushort* __restrict__ Xh, const ushort* __restrict__ Xl,
             const ushort* __restrict__ Wh, const ushort* __restrict__ Wl,
             const float* __restrict__ bias,
             ushort* __restrict__ Lh, ushort* __restrict__ Ll) {
    __shared__ uint S[3][12288];   // 144 KB

    const int tid = threadIdx.x;
    const int lane = tid & 63;
    const int wid = tid >> 6;               // 0..15
    const int wm = wid >> 3;                // 0..1 (rows, *64)
    const int wn = wid & 7;                 // 0..7 (cols, *32)

    int sid = blockIdx.x;
    sid = (sid & 7) * 32 + (sid >> 3);      // XCD swizzle (256 % 8 == 0)
    const int bx = sid & 7, by = sid >> 3;  // 8 N-tiles, 32 M-tiles
    const int row0 = by * 128, col0 = bx * 256;

    // 48 chunks: 0..7 Ah | 8..15 Al | 16..31 Bh | 32..47 Bl.
    // chunk local slot g = local*64+lane; row r = g>>2; logical 16B slot
    // q = (g&3)^((r>>1)&3)  (inverse of TP read swizzle).
    const uint* src[3];
    int dbase[3];
#pragma unroll
    for (int i = 0; i < 3; i++) {
        const int ch = wid * 3 + i;
        const ushort* plane;
        int local, pbase, grow0;
        if (ch < 8)       { plane = Xh; local = ch;      pbase = 0;    grow0 = row0; }
        else if (ch < 16) { plane = Xl; local = ch - 8;  pbase = 2048; grow0 = row0; }
        else if (ch < 32) { plane = Wh; local = ch - 16; pbase = 4096; grow0 = col0; }
        else              { plane = Wl; local = ch - 32; pbase = 8192; grow0 = col0; }
        const int g = local * 64 + lane;
        const int r = g >> 2, q = (g & 3) ^ ((r >> 1) & 3);
        dbase[i] = pbase + local * 256;
        src[i] = (const uint*)plane + (size_t)(grow0 + r) * 1024 + q * 4;
    }

    f32x4 acc[4][2];
#pragma unroll
    for (int i = 0; i < 4; i++)
#pragma unroll
        for (int j = 0; j < 2; j++)
#pragma unroll
            for (int r = 0; r < 4; r++) acc[i][j][r] = 0.0f;

    const int fr = lane & 15;
    const int sl = lane >> 4;
    const int NT = I_DIM / 32;              // 64

    // prologue: 2 tiles in flight (6 outstanding loads/thread)
#pragma unroll
    for (int i = 0; i < 3; i++) gload16(src[i], &S[0][dbase[i]]);
#pragma unroll
    for (int i = 0; i < 3; i++) gload16(src[i] + 16, &S[1][dbase[i]]);

    for (int t = 0; t < NT; t++) {
        if (t + 1 < NT) {
            asm volatile("s_waitcnt vmcnt(3)" ::: "memory");
        } else {
            asm volatile("s_waitcnt vmcnt(0)" ::: "memory");
        }
        asm volatile("s_barrier" ::: "memory");
        if (t + 2 < NT) {
            const int ko = (t + 2) * 16;
            uint* Sd = &S[(t + 2) % 3][0];
#pragma unroll
            for (int i = 0; i < 3; i++) gload16(src[i] + ko, &Sd[dbase[i]]);
        }
        const uint* Sc = &S[t % 3][0];
        f16x8 ah_[4], al_[4], bh_[2], bl_[2];
#pragma unroll
        for (int mi = 0; mi < 4; mi++) {
            const int r = wm * 64 + mi * 16 + fr;       // < 128
            ah_[mi] = *(const f16x8*)&Sc[TP(r, sl)];
            al_[mi] = *(const f16x8*)&Sc[2048 + TP(r, sl)];
        }
#pragma unroll
        for (int ni = 0; ni < 2; ni++) {
            const int r = wn * 32 + ni * 16 + fr;       // < 256
            bh_[ni] = *(const f16x8*)&Sc[4096 + TP(r, sl)];
            bl_[ni] = *(const f16x8*)&Sc[8192 + TP(r, sl)];
        }
#pragma unroll
        for (int mi = 0; mi < 4; mi++)
#pragma unroll
            for (int ni = 0; ni < 2; ni++) {
                acc[mi][ni] = __builtin_amdgcn_mfma_f32_16x16x32_f16(ah_[mi], bh_[ni], acc[mi][ni], 0, 0, 0);
                acc[mi][ni] = __builtin_amdgcn_mfma_f32_16x16x32_f16(ah_[mi], bl_[ni], acc[mi][ni], 0, 0, 0);
                acc[mi][ni] = __builtin_amdgcn_mfma_f32_16x16x32_f16(al_[mi], bh_[ni], acc[mi][ni], 0, 0, 0);
            }
    }

    // epilogue: descale+bias, split to planes (validated pattern, [4][2])
#pragma unroll
    for (int ni = 0; ni < 2; ni++) {
        const int col = col0 + wn * 32 + ni * 16 + fr;
        const float bv = bias[col];
#pragma unroll
        for (int mi = 0; mi < 4; mi++) {
            const int rb = row0 + wm * 64 + mi * 16 + ((lane >> 4) << 2);
            float e[4];
#pragma unroll
            for (int r = 0; r < 4; r++) e[r] = acc[mi][ni][r] * WDESCALE + bv;
            auto hp0 = __builtin_amdgcn_cvt_pkrtz(e[0], e[1]);
            auto hp1 = __builtin_amdgcn_cvt_pkrtz(e[2], e[3]);
            auto lp0 = __builtin_amdgcn_cvt_pkrtz(e[0] - (float)hp0[0], e[1] - (float)hp0[1]);
            auto lp1 = __builtin_amdgcn_cvt_pkrtz(e[2] - (float)hp1[0], e[3] - (float)hp1[1]);
            const uint uh0 = __builtin_bit_cast(uint, hp0);
            const uint uh1 = __builtin_bit_cast(uint, hp1);
            const uint ul0 = __builtin_bit_cast(uint, lp0);
            const uint ul1 = __builtin_bit_cast(uint, lp1);
            Lh[(size_t)(rb + 0) * O_DIM + col] = (ushort)(uh0 & 0xffff);
            Lh[(size_t)(rb + 1) * O_DIM + col] = (ushort)(uh0 >> 16);
            Lh[(size_t)(rb + 2) * O_DIM + col] = (ushort)(uh1 & 0xffff);
            Lh[(size_t)(rb + 3) * O_DIM + col] = (ushort)(uh1 >> 16);
            Ll[(size_t)(rb + 0) * O_DIM + col] = (ushort)(ul0 & 0xffff);
            Ll[(size_t)(rb + 1) * O_DIM + col] = (ushort)(ul0 >> 16);
            Ll[(size_t)(rb + 2) * O_DIM + col] = (ushort)(ul1 & 0xffff);
            Ll[(size_t)(rb + 3) * O_DIM + col] = (ushort)(ul1 >> 16);
        }
    }
}

// ===========================================================================
// GEMM1 tier B: Wsyn pre-split (gload16), X split in-loop (unchanged).
// ===========================================================================
__global__ __launch_bounds__(256)
void gemm1_b(const float* __restrict__ X,
             const ushort* __restrict__ Wh, const ushort* __restrict__ Wl,
             const float* __restrict__ bias,
             ushort* __restrict__ Lh, ushort* __restrict__ Ll) {
    __shared__ uint S[8192];

    const int tid = threadIdx.x;
    const int lane = tid & 63;
    const int wid = tid >> 6;
    const int wm = wid >> 1, wn = wid & 1;

    int sid = blockIdx.x;
    sid = (sid & 7) * 64 + (sid >> 3);
    const int bx = sid & 15, by = sid >> 4;
    const int row0 = by * 128, col0 = bx * 128;

    const int sr = tid >> 1;
    const int kh = (tid & 1) * 16;
    const int s0 = (tid & 1) * 2;
    const float* pA = X + (size_t)(row0 + sr) * I_DIM + kh;

    int r0, q0, r1, q1;
    {
        const int g0 = (wid * 2 + 0) * 64 + lane;
        const int g1 = (wid * 2 + 1) * 64 + lane;
        r0 = g0 >> 2; q0 = (g0 & 3) ^ ((r0 >> 1) & 3);
        r1 = g1 >> 2; q1 = (g1 & 3) ^ ((r1 >> 1) & 3);
    }
    const uint* sWh0 = (const uint*)Wh + (size_t)(col0 + r0) * 1024 + q0 * 4;
    const uint* sWh1 = (const uint*)Wh + (size_t)(col0 + r1) * 1024 + q1 * 4;
    const uint* sWl0 = (const uint*)Wl + (size_t)(col0 + r0) * 1024 + q0 * 4;
    const uint* sWl1 = (const uint*)Wl + (size_t)(col0 + r1) * 1024 + q1 * 4;
    const int c0 = (wid * 2 + 0) << 8;
    const int c1 = (wid * 2 + 1) << 8;

    f32x4 acc[4][4];
#pragma unroll
    for (int i = 0; i < 4; i++)
#pragma unroll
        for (int j = 0; j < 4; j++)
#pragma unroll
            for (int r = 0; r < 4; r++) acc[i][j][r] = 0.0f;

    const int fr = lane & 15;
    const int sl = lane >> 4;
    const int NT = I_DIM / 32;

    float4 a0 = *(const float4*)(pA + 0), a1 = *(const float4*)(pA + 4);
    float4 a2 = *(const float4*)(pA + 8), a3 = *(const float4*)(pA + 12);
    uint4 xh0, xl0, xh1, xl1;
    split8(a0, a1, xh0, xl0);
    split8(a2, a3, xh1, xl1);

    for (int t = 0; t < NT; t++) {
        __syncthreads();
        *(uint4*)&S[TP(sr, s0)] = xh0;         *(uint4*)&S[TP(sr, s0 + 1)] = xh1;
        *(uint4*)&S[2048 + TP(sr, s0)] = xl0;  *(uint4*)&S[2048 + TP(sr, s0 + 1)] = xl1;
        const int ko = t * 16;
        gload16(sWh0 + ko, &S[4096 + c0]);  gload16(sWh1 + ko, &S[4096 + c1]);
        gload16(sWl0 + ko, &S[6144 + c0]);  gload16(sWl1 + ko, &S[6144 + c1]);
        __syncthreads();
        if (t + 1 < NT) {
            const float* nA = pA + (t + 1) * 32;
            a0 = *(const float4*)(nA + 0); a1 = *(const float4*)(nA + 4);
            a2 = *(const float4*)(nA + 8); a3 = *(const float4*)(nA + 12);
        }
        f16x8 ah_[4], al_[4], bh_[4], bl_[4];
#pragma unroll
        for (int mi = 0; mi < 4; mi++) {
            const int r = wm * 64 + mi * 16 + fr;
            ah_[mi] = *(const f16x8*)&S[TP(r, sl)];
            al_[mi] = *(const f16x8*)&S[2048 + TP(r, sl)];
        }
#pragma unroll
        for (int ni = 0; ni < 4; ni++) {
            const int r = wn * 64 + ni * 16 + fr;
            bh_[ni] = *(const f16x8*)&S[4096 + TP(r, sl)];
            bl_[ni] = *(const f16x8*)&S[6144 + TP(r, sl)];
        }
#pragma unroll
        for (int mi = 0; mi < 4; mi++)
#pragma unroll
            for (int ni = 0; ni < 4; ni++) {
                acc[mi][ni] = __builtin_amdgcn_mfma_f32_16x16x32_f16(ah_[mi], bh_[ni], acc[mi][ni], 0, 0, 0);
                acc[mi][ni] = __builtin_amdgcn_mfma_f32_16x16x32_f16(ah_[mi], bl_[ni], acc[mi][ni], 0, 0, 0);
                acc[mi][ni] = __builtin_amdgcn_mfma_f32_16x16x32_f16(al_[mi], bh_[ni], acc[mi][ni], 0, 0, 0);
            }
        if (t + 1 < NT) {
            split8(a0, a1, xh0, xl0);
            split8(a2, a3, xh1, xl1);
        }
    }

    const int fr2 = lane & 15;
#pragma unroll
    for (int ni = 0; ni < 4; ni++) {
        const int col = col0 + wn * 64 + ni * 16 + fr2;
        const float bv = bias[col];
#pragma unroll
        for (int mi = 0; mi < 4; mi++) {
            const int rb = row0 + wm * 64 + mi * 16 + ((lane >> 4) << 2);
            float e[4];
#pragma unroll
            for (int r = 0; r < 4; r++) e[r] = acc[mi][ni][r] * WDESCALE + bv;
            auto hp0 = __builtin_amdgcn_cvt_pkrtz(e[0], e[1]);
            auto hp1 = __builtin_amdgcn_cvt_pkrtz(e[2], e[3]);
            auto lp0 = __builtin_amdgcn_cvt_pkrtz(e[0] - (float)hp0[0], e[1] - (float)hp0[1]);
            auto lp1 = __builtin_amdgcn_cvt_pkrtz(e[2] - (float)hp1[0], e[3] - (float)hp1[1]);
            const uint uh0 = __builtin_bit_cast(uint, hp0);
            const uint uh1 = __builtin_bit_cast(uint, hp1);
            const uint ul0 = __builtin_bit_cast(uint, lp0);
            const uint ul1 = __builtin_bit_cast(uint, lp1);
            Lh[(size_t)(rb + 0) * O_DIM + col] = (ushort)(uh0 & 0xffff);
            Lh[(size_t)(rb + 1) * O_DIM + col] = (ushort)(uh0 >> 16);
            Lh[(size_t)(rb + 2) * O_DIM + col] = (ushort)(uh1 & 0xffff);
            Lh[(size_t)(rb + 3) * O_DIM + col] = (ushort)(uh1 >> 16);
            Ll[(size_t)(rb + 0) * O_DIM + col] = (ushort)(ul0 & 0xffff);
            Ll[(size_t)(rb + 1) * O_DIM + col] = (ushort)(ul0 >> 16);
            Ll[(size_t)(rb + 2) * O_DIM + col] = (ushort)(ul1 & 0xffff);
            Ll[(size_t)(rb + 3) * O_DIM + col] = (ushort)(ul1 >> 16);
        }
    }
}

// ===========================================================================
// Stage-2 FAST: 128x128 tile, 4 waves of 64x64, 3-deep counted-vmcnt
// pipeline (validated round 13). LDS 48 KB. Two-pass LDS-transpose epilogue.
// ===========================================================================
__global__ __launch_bounds__(256)
void stage2_fast(const ushort* __restrict__ Lhp, const ushort* __restrict__ Llp,
                 const ushort* __restrict__ Mhp,
                 const float* __restrict__ bTm, float* __restrict__ out,
                 const uint* __restrict__ flag,
                 uint* __restrict__ cnt, uint* __restrict__ list, uint cap) {
    if (*flag != 0) return;

    __shared__ uint S[3][4096];   // 48 KB

    const int tid = threadIdx.x;
    const int lane = tid & 63;
    const int wid = tid >> 6;
    const int wm = wid >> 1, wn = wid & 1;

    int sid = blockIdx.x;
    sid = (sid & 7) * 64 + (sid >> 3);
    const int bx = sid & 15, by = sid >> 4;
    const int row0 = by * 128, col0 = bx * 128;

    const uint* srcL0; const uint* srcL1; const uint* srcM0; const uint* srcM1;
    {
        const int g0 = (wid * 2 + 0) * 64 + lane;
        const int g1 = (wid * 2 + 1) * 64 + lane;
        const int r0 = g0 >> 2, q0 = (g0 & 3) ^ ((r0 >> 1) & 3);
        const int r1 = g1 >> 2, q1 = (g1 & 3) ^ ((r1 >> 1) & 3);
        srcL0 = (const uint*)Lhp + (size_t)(row0 + r0) * 1024 + q0 * 4;
        srcL1 = (const uint*)Lhp + (size_t)(row0 + r1) * 1024 + q1 * 4;
        srcM0 = (const uint*)Mhp + (size_t)(col0 + r0) * 1024 + q0 * 4;
        srcM1 = (const uint*)Mhp + (size_t)(col0 + r1) * 1024 + q1 * 4;
    }
    const int c0 = (wid * 2 + 0) << 8;
    const int c1 = (wid * 2 + 1) << 8;

    f32x4 acc[4][4];
#pragma unroll
    for (int i = 0; i < 4; i++)
#pragma unroll
        for (int j = 0; j < 4; j++)
#pragma unroll
            for (int r = 0; r < 4; r++) acc[i][j][r] = 0.0f;

    const int fr = lane & 15;
    const int sl = lane >> 4;
    const int NT = O_DIM / 32;

    gload16(srcL0, &S[0][c0]);         gload16(srcL1, &S[0][c1]);
    gload16(srcM0, &S[0][2048 + c0]);  gload16(srcM1, &S[0][2048 + c1]);
    gload16(srcL0 + 16, &S[1][c0]);        gload16(srcL1 + 16, &S[1][c1]);
    gload16(srcM0 + 16, &S[1][2048 + c0]); gload16(srcM1 + 16, &S[1][2048 + c1]);

    for (int t = 0; t < NT; t++) {
        if (t + 1 < NT) {
            asm volatile("s_waitcnt vmcnt(4)" ::: "memory");
        } else {
            asm volatile("s_waitcnt vmcnt(0)" ::: "memory");
        }
        asm volatile("s_barrier" ::: "memory");
        if (t + 2 < NT) {
            const int ko = (t + 2) * 16;
            uint* Sd = &S[(t + 2) % 3][0];
            gload16(srcL0 + ko, &Sd[c0]);         gload16(srcL1 + ko, &Sd[c1]);
            gload16(srcM0 + ko, &Sd[2048 + c0]);  gload16(srcM1 + ko, &Sd[2048 + c1]);
        }
        const uint* Sc = &S[t % 3][0];
        f16x8 lh_[4], mh_[4];
#pragma unroll
        for (int mi = 0; mi < 4; mi++)
            lh_[mi] = *(const f16x8*)&Sc[TP(wm * 64 + mi * 16 + fr, sl)];
#pragma unroll
        for (int ni = 0; ni < 4; ni++)
            mh_[ni] = *(const f16x8*)&Sc[2048 + TP(wn * 64 + ni * 16 + fr, sl)];
#pragma unroll
        for (int mi = 0; mi < 4; mi++)
#pragma unroll
            for (int ni = 0; ni < 4; ni++)
                acc[mi][ni] = __builtin_amdgcn_mfma_f32_16x16x32_f16(lh_[mi], mh_[ni], acc[mi][ni], 0, 0, 0);
    }
    __syncthreads();

    float* Sf = (float*)&S[0][0];
    float bmv[4];
#pragma unroll
    for (int ni = 0; ni < 4; ni++)
        bmv[ni] = bTm[col0 + wn * 64 + ni * 16 + fr];

    const int erow = tid >> 1;
    const int ecg  = tid & 1;

#pragma unroll
    for (int h = 0; h < 2; h++) {
        if (h) __syncthreads();
#pragma unroll
        for (int ni2 = 0; ni2 < 2; ni2++) {
            const int ni = h * 2 + ni2;
#pragma unroll
            for (int mi = 0; mi < 4; mi++) {
                const int rbL = wm * 64 + mi * 16 + ((lane >> 4) << 2);
#pragma unroll
                for (int r = 0; r < 4; r++) {
                    const int row = rbL + r;
                    const int cm = wn * 32 + ni2 * 16 + fr;
                    const int phys = (cm + ((row >> 2) & 3) * 16 + (row & 3) * 4) & 63;
                    Sf[row * 64 + phys] = acc[mi][ni][r] * WDESCALE + bmv[ni];
                }
            }
        }
        __syncthreads();
        const int rsw = ((erow >> 2) & 3) * 16 + (erow & 3) * 4;
        float z[32];
#pragma unroll
        for (int j = 0; j < 8; j++) {
            const int phys = (ecg * 32 + j * 4 + rsw) & 63;
            *(float4*)&z[j * 4] = *(const float4*)&Sf[erow * 64 + phys];
        }
        const int colBase = col0 + ecg * 64 + h * 32;
        const size_t idx0 = (size_t)(row0 + erow) * O_DIM + colBase;
        uint4 lh4[4], ll4[4];
#pragma unroll
        for (int j = 0; j < 4; j++) {
            lh4[j] = ((const uint4*)(Lhp + idx0))[j];
            ll4[j] = ((const uint4*)(Llp + idx0))[j];
        }
        float ov[32];
#pragma unroll
        for (int m = 0; m < 32; m++) {
            const uint hu = ((const uint*)lh4)[m >> 1];
            const uint lu = ((const uint*)ll4)[m >> 1];
            const ushort hs = (m & 1) ? (ushort)(hu >> 16) : (ushort)(hu & 0xffff);
            const ushort ls = (m & 1) ? (ushort)(lu >> 16) : (ushort)(lu & 0xffff);
            const float l1 = h2f(hs) + h2f(ls);
            const float zm = z[m];
            const float ea = expf(-zm);
            const float d = l1 * (1.0f + ea) - 0.01f;
            ov[m] = d > 0.0f ? 1.0f : 0.0f;
            const float tol = 2e-4f + 1e-4f * ea * (1.0f + fabsf(l1));
            if (fabsf(d) < tol) {
                const uint pos = atomicAdd(cnt, 1u);
                if (pos < cap) list[pos] = (uint)(idx0 + m);
            }
        }
#pragma unroll
        for (int j = 0; j < 8; j++)
            *(float4*)(out + idx0 + j * 4) = *(const float4*)&ov[j * 4];
    }
}

// ===========================================================================
// Stage-2 SLOW path (general inputs) — unchanged.
// ===========================================================================
__global__ __launch_bounds__(512)
void stage2_slow(const ushort* __restrict__ Lhp, const ushort* __restrict__ Llp,
                 const float* __restrict__ u_t, const float* __restrict__ b_t,
                 const float* __restrict__ spk,
                 const float* __restrict__ WTm, const float* __restrict__ bTm,
                 const float* __restrict__ WTa, const float* __restrict__ bTa,
                 float* __restrict__ out, const uint* __restrict__ flag,
                 uint* __restrict__ cnt, uint* __restrict__ list, uint cap) {
    if (*flag == 0) return;

    __shared__ uint A1h[128][20], A1l[128][20], A2h[128][20], A2l[128][20];
    __shared__ uint Mh[128][20],  Ml[128][20],  Gh[128][20],  Gl[128][20];

    const int tid = threadIdx.x;
    const int lane = tid & 63;
    const int wid = tid >> 6;
    const int wm = wid >> 2;
    const int wn = wid & 3;

    int sid = blockIdx.x;
    sid = (sid & 7) * 64 + (sid >> 3);
    const int bx = sid & 15, by = sid >> 4;
    const int row0 = by * 128, col0 = bx * 128;

    const int srow = tid >> 2;
    const int skb = (tid & 3) * 8;
    const int swc = (tid & 3) * 4;

    const size_t aoff = (size_t)(row0 + srow) * O_DIM + skb;
    const float* pU = u_t + aoff;
    const float* pT = b_t + aoff;
    const float* pM = WTm + (size_t)(col0 + srow) * O_DIM + skb;
    const float* pG = WTa + (size_t)(col0 + srow) * O_DIM + skb;

    f32x4 accM[4][2], accA[4][2];
#pragma unroll
    for (int i = 0; i < 4; i++)
#pragma unroll
        for (int j = 0; j < 2; j++)
#pragma unroll
            for (int r = 0; r < 4; r++) { accM[i][j][r] = 0.0f; accA[i][j][r] = 0.0f; }

    float4 lq0, lq1;
    {
        const uint4 LH = *(const uint4*)(Lhp + aoff);
        const uint4 LL = *(const uint4*)(Llp + aoff);
        unpack8(LH, LL, lq0, lq1);
    }
    float4 uq0 = *(const float4*)(pU + 0), uq1 = *(const float4*)(pU + 4);
    float4 tq0 = *(const float4*)(pT + 0), tq1 = *(const float4*)(pT + 4);
    float4 mq0 = *(const float4*)(pM + 0), mq1 = *(const float4*)(pM + 4);
    float4 gq0 = *(const float4*)(pG + 0), gq1 = *(const float4*)(pG + 4);

    const int fr = lane & 15;
    const int kq = (lane >> 4) * 4;

    for (int t = 0; t < O_DIM / 32; t++) {
        uint4 A1hi, A1lo, A2hi, A2lo, Mhi, Mlo, Ghi, Glo;
        split8(add4(lq0, uq0), add4(lq1, uq1), A1hi, A1lo);
        split8(add4(lq0, tq0), add4(lq1, tq1), A2hi, A2lo);
        split8(mul64(mq0), mul64(mq1), Mhi, Mlo);
        split8(mul64(gq0), mul64(gq1), Ghi, Glo);
        __syncthreads();
        *(uint4*)&A1h[srow][swc] = A1hi;  *(uint4*)&A1l[srow][swc] = A1lo;
        *(uint4*)&A2h[srow][swc] = A2hi;  *(uint4*)&A2l[srow][swc] = A2lo;
        *(uint4*)&Mh[srow][swc]  = Mhi;   *(uint4*)&Ml[srow][swc]  = Mlo;
        *(uint4*)&Gh[srow][swc]  = Ghi;   *(uint4*)&Gl[srow][swc]  = Glo;
        __syncthreads();
        if (t + 1 < O_DIM / 32) {
            const int o = (t + 1) * 32;
            const uint4 LH = *(const uint4*)(Lhp + aoff + o);
            const uint4 LL = *(const uint4*)(Llp + aoff + o);
            unpack8(LH, LL, lq0, lq1);
            uq0 = *(const float4*)(pU + o);  uq1 = *(const float4*)(pU + o + 4);
            tq0 = *(const float4*)(pT + o);  tq1 = *(const float4*)(pT + o + 4);
            mq0 = *(const float4*)(pM + o);  mq1 = *(const float4*)(pM + o + 4);
            gq0 = *(const float4*)(pG + o);  gq1 = *(const float4*)(pG + o + 4);
        }
        {
            f16x8 ah_[4], al_[4], bh_[2], bl_[2];
#pragma unroll
            for (int mi = 0; mi < 4; mi++) {
                const int r = wm * 64 + mi * 16 + fr;
                ah_[mi] = *(const f16x8*)&A1h[r][kq];
                al_[mi] = *(const f16x8*)&A1l[r][kq];
            }
#pragma unroll
            for (int ni = 0; ni < 2; ni++) {
                const int r = wn * 32 + ni * 16 + fr;
                bh_[ni] = *(const f16x8*)&Mh[r][kq];
                bl_[ni] = *(const f16x8*)&Ml[r][kq];
            }
#pragma unroll
            for (int mi = 0; mi < 4; mi++)
#pragma unroll
                for (int ni = 0; ni < 2; ni++) {
                    accM[mi][ni] = __builtin_amdgcn_mfma_f32_16x16x32_f16(ah_[mi], bh_[ni], accM[mi][ni], 0, 0, 0);
                    accM[mi][ni] = __builtin_amdgcn_mfma_f32_16x16x32_f16(ah_[mi], bl_[ni], accM[mi][ni], 0, 0, 0);
                    accM[mi][ni] = __builtin_amdgcn_mfma_f32_16x16x32_f16(al_[mi], bh_[ni], accM[mi][ni], 0, 0, 0);
                }
        }
        {
            f16x8 ah_[4], al_[4], bh_[2], bl_[2];
#pragma unroll
            for (int mi = 0; mi < 4; mi++) {
                const int r = wm * 64 + mi * 16 + fr;
                ah_[mi] = *(const f16x8*)&A2h[r][kq];
                al_[mi] = *(const f16x8*)&A2l[r][kq];
            }
#pragma unroll
            for (int ni = 0; ni < 2; ni++) {
                const int r = wn * 32 + ni * 16 + fr;
                bh_[ni] = *(const f16x8*)&Gh[r][kq];
                bl_[ni] = *(const f16x8*)&Gl[r][kq];
            }
#pragma unroll
            for (int mi = 0; mi < 4; mi++)
#pragma unroll
                for (int ni = 0; ni < 2; ni++) {
                    accA[mi][ni] = __builtin_amdgcn_mfma_f32_16x16x32_f16(ah_[mi], bh_[ni], accA[mi][ni], 0, 0, 0);
                    accA[mi][ni] = __builtin_amdgcn_mfma_f32_16x16x32_f16(ah_[mi], bl_[ni], accA[mi][ni], 0, 0, 0);
                    accA[mi][ni] = __builtin_amdgcn_mfma_f32_16x16x32_f16(al_[mi], bh_[ni], accA[mi][ni], 0, 0, 0);
                }
        }
    }

#pragma unroll
    for (int ni = 0; ni < 2; ni++) {
        const int col = col0 + wn * 32 + ni * 16 + fr;
        const float bm = bTm[col], bg = bTa[col];
#pragma unroll
        for (int mi = 0; mi < 4; mi++) {
            const int rb = row0 + wm * 64 + mi * 16 + ((lane >> 4) << 2);
#pragma unroll
            for (int r = 0; r < 4; r++) {
                const size_t idx = (size_t)(rb + r) * O_DIM + col;
                const float zm = accM[mi][ni][r] * WDESCALE + bm;
                const float za = accA[mi][ni][r] * WDESCALE + bg;
                const float ut = u_t[idx], bt = b_t[idx];
                const float sp = spk[idx];
                const float l1 = h2f(Lhp[idx]) + h2f(Llp[idx]);
                const float ea  = expf(-zm);
                const float rho = 1.0f / (1.0f + expf(-za));
                const float bn  = sp + rho * (bt - sp);
                const float thr = 0.01f + 1.8f * bn;
                const float un  = ut + (l1 - ut) * (1.0f + ea);
                const float d   = un - thr;
                out[idx] = d > 0.0f ? 1.0f : 0.0f;
                const float tol = 2e-4f + 1e-4f * ea * (1.0f + fabsf(l1 - ut))
                                + 2e-4f * fabsf(bt - sp);
                if (fabsf(d) < tol) {
                    const uint pos = atomicAdd(cnt, 1u);
                    if (pos < cap) list[pos] = (uint)idx;
                }
            }
        }
    }
}

// ===========================================================================
__global__ __launch_bounds__(256)
void lsnn_fixup(const ushort* __restrict__ Lhp, const ushort* __restrict__ Llp,
                const float* __restrict__ X, const float* __restrict__ Wsyn,
                const float* __restrict__ bsyn,
                const float* __restrict__ u_t, const float* __restrict__ b_t,
                const float* __restrict__ spk,
                const float* __restrict__ WTm, const float* __restrict__ bTm,
                const float* __restrict__ WTa, const float* __restrict__ bTa,
                const uint* __restrict__ cnt, const uint* __restrict__ list,
                uint cap, float* __restrict__ out) {
    const uint nc = *cnt;
    const uint n = nc < cap ? nc : cap;
    const int lane = threadIdx.x & 63;
    const uint wid = (blockIdx.x * blockDim.x + threadIdx.x) >> 6;
    const uint nw = (gridDim.x * blockDim.x) >> 6;

    for (uint e = wid; e < n; e += nw) {
        const uint idx = list[e];
        const int b = idx >> 11;
        const int o = idx & (O_DIM - 1);

        double l1 = 0.0, zm = 0.0, za = 0.0;
        const float* xr = X + (size_t)b * I_DIM;
        const float* wr = Wsyn + (size_t)o * I_DIM;
        for (int k = lane; k < I_DIM; k += 64)
            l1 = fma((double)xr[k], (double)wr[k], l1);

        const ushort* lhr = Lhp + (size_t)b * O_DIM;
        const ushort* llr = Llp + (size_t)b * O_DIM;
        const float* ur = u_t + (size_t)b * O_DIM;
        const float* tr = b_t + (size_t)b * O_DIM;
        const float* mr = WTm + (size_t)o * O_DIM;
        const float* ar = WTa + (size_t)o * O_DIM;
        for (int k = lane; k < O_DIM; k += 64) {
            const double l = (double)(h2f(lhr[k]) + h2f(llr[k]));
            zm = fma(l + (double)ur[k], (double)mr[k], zm);
            za = fma(l + (double)tr[k], (double)ar[k], za);
        }
#pragma unroll
        for (int off = 32; off > 0; off >>= 1) {
            l1 += __shfl_down(l1, off);
            zm += __shfl_down(zm, off);
            za += __shfl_down(za, off);
        }
        if (lane == 0) {
            l1 += (double)bsyn[o];
            zm += (double)bTm[o];
            za += (double)bTa[o];
            const double inv_alpha = 1.0 + exp(-zm);
            const double rho = 1.0 / (1.0 + exp(-za));
            const double bt = (double)b_t[idx];
            const double sp = (double)spk[idx];
            const double ut = (double)u_t[idx];
            const double b_new = sp + rho * (bt - sp);
            const double thr = 0.01 + 1.8 * b_new;
            const double u_new = ut + (l1 - ut) * inv_alpha;
            out[idx] = (u_new - thr > 0.0) ? 1.0f : 0.0f;
        }
    }
}

// ===========================================================================
extern "C" void kernel_launch(void* const* d_in, const int* in_sizes, int n_in,
                              void* d_out, int out_size, void* d_ws, size_t ws_size,
                              hipStream_t stream) {
    const float* x    = (const float*)d_in[0];
    const float* u_t  = (const float*)d_in[1];
    const float* b_t  = (const float*)d_in[2];
    const float* spk  = (const float*)d_in[3];
    const float* Wsyn = (const float*)d_in[4];
    const float* bsyn = (const float*)d_in[5];
    const float* WTm  = (const float*)d_in[6];
    const float* bTm  = (const float*)d_in[7];
    const float* WTa  = (const float*)d_in[8];
    const float* bTa  = (const float*)d_in[9];
    float* out = (float*)d_out;

    char* ws = (char*)d_ws;
    ushort* Lhp = (ushort*)(ws + 0 * MBYTE);
    ushort* Llp = (ushort*)(ws + 16 * MBYTE);
    ushort* Mhp = (ushort*)(ws + 32 * MBYTE);
    ushort* Wsh = (ushort*)(ws + 40 * MBYTE);
    ushort* Wsl = (ushort*)(ws + 48 * MBYTE);

    const bool tierA = ws_size >= 91 * MBYTE;
    const size_t flag_off = tierA ? 88 * MBYTE : 56 * MBYTE;
    if (ws_size < flag_off + (1u << 16)) return;

    ushort* Xh = (ushort*)(ws + 56 * MBYTE);
    ushort* Xl = (ushort*)(ws + 72 * MBYTE);
    uint* flag = (uint*)(ws + flag_off);
    uint* cnt  = (uint*)(ws + flag_off + 4);
    uint* list = (uint*)(ws + flag_off + 256);
    const uint cap = (uint)((ws_size - flag_off - 256) / sizeof(uint));

    (void)hipMemsetAsync(ws + flag_off, 0, 8, stream);
    prep<<<dim3(2048), dim3(256), 0, stream>>>(x, Wsyn, WTm, u_t, b_t, spk,
                                               Xh, Xl, Wsh, Wsl, Mhp, flag,
                                               tierA ? 1 : 0);
    if (tierA) {
        gemm1_d<<<dim3(256), dim3(1024), 0, stream>>>(Xh, Xl, Wsh, Wsl, bsyn, Lhp, Llp);
    } else {
        gemm1_b<<<dim3(256), dim3(256), 0, stream>>>(x, Wsh, Wsl, bsyn, Lhp, Llp);
    }
    stage2_fast<<<dim3(512), dim3(256), 0, stream>>>(Lhp, Llp, Mhp, bTm,
                                                     out, flag, cnt, list, cap);
    stage2_slow<<<dim3(512), dim3(512), 0, stream>>>(Lhp, Llp, u_t, b_t, spk,
                                                     WTm, bTm, WTa, bTa,
                                                     out, flag, cnt, list, cap);
    lsnn_fixup<<<dim3(256), dim3(256), 0, stream>>>(Lhp, Llp, x, Wsyn, bsyn,
                                                    u_t, b_t, spk,
                                                    WTm, bTm, WTa, bTa,
                                                    cnt, list, cap, out);
}

// Round 15
// 239.797 us; speedup vs baseline: 1.1253x; 1.0393x over previous
//
#include <hip/hip_runtime.h>
#include <cmath>

#define B_DIM 4096
#define O_DIM 2048
#define I_DIM 2048

typedef _Float16 f16x8 __attribute__((ext_vector_type(8)));
typedef float f32x4 __attribute__((ext_vector_type(4)));
typedef unsigned int uint;
typedef unsigned short ushort;

#define WSCALE   64.0f
#define WDESCALE 0.015625f
#define MBYTE    ((size_t)1024 * 1024)

// ws layout:
// L1h 0..16M | L1l 16..32M | Mh 32..40M | Wsh 40..48M | Wsl 48..56M
// tier A adds: Xh 56..72M | Xl 72..88M ; flag at 88M (A) or 56M (B)

// Swizzled LDS tile: [rows][16 dwords]; 16B slot s: phys = s ^ ((r>>1)&3).
__device__ __forceinline__ int TP(int r, int s) {
    return r * 16 + (((s ^ ((r >> 1) & 3))) << 2);
}

__device__ __forceinline__ float h2f(ushort u) {
    _Float16 h = __builtin_bit_cast(_Float16, u);
    return (float)h;
}

__device__ __forceinline__ void gload16(const uint* src, uint* lds) {
    __builtin_amdgcn_global_load_lds(
        (const __attribute__((address_space(1))) void*)src,
        (__attribute__((address_space(3))) void*)lds, 16, 0, 0);
}

__device__ __forceinline__ void split8(const float4 a, const float4 b,
                                       uint4& hi, uint4& lo) {
    auto h0 = __builtin_amdgcn_cvt_pkrtz(a.x, a.y);
    auto h1 = __builtin_amdgcn_cvt_pkrtz(a.z, a.w);
    auto h2 = __builtin_amdgcn_cvt_pkrtz(b.x, b.y);
    auto h3 = __builtin_amdgcn_cvt_pkrtz(b.z, b.w);
    auto l0 = __builtin_amdgcn_cvt_pkrtz(a.x - (float)h0[0], a.y - (float)h0[1]);
    auto l1 = __builtin_amdgcn_cvt_pkrtz(a.z - (float)h1[0], a.w - (float)h1[1]);
    auto l2 = __builtin_amdgcn_cvt_pkrtz(b.x - (float)h2[0], b.y - (float)h2[1]);
    auto l3 = __builtin_amdgcn_cvt_pkrtz(b.z - (float)h3[0], b.w - (float)h3[1]);
    hi.x = __builtin_bit_cast(uint, h0); hi.y = __builtin_bit_cast(uint, h1);
    hi.z = __builtin_bit_cast(uint, h2); hi.w = __builtin_bit_cast(uint, h3);
    lo.x = __builtin_bit_cast(uint, l0); lo.y = __builtin_bit_cast(uint, l1);
    lo.z = __builtin_bit_cast(uint, l2); lo.w = __builtin_bit_cast(uint, l3);
}

__device__ __forceinline__ float4 add4(const float4 a, const float4 b) {
    return make_float4(a.x + b.x, a.y + b.y, a.z + b.z, a.w + b.w);
}
__device__ __forceinline__ float4 mul64(const float4 a) {
    return make_float4(a.x * WSCALE, a.y * WSCALE, a.z * WSCALE, a.w * WSCALE);
}
__device__ __forceinline__ void unpack8(const uint4 h, const uint4 l,
                                        float4& f0, float4& f1) {
    f0.x = h2f((ushort)(h.x & 0xffff)) + h2f((ushort)(l.x & 0xffff));
    f0.y = h2f((ushort)(h.x >> 16))    + h2f((ushort)(l.x >> 16));
    f0.z = h2f((ushort)(h.y & 0xffff)) + h2f((ushort)(l.y & 0xffff));
    f0.w = h2f((ushort)(h.y >> 16))    + h2f((ushort)(l.y >> 16));
    f1.x = h2f((ushort)(h.z & 0xffff)) + h2f((ushort)(l.z & 0xffff));
    f1.y = h2f((ushort)(h.z >> 16))    + h2f((ushort)(l.z >> 16));
    f1.z = h2f((ushort)(h.w & 0xffff)) + h2f((ushort)(l.w & 0xffff));
    f1.w = h2f((ushort)(h.w >> 16))    + h2f((ushort)(l.w >> 16));
}

// ===========================================================================
// prep: fused zcheck + split(x) + split(Wsyn*64) + split_hi(WTm*64)
// ===========================================================================
__global__ __launch_bounds__(256)
void prep(const float* __restrict__ x, const float* __restrict__ Wsyn,
          const float* __restrict__ WTm,
          const float* __restrict__ u, const float* __restrict__ b,
          const float* __restrict__ s,
          ushort* __restrict__ Xh, ushort* __restrict__ Xl,
          ushort* __restrict__ Wsh, ushort* __restrict__ Wsl,
          ushort* __restrict__ Mhp, uint* __restrict__ flag, int doX) {
    const uint NX = (uint)((size_t)B_DIM * I_DIM / 8);
    const uint NW = (uint)((size_t)O_DIM * I_DIM / 8);
    const uint NZ = (uint)((size_t)B_DIM * O_DIM / 8);
    const uint nx = doX ? NX : 0;
    const uint total = nx + 2 * NW + NZ;
    const uint stride = gridDim.x * blockDim.x;
    bool nz = false;
    for (uint t = blockIdx.x * blockDim.x + threadIdx.x; t < total; t += stride) {
        if (t < nx) {
            const size_t i = (size_t)t * 8;
            uint4 h, l;
            split8(*(const float4*)(x + i), *(const float4*)(x + i + 4), h, l);
            *(uint4*)(Xh + i) = h; *(uint4*)(Xl + i) = l;
        } else if (t < nx + NW) {
            const size_t i = (size_t)(t - nx) * 8;
            uint4 h, l;
            split8(mul64(*(const float4*)(Wsyn + i)),
                   mul64(*(const float4*)(Wsyn + i + 4)), h, l);
            *(uint4*)(Wsh + i) = h; *(uint4*)(Wsl + i) = l;
        } else if (t < nx + 2 * NW) {
            const size_t i = (size_t)(t - nx - NW) * 8;
            const float4 a = mul64(*(const float4*)(WTm + i));
            const float4 c = mul64(*(const float4*)(WTm + i + 4));
            auto h0 = __builtin_amdgcn_cvt_pkrtz(a.x, a.y);
            auto h1 = __builtin_amdgcn_cvt_pkrtz(a.z, a.w);
            auto h2 = __builtin_amdgcn_cvt_pkrtz(c.x, c.y);
            auto h3 = __builtin_amdgcn_cvt_pkrtz(c.z, c.w);
            uint4 h;
            h.x = __builtin_bit_cast(uint, h0); h.y = __builtin_bit_cast(uint, h1);
            h.z = __builtin_bit_cast(uint, h2); h.w = __builtin_bit_cast(uint, h3);
            *(uint4*)(Mhp + i) = h;
        } else {
            const size_t i = (size_t)(t - nx - 2 * NW) * 8;
            const float4 a0 = *(const float4*)(u + i), a1 = *(const float4*)(u + i + 4);
            const float4 b0 = *(const float4*)(b + i), b1 = *(const float4*)(b + i + 4);
            const float4 c0 = *(const float4*)(s + i), c1 = *(const float4*)(s + i + 4);
            nz |= (a0.x != 0.f) | (a0.y != 0.f) | (a0.z != 0.f) | (a0.w != 0.f);
            nz |= (a1.x != 0.f) | (a1.y != 0.f) | (a1.z != 0.f) | (a1.w != 0.f);
            nz |= (b0.x != 0.f) | (b0.y != 0.f) | (b0.z != 0.f) | (b0.w != 0.f);
            nz |= (b1.x != 0.f) | (b1.y != 0.f) | (b1.z != 0.f) | (b1.w != 0.f);
            nz |= (c0.x != 0.f) | (c0.y != 0.f) | (c0.z != 0.f) | (c0.w != 0.f);
            nz |= (c1.x != 0.f) | (c1.y != 0.f) | (c1.z != 0.f) | (c1.w != 0.f);
        }
    }
    if (nz) atomicOr(flag, 1u);
}

// ===========================================================================
// GEMM1 tier A (gemm1_d): 128x256 tile, 1024 thr (16 waves, 64x32 each),
// 3-deep counted-vmcnt pipeline (validated round 14, 1120 TF) + T5 setprio.
// ===========================================================================
__global__ __launch_bounds__(1024)
void gemm1_d(const ushort* __restrict__ Xh, const ushort* __restrict__ Xl,
             const ushort* __restrict__ Wh, const ushort* __restrict__ Wl,
             const float* __restrict__ bias,
             ushort* __restrict__ Lh, ushort* __restrict__ Ll) {
    __shared__ uint S[3][12288];   // 144 KB

    const int tid = threadIdx.x;
    const int lane = tid & 63;
    const int wid = tid >> 6;
    const int wm = wid >> 3;
    const int wn = wid & 7;

    int sid = blockIdx.x;
    sid = (sid & 7) * 32 + (sid >> 3);
    const int bx = sid & 7, by = sid >> 3;
    const int row0 = by * 128, col0 = bx * 256;

    const uint* src[3];
    int dbase[3];
#pragma unroll
    for (int i = 0; i < 3; i++) {
        const int ch = wid * 3 + i;
        const ushort* plane;
        int local, pbase, grow0;
        if (ch < 8)       { plane = Xh; local = ch;      pbase = 0;    grow0 = row0; }
        else if (ch < 16) { plane = Xl; local = ch - 8;  pbase = 2048; grow0 = row0; }
        else if (ch < 32) { plane = Wh; local = ch - 16; pbase = 4096; grow0 = col0; }
        else              { plane = Wl; local = ch - 32; pbase = 8192; grow0 = col0; }
        const int g = local * 64 + lane;
        const int r = g >> 2, q = (g & 3) ^ ((r >> 1) & 3);
        dbase[i] = pbase + local * 256;
        src[i] = (const uint*)plane + (size_t)(grow0 + r) * 1024 + q * 4;
    }

    f32x4 acc[4][2];
#pragma unroll
    for (int i = 0; i < 4; i++)
#pragma unroll
        for (int j = 0; j < 2; j++)
#pragma unroll
            for (int r = 0; r < 4; r++) acc[i][j][r] = 0.0f;

    const int fr = lane & 15;
    const int sl = lane >> 4;
    const int NT = I_DIM / 32;

#pragma unroll
    for (int i = 0; i < 3; i++) gload16(src[i], &S[0][dbase[i]]);
#pragma unroll
    for (int i = 0; i < 3; i++) gload16(src[i] + 16, &S[1][dbase[i]]);

    for (int t = 0; t < NT; t++) {
        if (t + 1 < NT) {
            asm volatile("s_waitcnt vmcnt(3)" ::: "memory");
        } else {
            asm volatile("s_waitcnt vmcnt(0)" ::: "memory");
        }
        asm volatile("s_barrier" ::: "memory");
        if (t + 2 < NT) {
            const int ko = (t + 2) * 16;
            uint* Sd = &S[(t + 2) % 3][0];
#pragma unroll
            for (int i = 0; i < 3; i++) gload16(src[i] + ko, &Sd[dbase[i]]);
        }
        const uint* Sc = &S[t % 3][0];
        f16x8 ah_[4], al_[4], bh_[2], bl_[2];
#pragma unroll
        for (int mi = 0; mi < 4; mi++) {
            const int r = wm * 64 + mi * 16 + fr;
            ah_[mi] = *(const f16x8*)&Sc[TP(r, sl)];
            al_[mi] = *(const f16x8*)&Sc[2048 + TP(r, sl)];
        }
#pragma unroll
        for (int ni = 0; ni < 2; ni++) {
            const int r = wn * 32 + ni * 16 + fr;
            bh_[ni] = *(const f16x8*)&Sc[4096 + TP(r, sl)];
            bl_[ni] = *(const f16x8*)&Sc[8192 + TP(r, sl)];
        }
        __builtin_amdgcn_s_setprio(1);
#pragma unroll
        for (int mi = 0; mi < 4; mi++)
#pragma unroll
            for (int ni = 0; ni < 2; ni++) {
                acc[mi][ni] = __builtin_amdgcn_mfma_f32_16x16x32_f16(ah_[mi], bh_[ni], acc[mi][ni], 0, 0, 0);
                acc[mi][ni] = __builtin_amdgcn_mfma_f32_16x16x32_f16(ah_[mi], bl_[ni], acc[mi][ni], 0, 0, 0);
                acc[mi][ni] = __builtin_amdgcn_mfma_f32_16x16x32_f16(al_[mi], bh_[ni], acc[mi][ni], 0, 0, 0);
            }
        __builtin_amdgcn_s_setprio(0);
    }

#pragma unroll
    for (int ni = 0; ni < 2; ni++) {
        const int col = col0 + wn * 32 + ni * 16 + fr;
        const float bv = bias[col];
#pragma unroll
        for (int mi = 0; mi < 4; mi++) {
            const int rb = row0 + wm * 64 + mi * 16 + ((lane >> 4) << 2);
            float e[4];
#pragma unroll
            for (int r = 0; r < 4; r++) e[r] = acc[mi][ni][r] * WDESCALE + bv;
            auto hp0 = __builtin_amdgcn_cvt_pkrtz(e[0], e[1]);
            auto hp1 = __builtin_amdgcn_cvt_pkrtz(e[2], e[3]);
            auto lp0 = __builtin_amdgcn_cvt_pkrtz(e[0] - (float)hp0[0], e[1] - (float)hp0[1]);
            auto lp1 = __builtin_amdgcn_cvt_pkrtz(e[2] - (float)hp1[0], e[3] - (float)hp1[1]);
            const uint uh0 = __builtin_bit_cast(uint, hp0);
            const uint uh1 = __builtin_bit_cast(uint, hp1);
            const uint ul0 = __builtin_bit_cast(uint, lp0);
            const uint ul1 = __builtin_bit_cast(uint, lp1);
            Lh[(size_t)(rb + 0) * O_DIM + col] = (ushort)(uh0 & 0xffff);
            Lh[(size_t)(rb + 1) * O_DIM + col] = (ushort)(uh0 >> 16);
            Lh[(size_t)(rb + 2) * O_DIM + col] = (ushort)(uh1 & 0xffff);
            Lh[(size_t)(rb + 3) * O_DIM + col] = (ushort)(uh1 >> 16);
            Ll[(size_t)(rb + 0) * O_DIM + col] = (ushort)(ul0 & 0xffff);
            Ll[(size_t)(rb + 1) * O_DIM + col] = (ushort)(ul0 >> 16);
            Ll[(size_t)(rb + 2) * O_DIM + col] = (ushort)(ul1 & 0xffff);
            Ll[(size_t)(rb + 3) * O_DIM + col] = (ushort)(ul1 >> 16);
        }
    }
}

// ===========================================================================
// GEMM1 tier B: Wsyn pre-split (gload16), X split in-loop (unchanged).
// ===========================================================================
__global__ __launch_bounds__(256)
void gemm1_b(const float* __restrict__ X,
             const ushort* __restrict__ Wh, const ushort* __restrict__ Wl,
             const float* __restrict__ bias,
             ushort* __restrict__ Lh, ushort* __restrict__ Ll) {
    __shared__ uint S[8192];

    const int tid = threadIdx.x;
    const int lane = tid & 63;
    const int wid = tid >> 6;
    const int wm = wid >> 1, wn = wid & 1;

    int sid = blockIdx.x;
    sid = (sid & 7) * 64 + (sid >> 3);
    const int bx = sid & 15, by = sid >> 4;
    const int row0 = by * 128, col0 = bx * 128;

    const int sr = tid >> 1;
    const int kh = (tid & 1) * 16;
    const int s0 = (tid & 1) * 2;
    const float* pA = X + (size_t)(row0 + sr) * I_DIM + kh;

    int r0, q0, r1, q1;
    {
        const int g0 = (wid * 2 + 0) * 64 + lane;
        const int g1 = (wid * 2 + 1) * 64 + lane;
        r0 = g0 >> 2; q0 = (g0 & 3) ^ ((r0 >> 1) & 3);
        r1 = g1 >> 2; q1 = (g1 & 3) ^ ((r1 >> 1) & 3);
    }
    const uint* sWh0 = (const uint*)Wh + (size_t)(col0 + r0) * 1024 + q0 * 4;
    const uint* sWh1 = (const uint*)Wh + (size_t)(col0 + r1) * 1024 + q1 * 4;
    const uint* sWl0 = (const uint*)Wl + (size_t)(col0 + r0) * 1024 + q0 * 4;
    const uint* sWl1 = (const uint*)Wl + (size_t)(col0 + r1) * 1024 + q1 * 4;
    const int c0 = (wid * 2 + 0) << 8;
    const int c1 = (wid * 2 + 1) << 8;

    f32x4 acc[4][4];
#pragma unroll
    for (int i = 0; i < 4; i++)
#pragma unroll
        for (int j = 0; j < 4; j++)
#pragma unroll
            for (int r = 0; r < 4; r++) acc[i][j][r] = 0.0f;

    const int fr = lane & 15;
    const int sl = lane >> 4;
    const int NT = I_DIM / 32;

    float4 a0 = *(const float4*)(pA + 0), a1 = *(const float4*)(pA + 4);
    float4 a2 = *(const float4*)(pA + 8), a3 = *(const float4*)(pA + 12);
    uint4 xh0, xl0, xh1, xl1;
    split8(a0, a1, xh0, xl0);
    split8(a2, a3, xh1, xl1);

    for (int t = 0; t < NT; t++) {
        __syncthreads();
        *(uint4*)&S[TP(sr, s0)] = xh0;         *(uint4*)&S[TP(sr, s0 + 1)] = xh1;
        *(uint4*)&S[2048 + TP(sr, s0)] = xl0;  *(uint4*)&S[2048 + TP(sr, s0 + 1)] = xl1;
        const int ko = t * 16;
        gload16(sWh0 + ko, &S[4096 + c0]);  gload16(sWh1 + ko, &S[4096 + c1]);
        gload16(sWl0 + ko, &S[6144 + c0]);  gload16(sWl1 + ko, &S[6144 + c1]);
        __syncthreads();
        if (t + 1 < NT) {
            const float* nA = pA + (t + 1) * 32;
            a0 = *(const float4*)(nA + 0); a1 = *(const float4*)(nA + 4);
            a2 = *(const float4*)(nA + 8); a3 = *(const float4*)(nA + 12);
        }
        f16x8 ah_[4], al_[4], bh_[4], bl_[4];
#pragma unroll
        for (int mi = 0; mi < 4; mi++) {
            const int r = wm * 64 + mi * 16 + fr;
            ah_[mi] = *(const f16x8*)&S[TP(r, sl)];
            al_[mi] = *(const f16x8*)&S[2048 + TP(r, sl)];
        }
#pragma unroll
        for (int ni = 0; ni < 4; ni++) {
            const int r = wn * 64 + ni * 16 + fr;
            bh_[ni] = *(const f16x8*)&S[4096 + TP(r, sl)];
            bl_[ni] = *(const f16x8*)&S[6144 + TP(r, sl)];
        }
#pragma unroll
        for (int mi = 0; mi < 4; mi++)
#pragma unroll
            for (int ni = 0; ni < 4; ni++) {
                acc[mi][ni] = __builtin_amdgcn_mfma_f32_16x16x32_f16(ah_[mi], bh_[ni], acc[mi][ni], 0, 0, 0);
                acc[mi][ni] = __builtin_amdgcn_mfma_f32_16x16x32_f16(ah_[mi], bl_[ni], acc[mi][ni], 0, 0, 0);
                acc[mi][ni] = __builtin_amdgcn_mfma_f32_16x16x32_f16(al_[mi], bh_[ni], acc[mi][ni], 0, 0, 0);
            }
        if (t + 1 < NT) {
            split8(a0, a1, xh0, xl0);
            split8(a2, a3, xh1, xl1);
        }
    }

    const int fr2 = lane & 15;
#pragma unroll
    for (int ni = 0; ni < 4; ni++) {
        const int col = col0 + wn * 64 + ni * 16 + fr2;
        const float bv = bias[col];
#pragma unroll
        for (int mi = 0; mi < 4; mi++) {
            const int rb = row0 + wm * 64 + mi * 16 + ((lane >> 4) << 2);
            float e[4];
#pragma unroll
            for (int r = 0; r < 4; r++) e[r] = acc[mi][ni][r] * WDESCALE + bv;
            auto hp0 = __builtin_amdgcn_cvt_pkrtz(e[0], e[1]);
            auto hp1 = __builtin_amdgcn_cvt_pkrtz(e[2], e[3]);
            auto lp0 = __builtin_amdgcn_cvt_pkrtz(e[0] - (float)hp0[0], e[1] - (float)hp0[1]);
            auto lp1 = __builtin_amdgcn_cvt_pkrtz(e[2] - (float)hp1[0], e[3] - (float)hp1[1]);
            const uint uh0 = __builtin_bit_cast(uint, hp0);
            const uint uh1 = __builtin_bit_cast(uint, hp1);
            const uint ul0 = __builtin_bit_cast(uint, lp0);
            const uint ul1 = __builtin_bit_cast(uint, lp1);
            Lh[(size_t)(rb + 0) * O_DIM + col] = (ushort)(uh0 & 0xffff);
            Lh[(size_t)(rb + 1) * O_DIM + col] = (ushort)(uh0 >> 16);
            Lh[(size_t)(rb + 2) * O_DIM + col] = (ushort)(uh1 & 0xffff);
            Lh[(size_t)(rb + 3) * O_DIM + col] = (ushort)(uh1 >> 16);
            Ll[(size_t)(rb + 0) * O_DIM + col] = (ushort)(ul0 & 0xffff);
            Ll[(size_t)(rb + 1) * O_DIM + col] = (ushort)(ul0 >> 16);
            Ll[(size_t)(rb + 2) * O_DIM + col] = (ushort)(ul1 & 0xffff);
            Ll[(size_t)(rb + 3) * O_DIM + col] = (ushort)(ul1 >> 16);
        }
    }
}

// ===========================================================================
// Stage-2 FAST (v2): 128x128 tile, NOW 8 waves (512 thr, 64x32 each ->
// 6 waves/SIMD at 3 blocks/CU), 3-deep counted-vmcnt (2 gload16/wave/tile,
// wait vmcnt(2)). LDS 48 KB. Two-pass LDS-transpose epilogue (16 cols/thr).
// ===========================================================================
__global__ __launch_bounds__(512)
void stage2_fast(const ushort* __restrict__ Lhp, const ushort* __restrict__ Llp,
                 const ushort* __restrict__ Mhp,
                 const float* __restrict__ bTm, float* __restrict__ out,
                 const uint* __restrict__ flag,
                 uint* __restrict__ cnt, uint* __restrict__ list, uint cap) {
    if (*flag != 0) return;

    // per buf 4096 dwords: Lh tile [0,2048), Mh tile [2048,4096)
    __shared__ uint S[3][4096];   // 48 KB

    const int tid = threadIdx.x;
    const int lane = tid & 63;
    const int wid = tid >> 6;          // 0..7
    const int wm = wid >> 2;           // 0..1 (rows, *64)
    const int wn = wid & 3;            // 0..3 (cols, *32)

    int sid = blockIdx.x;
    sid = (sid & 7) * 64 + (sid >> 3);
    const int bx = sid & 15, by = sid >> 4;
    const int row0 = by * 128, col0 = bx * 128;

    // 16 chunks: ch = wid*2+i; ch<8 -> Lh (local=ch), else Mh (local=ch-8).
    const uint* src[2];
    int base[2];
#pragma unroll
    for (int i = 0; i < 2; i++) {
        const int ch = wid * 2 + i;
        if (ch < 8) {
            const int g = ch * 64 + lane;
            const int r = g >> 2, q = (g & 3) ^ ((r >> 1) & 3);
            base[i] = ch * 256;
            src[i] = (const uint*)Lhp + (size_t)(row0 + r) * 1024 + q * 4;
        } else {
            const int g = (ch - 8) * 64 + lane;
            const int r = g >> 2, q = (g & 3) ^ ((r >> 1) & 3);
            base[i] = 2048 + (ch - 8) * 256;
            src[i] = (const uint*)Mhp + (size_t)(col0 + r) * 1024 + q * 4;
        }
    }

    f32x4 acc[4][2];
#pragma unroll
    for (int i = 0; i < 4; i++)
#pragma unroll
        for (int j = 0; j < 2; j++)
#pragma unroll
            for (int r = 0; r < 4; r++) acc[i][j][r] = 0.0f;

    const int fr = lane & 15;
    const int sl = lane >> 4;
    const int NT = O_DIM / 32;

    // prologue: 2 tiles in flight (4 outstanding loads/thread)
#pragma unroll
    for (int i = 0; i < 2; i++) gload16(src[i], &S[0][base[i]]);
#pragma unroll
    for (int i = 0; i < 2; i++) gload16(src[i] + 16, &S[1][base[i]]);

    for (int t = 0; t < NT; t++) {
        if (t + 1 < NT) {
            asm volatile("s_waitcnt vmcnt(2)" ::: "memory");
        } else {
            asm volatile("s_waitcnt vmcnt(0)" ::: "memory");
        }
        asm volatile("s_barrier" ::: "memory");
        if (t + 2 < NT) {
            const int ko = (t + 2) * 16;
            uint* Sd = &S[(t + 2) % 3][0];
#pragma unroll
            for (int i = 0; i < 2; i++) gload16(src[i] + ko, &Sd[base[i]]);
        }
        const uint* Sc = &S[t % 3][0];
        f16x8 lh_[4], mh_[2];
#pragma unroll
        for (int mi = 0; mi < 4; mi++)
            lh_[mi] = *(const f16x8*)&Sc[TP(wm * 64 + mi * 16 + fr, sl)];
#pragma unroll
        for (int ni = 0; ni < 2; ni++)
            mh_[ni] = *(const f16x8*)&Sc[2048 + TP(wn * 32 + ni * 16 + fr, sl)];
        __builtin_amdgcn_s_setprio(1);
#pragma unroll
        for (int mi = 0; mi < 4; mi++)
#pragma unroll
            for (int ni = 0; ni < 2; ni++)
                acc[mi][ni] = __builtin_amdgcn_mfma_f32_16x16x32_f16(lh_[mi], mh_[ni], acc[mi][ni], 0, 0, 0);
        __builtin_amdgcn_s_setprio(0);
    }
    __syncthreads();   // all compute done before S is reused as f32 scratch

    // ---- Epilogue: two-pass LDS transpose; 512 thr, 16 cols/thread/pass ----
    float* Sf = (float*)&S[0][0];    // 128 x 64 f32 = 32 KB
    float bmv[2];
#pragma unroll
    for (int ni = 0; ni < 2; ni++)
        bmv[ni] = bTm[col0 + wn * 32 + ni * 16 + fr];

    const int erow = tid >> 2;        // 0..127
    const int ecg  = tid & 3;         // 0..3 (16-col group within 64)

#pragma unroll
    for (int h = 0; h < 2; h++) {     // pass h covers cols [h*64, h*64+64)
        if (h) __syncthreads();
        // write phase: waves with (wn>>1)==h own cols in this half
        if ((wn >> 1) == h) {
            const int cm0 = (wn & 1) * 32;   // 0 or 32 within the 64-col half
#pragma unroll
            for (int ni = 0; ni < 2; ni++) {
#pragma unroll
                for (int mi = 0; mi < 4; mi++) {
                    const int rbL = wm * 64 + mi * 16 + ((lane >> 4) << 2);
#pragma unroll
                    for (int r = 0; r < 4; r++) {
                        const int row = rbL + r;
                        const int cm = cm0 + ni * 16 + fr;
                        const int phys = (cm + ((row >> 2) & 3) * 16 + (row & 3) * 4) & 63;
                        Sf[row * 64 + phys] = acc[mi][ni][r] * WDESCALE + bmv[ni];
                    }
                }
            }
        }
        __syncthreads();
        // read phase: 16 contiguous cols per thread
        const int rsw = ((erow >> 2) & 3) * 16 + (erow & 3) * 4;
        float z[16];
#pragma unroll
        for (int j = 0; j < 4; j++) {
            const int phys = (ecg * 16 + j * 4 + rsw) & 63;
            *(float4*)&z[j * 4] = *(const float4*)&Sf[erow * 64 + phys];
        }
        const int colBase = col0 + h * 64 + ecg * 16;
        const size_t idx0 = (size_t)(row0 + erow) * O_DIM + colBase;
        uint4 lh4[2], ll4[2];
#pragma unroll
        for (int j = 0; j < 2; j++) {
            lh4[j] = ((const uint4*)(Lhp + idx0))[j];
            ll4[j] = ((const uint4*)(Llp + idx0))[j];
        }
        float ov[16];
#pragma unroll
        for (int m = 0; m < 16; m++) {
            const uint hu = ((const uint*)lh4)[m >> 1];
            const uint lu = ((const uint*)ll4)[m >> 1];
            const ushort hs = (m & 1) ? (ushort)(hu >> 16) : (ushort)(hu & 0xffff);
            const ushort ls = (m & 1) ? (ushort)(lu >> 16) : (ushort)(lu & 0xffff);
            const float l1 = h2f(hs) + h2f(ls);
            const float zm = z[m];
            const float ea = expf(-zm);
            const float d = l1 * (1.0f + ea) - 0.01f;
            ov[m] = d > 0.0f ? 1.0f : 0.0f;
            const float tol = 2e-4f + 1e-4f * ea * (1.0f + fabsf(l1));
            if (fabsf(d) < tol) {
                const uint pos = atomicAdd(cnt, 1u);
                if (pos < cap) list[pos] = (uint)(idx0 + m);
            }
        }
#pragma unroll
        for (int j = 0; j < 4; j++)
            *(float4*)(out + idx0 + j * 4) = *(const float4*)&ov[j * 4];
    }
}

// ===========================================================================
// Stage-2 SLOW path (general inputs) — unchanged.
// ===========================================================================
__global__ __launch_bounds__(512)
void stage2_slow(const ushort* __restrict__ Lhp, const ushort* __restrict__ Llp,
                 const float* __restrict__ u_t, const float* __restrict__ b_t,
                 const float* __restrict__ spk,
                 const float* __restrict__ WTm, const float* __restrict__ bTm,
                 const float* __restrict__ WTa, const float* __restrict__ bTa,
                 float* __restrict__ out, const uint* __restrict__ flag,
                 uint* __restrict__ cnt, uint* __restrict__ list, uint cap) {
    if (*flag == 0) return;

    __shared__ uint A1h[128][20], A1l[128][20], A2h[128][20], A2l[128][20];
    __shared__ uint Mh[128][20],  Ml[128][20],  Gh[128][20],  Gl[128][20];

    const int tid = threadIdx.x;
    const int lane = tid & 63;
    const int wid = tid >> 6;
    const int wm = wid >> 2;
    const int wn = wid & 3;

    int sid = blockIdx.x;
    sid = (sid & 7) * 64 + (sid >> 3);
    const int bx = sid & 15, by = sid >> 4;
    const int row0 = by * 128, col0 = bx * 128;

    const int srow = tid >> 2;
    const int skb = (tid & 3) * 8;
    const int swc = (tid & 3) * 4;

    const size_t aoff = (size_t)(row0 + srow) * O_DIM + skb;
    const float* pU = u_t + aoff;
    const float* pT = b_t + aoff;
    const float* pM = WTm + (size_t)(col0 + srow) * O_DIM + skb;
    const float* pG = WTa + (size_t)(col0 + srow) * O_DIM + skb;

    f32x4 accM[4][2], accA[4][2];
#pragma unroll
    for (int i = 0; i < 4; i++)
#pragma unroll
        for (int j = 0; j < 2; j++)
#pragma unroll
            for (int r = 0; r < 4; r++) { accM[i][j][r] = 0.0f; accA[i][j][r] = 0.0f; }

    float4 lq0, lq1;
    {
        const uint4 LH = *(const uint4*)(Lhp + aoff);
        const uint4 LL = *(const uint4*)(Llp + aoff);
        unpack8(LH, LL, lq0, lq1);
    }
    float4 uq0 = *(const float4*)(pU + 0), uq1 = *(const float4*)(pU + 4);
    float4 tq0 = *(const float4*)(pT + 0), tq1 = *(const float4*)(pT + 4);
    float4 mq0 = *(const float4*)(pM + 0), mq1 = *(const float4*)(pM + 4);
    float4 gq0 = *(const float4*)(pG + 0), gq1 = *(const float4*)(pG + 4);

    const int fr = lane & 15;
    const int kq = (lane >> 4) * 4;

    for (int t = 0; t < O_DIM / 32; t++) {
        uint4 A1hi, A1lo, A2hi, A2lo, Mhi, Mlo, Ghi, Glo;
        split8(add4(lq0, uq0), add4(lq1, uq1), A1hi, A1lo);
        split8(add4(lq0, tq0), add4(lq1, tq1), A2hi, A2lo);
        split8(mul64(mq0), mul64(mq1), Mhi, Mlo);
        split8(mul64(gq0), mul64(gq1), Ghi, Glo);
        __syncthreads();
        *(uint4*)&A1h[srow][swc] = A1hi;  *(uint4*)&A1l[srow][swc] = A1lo;
        *(uint4*)&A2h[srow][swc] = A2hi;  *(uint4*)&A2l[srow][swc] = A2lo;
        *(uint4*)&Mh[srow][swc]  = Mhi;   *(uint4*)&Ml[srow][swc]  = Mlo;
        *(uint4*)&Gh[srow][swc]  = Ghi;   *(uint4*)&Gl[srow][swc]  = Glo;
        __syncthreads();
        if (t + 1 < O_DIM / 32) {
            const int o = (t + 1) * 32;
            const uint4 LH = *(const uint4*)(Lhp + aoff + o);
            const uint4 LL = *(const uint4*)(Llp + aoff + o);
            unpack8(LH, LL, lq0, lq1);
            uq0 = *(const float4*)(pU + o);  uq1 = *(const float4*)(pU + o + 4);
            tq0 = *(const float4*)(pT + o);  tq1 = *(const float4*)(pT + o + 4);
            mq0 = *(const float4*)(pM + o);  mq1 = *(const float4*)(pM + o + 4);
            gq0 = *(const float4*)(pG + o);  gq1 = *(const float4*)(pG + o + 4);
        }
        {
            f16x8 ah_[4], al_[4], bh_[2], bl_[2];
#pragma unroll
            for (int mi = 0; mi < 4; mi++) {
                const int r = wm * 64 + mi * 16 + fr;
                ah_[mi] = *(const f16x8*)&A1h[r][kq];
                al_[mi] = *(const f16x8*)&A1l[r][kq];
            }
#pragma unroll
            for (int ni = 0; ni < 2; ni++) {
                const int r = wn * 32 + ni * 16 + fr;
                bh_[ni] = *(const f16x8*)&Mh[r][kq];
                bl_[ni] = *(const f16x8*)&Ml[r][kq];
            }
#pragma unroll
            for (int mi = 0; mi < 4; mi++)
#pragma unroll
                for (int ni = 0; ni < 2; ni++) {
                    accM[mi][ni] = __builtin_amdgcn_mfma_f32_16x16x32_f16(ah_[mi], bh_[ni], accM[mi][ni], 0, 0, 0);
                    accM[mi][ni] = __builtin_amdgcn_mfma_f32_16x16x32_f16(ah_[mi], bl_[ni], accM[mi][ni], 0, 0, 0);
                    accM[mi][ni] = __builtin_amdgcn_mfma_f32_16x16x32_f16(al_[mi], bh_[ni], accM[mi][ni], 0, 0, 0);
                }
        }
        {
            f16x8 ah_[4], al_[4], bh_[2], bl_[2];
#pragma unroll
            for (int mi = 0; mi < 4; mi++) {
                const int r = wm * 64 + mi * 16 + fr;
                ah_[mi] = *(const f16x8*)&A2h[r][kq];
                al_[mi] = *(const f16x8*)&A2l[r][kq];
            }
#pragma unroll
            for (int ni = 0; ni < 2; ni++) {
                const int r = wn * 32 + ni * 16 + fr;
                bh_[ni] = *(const f16x8*)&Gh[r][kq];
                bl_[ni] = *(const f16x8*)&Gl[r][kq];
            }
#pragma unroll
            for (int mi = 0; mi < 4; mi++)
#pragma unroll
                for (int ni = 0; ni < 2; ni++) {
                    accA[mi][ni] = __builtin_amdgcn_mfma_f32_16x16x32_f16(ah_[mi], bh_[ni], accA[mi][ni], 0, 0, 0);
                    accA[mi][ni] = __builtin_amdgcn_mfma_f32_16x16x32_f16(ah_[mi], bl_[ni], accA[mi][ni], 0, 0, 0);
                    accA[mi][ni] = __builtin_amdgcn_mfma_f32_16x16x32_f16(al_[mi], bh_[ni], accA[mi][ni], 0, 0, 0);
                }
        }
    }

#pragma unroll
    for (int ni = 0; ni < 2; ni++) {
        const int col = col0 + wn * 32 + ni * 16 + fr;
        const float bm = bTm[col], bg = bTa[col];
#pragma unroll
        for (int mi = 0; mi < 4; mi++) {
            const int rb = row0 + wm * 64 + mi * 16 + ((lane >> 4) << 2);
#pragma unroll
            for (int r = 0; r < 4; r++) {
                const size_t idx = (size_t)(rb + r) * O_DIM + col;
                const float zm = accM[mi][ni][r] * WDESCALE + bm;
                const float za = accA[mi][ni][r] * WDESCALE + bg;
                const float ut = u_t[idx], bt = b_t[idx];
                const float sp = spk[idx];
                const float l1 = h2f(Lhp[idx]) + h2f(Llp[idx]);
                const float ea  = expf(-zm);
                const float rho = 1.0f / (1.0f + expf(-za));
                const float bn  = sp + rho * (bt - sp);
                const float thr = 0.01f + 1.8f * bn;
                const float un  = ut + (l1 - ut) * (1.0f + ea);
                const float d   = un - thr;
                out[idx] = d > 0.0f ? 1.0f : 0.0f;
                const float tol = 2e-4f + 1e-4f * ea * (1.0f + fabsf(l1 - ut))
                                + 2e-4f * fabsf(bt - sp);
                if (fabsf(d) < tol) {
                    const uint pos = atomicAdd(cnt, 1u);
                    if (pos < cap) list[pos] = (uint)idx;
                }
            }
        }
    }
}

// ===========================================================================
__global__ __launch_bounds__(256)
void lsnn_fixup(const ushort* __restrict__ Lhp, const ushort* __restrict__ Llp,
                const float* __restrict__ X, const float* __restrict__ Wsyn,
                const float* __restrict__ bsyn,
                const float* __restrict__ u_t, const float* __restrict__ b_t,
                const float* __restrict__ spk,
                const float* __restrict__ WTm, const float* __restrict__ bTm,
                const float* __restrict__ WTa, const float* __restrict__ bTa,
                const uint* __restrict__ cnt, const uint* __restrict__ list,
                uint cap, float* __restrict__ out) {
    const uint nc = *cnt;
    const uint n = nc < cap ? nc : cap;
    const int lane = threadIdx.x & 63;
    const uint wid = (blockIdx.x * blockDim.x + threadIdx.x) >> 6;
    const uint nw = (gridDim.x * blockDim.x) >> 6;

    for (uint e = wid; e < n; e += nw) {
        const uint idx = list[e];
        const int b = idx >> 11;
        const int o = idx & (O_DIM - 1);

        double l1 = 0.0, zm = 0.0, za = 0.0;
        const float* xr = X + (size_t)b * I_DIM;
        const float* wr = Wsyn + (size_t)o * I_DIM;
        for (int k = lane; k < I_DIM; k += 64)
            l1 = fma((double)xr[k], (double)wr[k], l1);

        const ushort* lhr = Lhp + (size_t)b * O_DIM;
        const ushort* llr = Llp + (size_t)b * O_DIM;
        const float* ur = u_t + (size_t)b * O_DIM;
        const float* tr = b_t + (size_t)b * O_DIM;
        const float* mr = WTm + (size_t)o * O_DIM;
        const float* ar = WTa + (size_t)o * O_DIM;
        for (int k = lane; k < O_DIM; k += 64) {
            const double l = (double)(h2f(lhr[k]) + h2f(llr[k]));
            zm = fma(l + (double)ur[k], (double)mr[k], zm);
            za = fma(l + (double)tr[k], (double)ar[k], za);
        }
#pragma unroll
        for (int off = 32; off > 0; off >>= 1) {
            l1 += __shfl_down(l1, off);
            zm += __shfl_down(zm, off);
            za += __shfl_down(za, off);
        }
        if (lane == 0) {
            l1 += (double)bsyn[o];
            zm += (double)bTm[o];
            za += (double)bTa[o];
            const double inv_alpha = 1.0 + exp(-zm);
            const double rho = 1.0 / (1.0 + exp(-za));
            const double bt = (double)b_t[idx];
            const double sp = (double)spk[idx];
            const double ut = (double)u_t[idx];
            const double b_new = sp + rho * (bt - sp);
            const double thr = 0.01 + 1.8 * b_new;
            const double u_new = ut + (l1 - ut) * inv_alpha;
            out[idx] = (u_new - thr > 0.0) ? 1.0f : 0.0f;
        }
    }
}

// ===========================================================================
extern "C" void kernel_launch(void* const* d_in, const int* in_sizes, int n_in,
                              void* d_out, int out_size, void* d_ws, size_t ws_size,
                              hipStream_t stream) {
    const float* x    = (const float*)d_in[0];
    const float* u_t  = (const float*)d_in[1];
    const float* b_t  = (const float*)d_in[2];
    const float* spk  = (const float*)d_in[3];
    const float* Wsyn = (const float*)d_in[4];
    const float* bsyn = (const float*)d_in[5];
    const float* WTm  = (const float*)d_in[6];
    const float* bTm  = (const float*)d_in[7];
    const float* WTa  = (const float*)d_in[8];
    const float* bTa  = (const float*)d_in[9];
    float* out = (float*)d_out;

    char* ws = (char*)d_ws;
    ushort* Lhp = (ushort*)(ws + 0 * MBYTE);
    ushort* Llp = (ushort*)(ws + 16 * MBYTE);
    ushort* Mhp = (ushort*)(ws + 32 * MBYTE);
    ushort* Wsh = (ushort*)(ws + 40 * MBYTE);
    ushort* Wsl = (ushort*)(ws + 48 * MBYTE);

    const bool tierA = ws_size >= 91 * MBYTE;
    const size_t flag_off = tierA ? 88 * MBYTE : 56 * MBYTE;
    if (ws_size < flag_off + (1u << 16)) return;

    ushort* Xh = (ushort*)(ws + 56 * MBYTE);
    ushort* Xl = (ushort*)(ws + 72 * MBYTE);
    uint* flag = (uint*)(ws + flag_off);
    uint* cnt  = (uint*)(ws + flag_off + 4);
    uint* list = (uint*)(ws + flag_off + 256);
    const uint cap = (uint)((ws_size - flag_off - 256) / sizeof(uint));

    (void)hipMemsetAsync(ws + flag_off, 0, 8, stream);
    prep<<<dim3(2048), dim3(256), 0, stream>>>(x, Wsyn, WTm, u_t, b_t, spk,
                                               Xh, Xl, Wsh, Wsl, Mhp, flag,
                                               tierA ? 1 : 0);
    if (tierA) {
        gemm1_d<<<dim3(256), dim3(1024), 0, stream>>>(Xh, Xl, Wsh, Wsl, bsyn, Lhp, Llp);
    } else {
        gemm1_b<<<dim3(256), dim3(256), 0, stream>>>(x, Wsh, Wsl, bsyn, Lhp, Llp);
    }
    stage2_fast<<<dim3(512), dim3(512), 0, stream>>>(Lhp, Llp, Mhp, bTm,
                                                     out, flag, cnt, list, cap);
    stage2_slow<<<dim3(512), dim3(512), 0, stream>>>(Lhp, Llp, u_t, b_t, spk,
                                                     WTm, bTm, WTa, bTa,
                                                     out, flag, cnt, list, cap);
    lsnn_fixup<<<dim3(256), dim3(256), 0, stream>>>(Lhp, Llp, x, Wsyn, bsyn,
                                                    u_t, b_t, spk,
                                                    WTm, bTm, WTa, bTa,
                                                    cnt, list, cap, out);
}

// Round 16
// 235.050 us; speedup vs baseline: 1.1480x; 1.0202x over previous
//
#include <hip/hip_runtime.h>
#include <cmath>

#define B_DIM 4096
#define O_DIM 2048
#define I_DIM 2048

typedef _Float16 f16x8 __attribute__((ext_vector_type(8)));
typedef float f32x4 __attribute__((ext_vector_type(4)));
typedef unsigned int uint;
typedef unsigned short ushort;

#define WSCALE   64.0f
#define WDESCALE 0.015625f
#define MBYTE    ((size_t)1024 * 1024)

// ws layout:
// L1h 0..16M | L1l 16..32M | Mh 32..40M | Wsh 40..48M | Wsl 48..56M
// tier A adds: Xh 56..72M | Xl 72..88M ; flag at 88M (A) or 56M (B)

// Swizzled LDS tile: [rows][16 dwords]; 16B slot s: phys = s ^ ((r>>1)&3).
__device__ __forceinline__ int TP(int r, int s) {
    return r * 16 + (((s ^ ((r >> 1) & 3))) << 2);
}

__device__ __forceinline__ float h2f(ushort u) {
    _Float16 h = __builtin_bit_cast(_Float16, u);
    return (float)h;
}

__device__ __forceinline__ void gload16(const uint* src, uint* lds) {
    __builtin_amdgcn_global_load_lds(
        (const __attribute__((address_space(1))) void*)src,
        (__attribute__((address_space(3))) void*)lds, 16, 0, 0);
}

__device__ __forceinline__ void split8(const float4 a, const float4 b,
                                       uint4& hi, uint4& lo) {
    auto h0 = __builtin_amdgcn_cvt_pkrtz(a.x, a.y);
    auto h1 = __builtin_amdgcn_cvt_pkrtz(a.z, a.w);
    auto h2 = __builtin_amdgcn_cvt_pkrtz(b.x, b.y);
    auto h3 = __builtin_amdgcn_cvt_pkrtz(b.z, b.w);
    auto l0 = __builtin_amdgcn_cvt_pkrtz(a.x - (float)h0[0], a.y - (float)h0[1]);
    auto l1 = __builtin_amdgcn_cvt_pkrtz(a.z - (float)h1[0], a.w - (float)h1[1]);
    auto l2 = __builtin_amdgcn_cvt_pkrtz(b.x - (float)h2[0], b.y - (float)h2[1]);
    auto l3 = __builtin_amdgcn_cvt_pkrtz(b.z - (float)h3[0], b.w - (float)h3[1]);
    hi.x = __builtin_bit_cast(uint, h0); hi.y = __builtin_bit_cast(uint, h1);
    hi.z = __builtin_bit_cast(uint, h2); hi.w = __builtin_bit_cast(uint, h3);
    lo.x = __builtin_bit_cast(uint, l0); lo.y = __builtin_bit_cast(uint, l1);
    lo.z = __builtin_bit_cast(uint, l2); lo.w = __builtin_bit_cast(uint, l3);
}

__device__ __forceinline__ float4 add4(const float4 a, const float4 b) {
    return make_float4(a.x + b.x, a.y + b.y, a.z + b.z, a.w + b.w);
}
__device__ __forceinline__ float4 mul64(const float4 a) {
    return make_float4(a.x * WSCALE, a.y * WSCALE, a.z * WSCALE, a.w * WSCALE);
}
__device__ __forceinline__ void unpack8(const uint4 h, const uint4 l,
                                        float4& f0, float4& f1) {
    f0.x = h2f((ushort)(h.x & 0xffff)) + h2f((ushort)(l.x & 0xffff));
    f0.y = h2f((ushort)(h.x >> 16))    + h2f((ushort)(l.x >> 16));
    f0.z = h2f((ushort)(h.y & 0xffff)) + h2f((ushort)(l.y & 0xffff));
    f0.w = h2f((ushort)(h.y >> 16))    + h2f((ushort)(l.y >> 16));
    f1.x = h2f((ushort)(h.z & 0xffff)) + h2f((ushort)(l.z & 0xffff));
    f1.y = h2f((ushort)(h.z >> 16))    + h2f((ushort)(l.z >> 16));
    f1.z = h2f((ushort)(h.w & 0xffff)) + h2f((ushort)(l.w & 0xffff));
    f1.w = h2f((ushort)(h.w >> 16))    + h2f((ushort)(l.w >> 16));
}

// ===========================================================================
// prep: fused zcheck + split(x) + split(Wsyn*64) + split_hi(WTm*64)
// ===========================================================================
__global__ __launch_bounds__(256)
void prep(const float* __restrict__ x, const float* __restrict__ Wsyn,
          const float* __restrict__ WTm,
          const float* __restrict__ u, const float* __restrict__ b,
          const float* __restrict__ s,
          ushort* __restrict__ Xh, ushort* __restrict__ Xl,
          ushort* __restrict__ Wsh, ushort* __restrict__ Wsl,
          ushort* __restrict__ Mhp, uint* __restrict__ flag, int doX) {
    const uint NX = (uint)((size_t)B_DIM * I_DIM / 8);
    const uint NW = (uint)((size_t)O_DIM * I_DIM / 8);
    const uint NZ = (uint)((size_t)B_DIM * O_DIM / 8);
    const uint nx = doX ? NX : 0;
    const uint total = nx + 2 * NW + NZ;
    const uint stride = gridDim.x * blockDim.x;
    bool nz = false;
    for (uint t = blockIdx.x * blockDim.x + threadIdx.x; t < total; t += stride) {
        if (t < nx) {
            const size_t i = (size_t)t * 8;
            uint4 h, l;
            split8(*(const float4*)(x + i), *(const float4*)(x + i + 4), h, l);
            *(uint4*)(Xh + i) = h; *(uint4*)(Xl + i) = l;
        } else if (t < nx + NW) {
            const size_t i = (size_t)(t - nx) * 8;
            uint4 h, l;
            split8(mul64(*(const float4*)(Wsyn + i)),
                   mul64(*(const float4*)(Wsyn + i + 4)), h, l);
            *(uint4*)(Wsh + i) = h; *(uint4*)(Wsl + i) = l;
        } else if (t < nx + 2 * NW) {
            const size_t i = (size_t)(t - nx - NW) * 8;
            const float4 a = mul64(*(const float4*)(WTm + i));
            const float4 c = mul64(*(const float4*)(WTm + i + 4));
            auto h0 = __builtin_amdgcn_cvt_pkrtz(a.x, a.y);
            auto h1 = __builtin_amdgcn_cvt_pkrtz(a.z, a.w);
            auto h2 = __builtin_amdgcn_cvt_pkrtz(c.x, c.y);
            auto h3 = __builtin_amdgcn_cvt_pkrtz(c.z, c.w);
            uint4 h;
            h.x = __builtin_bit_cast(uint, h0); h.y = __builtin_bit_cast(uint, h1);
            h.z = __builtin_bit_cast(uint, h2); h.w = __builtin_bit_cast(uint, h3);
            *(uint4*)(Mhp + i) = h;
        } else {
            const size_t i = (size_t)(t - nx - 2 * NW) * 8;
            const float4 a0 = *(const float4*)(u + i), a1 = *(const float4*)(u + i + 4);
            const float4 b0 = *(const float4*)(b + i), b1 = *(const float4*)(b + i + 4);
            const float4 c0 = *(const float4*)(s + i), c1 = *(const float4*)(s + i + 4);
            nz |= (a0.x != 0.f) | (a0.y != 0.f) | (a0.z != 0.f) | (a0.w != 0.f);
            nz |= (a1.x != 0.f) | (a1.y != 0.f) | (a1.z != 0.f) | (a1.w != 0.f);
            nz |= (b0.x != 0.f) | (b0.y != 0.f) | (b0.z != 0.f) | (b0.w != 0.f);
            nz |= (b1.x != 0.f) | (b1.y != 0.f) | (b1.z != 0.f) | (b1.w != 0.f);
            nz |= (c0.x != 0.f) | (c0.y != 0.f) | (c0.z != 0.f) | (c0.w != 0.f);
            nz |= (c1.x != 0.f) | (c1.y != 0.f) | (c1.z != 0.f) | (c1.w != 0.f);
        }
    }
    if (nz) atomicOr(flag, 1u);
}

// ===========================================================================
// GEMM1 tier A (gemm1_d): 128x256 tile, 1024 thr (16 waves, 64x32 each),
// 3-deep counted-vmcnt pipeline (validated round 14; setprio removed).
// ===========================================================================
__global__ __launch_bounds__(1024)
void gemm1_d(const ushort* __restrict__ Xh, const ushort* __restrict__ Xl,
             const ushort* __restrict__ Wh, const ushort* __restrict__ Wl,
             const float* __restrict__ bias,
             ushort* __restrict__ Lh, ushort* __restrict__ Ll) {
    __shared__ uint S[3][12288];   // 144 KB

    const int tid = threadIdx.x;
    const int lane = tid & 63;
    const int wid = tid >> 6;
    const int wm = wid >> 3;
    const int wn = wid & 7;

    int sid = blockIdx.x;
    sid = (sid & 7) * 32 + (sid >> 3);
    const int bx = sid & 7, by = sid >> 3;
    const int row0 = by * 128, col0 = bx * 256;

    const uint* src[3];
    int dbase[3];
#pragma unroll
    for (int i = 0; i < 3; i++) {
        const int ch = wid * 3 + i;
        const ushort* plane;
        int local, pbase, grow0;
        if (ch < 8)       { plane = Xh; local = ch;      pbase = 0;    grow0 = row0; }
        else if (ch < 16) { plane = Xl; local = ch - 8;  pbase = 2048; grow0 = row0; }
        else if (ch < 32) { plane = Wh; local = ch - 16; pbase = 4096; grow0 = col0; }
        else              { plane = Wl; local = ch - 32; pbase = 8192; grow0 = col0; }
        const int g = local * 64 + lane;
        const int r = g >> 2, q = (g & 3) ^ ((r >> 1) & 3);
        dbase[i] = pbase + local * 256;
        src[i] = (const uint*)plane + (size_t)(grow0 + r) * 1024 + q * 4;
    }

    f32x4 acc[4][2];
#pragma unroll
    for (int i = 0; i < 4; i++)
#pragma unroll
        for (int j = 0; j < 2; j++)
#pragma unroll
            for (int r = 0; r < 4; r++) acc[i][j][r] = 0.0f;

    const int fr = lane & 15;
    const int sl = lane >> 4;
    const int NT = I_DIM / 32;

#pragma unroll
    for (int i = 0; i < 3; i++) gload16(src[i], &S[0][dbase[i]]);
#pragma unroll
    for (int i = 0; i < 3; i++) gload16(src[i] + 16, &S[1][dbase[i]]);

    for (int t = 0; t < NT; t++) {
        if (t + 1 < NT) {
            asm volatile("s_waitcnt vmcnt(3)" ::: "memory");
        } else {
            asm volatile("s_waitcnt vmcnt(0)" ::: "memory");
        }
        asm volatile("s_barrier" ::: "memory");
        if (t + 2 < NT) {
            const int ko = (t + 2) * 16;
            uint* Sd = &S[(t + 2) % 3][0];
#pragma unroll
            for (int i = 0; i < 3; i++) gload16(src[i] + ko, &Sd[dbase[i]]);
        }
        const uint* Sc = &S[t % 3][0];
        f16x8 ah_[4], al_[4], bh_[2], bl_[2];
#pragma unroll
        for (int mi = 0; mi < 4; mi++) {
            const int r = wm * 64 + mi * 16 + fr;
            ah_[mi] = *(const f16x8*)&Sc[TP(r, sl)];
            al_[mi] = *(const f16x8*)&Sc[2048 + TP(r, sl)];
        }
#pragma unroll
        for (int ni = 0; ni < 2; ni++) {
            const int r = wn * 32 + ni * 16 + fr;
            bh_[ni] = *(const f16x8*)&Sc[4096 + TP(r, sl)];
            bl_[ni] = *(const f16x8*)&Sc[8192 + TP(r, sl)];
        }
#pragma unroll
        for (int mi = 0; mi < 4; mi++)
#pragma unroll
            for (int ni = 0; ni < 2; ni++) {
                acc[mi][ni] = __builtin_amdgcn_mfma_f32_16x16x32_f16(ah_[mi], bh_[ni], acc[mi][ni], 0, 0, 0);
                acc[mi][ni] = __builtin_amdgcn_mfma_f32_16x16x32_f16(ah_[mi], bl_[ni], acc[mi][ni], 0, 0, 0);
                acc[mi][ni] = __builtin_amdgcn_mfma_f32_16x16x32_f16(al_[mi], bh_[ni], acc[mi][ni], 0, 0, 0);
            }
    }

#pragma unroll
    for (int ni = 0; ni < 2; ni++) {
        const int col = col0 + wn * 32 + ni * 16 + fr;
        const float bv = bias[col];
#pragma unroll
        for (int mi = 0; mi < 4; mi++) {
            const int rb = row0 + wm * 64 + mi * 16 + ((lane >> 4) << 2);
            float e[4];
#pragma unroll
            for (int r = 0; r < 4; r++) e[r] = acc[mi][ni][r] * WDESCALE + bv;
            auto hp0 = __builtin_amdgcn_cvt_pkrtz(e[0], e[1]);
            auto hp1 = __builtin_amdgcn_cvt_pkrtz(e[2], e[3]);
            auto lp0 = __builtin_amdgcn_cvt_pkrtz(e[0] - (float)hp0[0], e[1] - (float)hp0[1]);
            auto lp1 = __builtin_amdgcn_cvt_pkrtz(e[2] - (float)hp1[0], e[3] - (float)hp1[1]);
            const uint uh0 = __builtin_bit_cast(uint, hp0);
            const uint uh1 = __builtin_bit_cast(uint, hp1);
            const uint ul0 = __builtin_bit_cast(uint, lp0);
            const uint ul1 = __builtin_bit_cast(uint, lp1);
            Lh[(size_t)(rb + 0) * O_DIM + col] = (ushort)(uh0 & 0xffff);
            Lh[(size_t)(rb + 1) * O_DIM + col] = (ushort)(uh0 >> 16);
            Lh[(size_t)(rb + 2) * O_DIM + col] = (ushort)(uh1 & 0xffff);
            Lh[(size_t)(rb + 3) * O_DIM + col] = (ushort)(uh1 >> 16);
            Ll[(size_t)(rb + 0) * O_DIM + col] = (ushort)(ul0 & 0xffff);
            Ll[(size_t)(rb + 1) * O_DIM + col] = (ushort)(ul0 >> 16);
            Ll[(size_t)(rb + 2) * O_DIM + col] = (ushort)(ul1 & 0xffff);
            Ll[(size_t)(rb + 3) * O_DIM + col] = (ushort)(ul1 >> 16);
        }
    }
}

// ===========================================================================
// GEMM1 tier B: Wsyn pre-split (gload16), X split in-loop (unchanged).
// ===========================================================================
__global__ __launch_bounds__(256)
void gemm1_b(const float* __restrict__ X,
             const ushort* __restrict__ Wh, const ushort* __restrict__ Wl,
             const float* __restrict__ bias,
             ushort* __restrict__ Lh, ushort* __restrict__ Ll) {
    __shared__ uint S[8192];

    const int tid = threadIdx.x;
    const int lane = tid & 63;
    const int wid = tid >> 6;
    const int wm = wid >> 1, wn = wid & 1;

    int sid = blockIdx.x;
    sid = (sid & 7) * 64 + (sid >> 3);
    const int bx = sid & 15, by = sid >> 4;
    const int row0 = by * 128, col0 = bx * 128;

    const int sr = tid >> 1;
    const int kh = (tid & 1) * 16;
    const int s0 = (tid & 1) * 2;
    const float* pA = X + (size_t)(row0 + sr) * I_DIM + kh;

    int r0, q0, r1, q1;
    {
        const int g0 = (wid * 2 + 0) * 64 + lane;
        const int g1 = (wid * 2 + 1) * 64 + lane;
        r0 = g0 >> 2; q0 = (g0 & 3) ^ ((r0 >> 1) & 3);
        r1 = g1 >> 2; q1 = (g1 & 3) ^ ((r1 >> 1) & 3);
    }
    const uint* sWh0 = (const uint*)Wh + (size_t)(col0 + r0) * 1024 + q0 * 4;
    const uint* sWh1 = (const uint*)Wh + (size_t)(col0 + r1) * 1024 + q1 * 4;
    const uint* sWl0 = (const uint*)Wl + (size_t)(col0 + r0) * 1024 + q0 * 4;
    const uint* sWl1 = (const uint*)Wl + (size_t)(col0 + r1) * 1024 + q1 * 4;
    const int c0 = (wid * 2 + 0) << 8;
    const int c1 = (wid * 2 + 1) << 8;

    f32x4 acc[4][4];
#pragma unroll
    for (int i = 0; i < 4; i++)
#pragma unroll
        for (int j = 0; j < 4; j++)
#pragma unroll
            for (int r = 0; r < 4; r++) acc[i][j][r] = 0.0f;

    const int fr = lane & 15;
    const int sl = lane >> 4;
    const int NT = I_DIM / 32;

    float4 a0 = *(const float4*)(pA + 0), a1 = *(const float4*)(pA + 4);
    float4 a2 = *(const float4*)(pA + 8), a3 = *(const float4*)(pA + 12);
    uint4 xh0, xl0, xh1, xl1;
    split8(a0, a1, xh0, xl0);
    split8(a2, a3, xh1, xl1);

    for (int t = 0; t < NT; t++) {
        __syncthreads();
        *(uint4*)&S[TP(sr, s0)] = xh0;         *(uint4*)&S[TP(sr, s0 + 1)] = xh1;
        *(uint4*)&S[2048 + TP(sr, s0)] = xl0;  *(uint4*)&S[2048 + TP(sr, s0 + 1)] = xl1;
        const int ko = t * 16;
        gload16(sWh0 + ko, &S[4096 + c0]);  gload16(sWh1 + ko, &S[4096 + c1]);
        gload16(sWl0 + ko, &S[6144 + c0]);  gload16(sWl1 + ko, &S[6144 + c1]);
        __syncthreads();
        if (t + 1 < NT) {
            const float* nA = pA + (t + 1) * 32;
            a0 = *(const float4*)(nA + 0); a1 = *(const float4*)(nA + 4);
            a2 = *(const float4*)(nA + 8); a3 = *(const float4*)(nA + 12);
        }
        f16x8 ah_[4], al_[4], bh_[4], bl_[4];
#pragma unroll
        for (int mi = 0; mi < 4; mi++) {
            const int r = wm * 64 + mi * 16 + fr;
            ah_[mi] = *(const f16x8*)&S[TP(r, sl)];
            al_[mi] = *(const f16x8*)&S[2048 + TP(r, sl)];
        }
#pragma unroll
        for (int ni = 0; ni < 4; ni++) {
            const int r = wn * 64 + ni * 16 + fr;
            bh_[ni] = *(const f16x8*)&S[4096 + TP(r, sl)];
            bl_[ni] = *(const f16x8*)&S[6144 + TP(r, sl)];
        }
#pragma unroll
        for (int mi = 0; mi < 4; mi++)
#pragma unroll
            for (int ni = 0; ni < 4; ni++) {
                acc[mi][ni] = __builtin_amdgcn_mfma_f32_16x16x32_f16(ah_[mi], bh_[ni], acc[mi][ni], 0, 0, 0);
                acc[mi][ni] = __builtin_amdgcn_mfma_f32_16x16x32_f16(ah_[mi], bl_[ni], acc[mi][ni], 0, 0, 0);
                acc[mi][ni] = __builtin_amdgcn_mfma_f32_16x16x32_f16(al_[mi], bh_[ni], acc[mi][ni], 0, 0, 0);
            }
        if (t + 1 < NT) {
            split8(a0, a1, xh0, xl0);
            split8(a2, a3, xh1, xl1);
        }
    }

    const int fr2 = lane & 15;
#pragma unroll
    for (int ni = 0; ni < 4; ni++) {
        const int col = col0 + wn * 64 + ni * 16 + fr2;
        const float bv = bias[col];
#pragma unroll
        for (int mi = 0; mi < 4; mi++) {
            const int rb = row0 + wm * 64 + mi * 16 + ((lane >> 4) << 2);
            float e[4];
#pragma unroll
            for (int r = 0; r < 4; r++) e[r] = acc[mi][ni][r] * WDESCALE + bv;
            auto hp0 = __builtin_amdgcn_cvt_pkrtz(e[0], e[1]);
            auto hp1 = __builtin_amdgcn_cvt_pkrtz(e[2], e[3]);
            auto lp0 = __builtin_amdgcn_cvt_pkrtz(e[0] - (float)hp0[0], e[1] - (float)hp0[1]);
            auto lp1 = __builtin_amdgcn_cvt_pkrtz(e[2] - (float)hp1[0], e[3] - (float)hp1[1]);
            const uint uh0 = __builtin_bit_cast(uint, hp0);
            const uint uh1 = __builtin_bit_cast(uint, hp1);
            const uint ul0 = __builtin_bit_cast(uint, lp0);
            const uint ul1 = __builtin_bit_cast(uint, lp1);
            Lh[(size_t)(rb + 0) * O_DIM + col] = (ushort)(uh0 & 0xffff);
            Lh[(size_t)(rb + 1) * O_DIM + col] = (ushort)(uh0 >> 16);
            Lh[(size_t)(rb + 2) * O_DIM + col] = (ushort)(uh1 & 0xffff);
            Lh[(size_t)(rb + 3) * O_DIM + col] = (ushort)(uh1 >> 16);
            Ll[(size_t)(rb + 0) * O_DIM + col] = (ushort)(ul0 & 0xffff);
            Ll[(size_t)(rb + 1) * O_DIM + col] = (ushort)(ul0 >> 16);
            Ll[(size_t)(rb + 2) * O_DIM + col] = (ushort)(ul1 & 0xffff);
            Ll[(size_t)(rb + 3) * O_DIM + col] = (ushort)(ul1 >> 16);
        }
    }
}

// ===========================================================================
// Stage-2 FAST (v3): gemm1_d shape — 128x256 tile, 1024 thr (16 waves,
// 64x32 each, 8 waves/SIMD at 2 blocks/CU). 3-deep counted-vmcnt; waves 0-7
// are loaders (3 chunks each, wait vmcnt(3)); waves 8-15 compute-only.
// LDS 3 x 24 KB = 72 KB. Four-pass LDS-transpose epilogue (8 cols/thread).
// ===========================================================================
__global__ __launch_bounds__(1024)
void stage2_fast(const ushort* __restrict__ Lhp, const ushort* __restrict__ Llp,
                 const ushort* __restrict__ Mhp,
                 const float* __restrict__ bTm, float* __restrict__ out,
                 const uint* __restrict__ flag,
                 uint* __restrict__ cnt, uint* __restrict__ list, uint cap) {
    if (*flag != 0) return;

    // per buf 6144 dwords: Lh tile [0,2048) (128x32 f16), Mh [2048,6144) (256x32)
    __shared__ uint S[3][6144];   // 72 KB

    const int tid = threadIdx.x;
    const int lane = tid & 63;
    const int wid = tid >> 6;          // 0..15
    const int wm = wid >> 3;           // 0..1 (rows *64)
    const int wn = wid & 7;            // 0..7 (cols *32)

    int sid = blockIdx.x;
    sid = (sid & 7) * 32 + (sid >> 3);    // XCD swizzle (256 % 8 == 0)
    const int bx = sid & 7, by = sid >> 3;
    const int row0 = by * 128, col0 = bx * 256;

    // 24 chunks: 0..7 Lh (local=ch), 8..23 Mh (local=ch-8).
    // Waves 0..7 load 3 chunks each; waves 8..15 load none.
    const bool loader = (wid < 8);
    const uint* src[3];
    int base[3];
#pragma unroll
    for (int i = 0; i < 3; i++) {
        const int ch = loader ? (wid * 3 + i) : 0;
        if (ch < 8) {
            const int g = ch * 64 + lane;
            const int r = g >> 2, q = (g & 3) ^ ((r >> 1) & 3);
            base[i] = ch * 256;
            src[i] = (const uint*)Lhp + (size_t)(row0 + r) * 1024 + q * 4;
        } else {
            const int g = (ch - 8) * 64 + lane;
            const int r = g >> 2, q = (g & 3) ^ ((r >> 1) & 3);
            base[i] = 2048 + (ch - 8) * 256;
            src[i] = (const uint*)Mhp + (size_t)(col0 + r) * 1024 + q * 4;
        }
    }

    f32x4 acc[4][2];
#pragma unroll
    for (int i = 0; i < 4; i++)
#pragma unroll
        for (int j = 0; j < 2; j++)
#pragma unroll
            for (int r = 0; r < 4; r++) acc[i][j][r] = 0.0f;

    const int fr = lane & 15;
    const int sl = lane >> 4;
    const int NT = O_DIM / 32;

    // prologue: 2 tiles in flight (loaders: 6 outstanding)
    if (loader) {
#pragma unroll
        for (int i = 0; i < 3; i++) gload16(src[i], &S[0][base[i]]);
#pragma unroll
        for (int i = 0; i < 3; i++) gload16(src[i] + 16, &S[1][base[i]]);
    }

    for (int t = 0; t < NT; t++) {
        if (t + 1 < NT) {
            asm volatile("s_waitcnt vmcnt(3)" ::: "memory");
        } else {
            asm volatile("s_waitcnt vmcnt(0)" ::: "memory");
        }
        asm volatile("s_barrier" ::: "memory");
        if (loader && t + 2 < NT) {
            const int ko = (t + 2) * 16;
            uint* Sd = &S[(t + 2) % 3][0];
#pragma unroll
            for (int i = 0; i < 3; i++) gload16(src[i] + ko, &Sd[base[i]]);
        }
        const uint* Sc = &S[t % 3][0];
        f16x8 lh_[4], mh_[2];
#pragma unroll
        for (int mi = 0; mi < 4; mi++)
            lh_[mi] = *(const f16x8*)&Sc[TP(wm * 64 + mi * 16 + fr, sl)];
#pragma unroll
        for (int ni = 0; ni < 2; ni++)
            mh_[ni] = *(const f16x8*)&Sc[2048 + TP(wn * 32 + ni * 16 + fr, sl)];
#pragma unroll
        for (int mi = 0; mi < 4; mi++)
#pragma unroll
            for (int ni = 0; ni < 2; ni++)
                acc[mi][ni] = __builtin_amdgcn_mfma_f32_16x16x32_f16(lh_[mi], mh_[ni], acc[mi][ni], 0, 0, 0);
    }
    __syncthreads();   // all compute done before S is reused as f32 scratch

    // ---- Epilogue: 4-pass LDS transpose; pass p covers cols [p*64, p*64+64)
    float* Sf = (float*)&S[0][0];    // 128 x 64 f32 = 32 KB (fits in 72 KB)
    float bmv[2];
#pragma unroll
    for (int ni = 0; ni < 2; ni++)
        bmv[ni] = bTm[col0 + wn * 32 + ni * 16 + fr];

    const int erow = tid >> 3;        // 0..127
    const int ecg  = tid & 7;         // 0..7 (8-col group within 64)

#pragma unroll
    for (int p = 0; p < 4; p++) {
        if (p) __syncthreads();
        // write phase: waves with (wn>>1)==p own this 64-col half
        if ((wn >> 1) == p) {
            const int cm0 = (wn & 1) * 32;
#pragma unroll
            for (int ni = 0; ni < 2; ni++) {
#pragma unroll
                for (int mi = 0; mi < 4; mi++) {
                    const int rbL = wm * 64 + mi * 16 + ((lane >> 4) << 2);
#pragma unroll
                    for (int r = 0; r < 4; r++) {
                        const int row = rbL + r;
                        const int cm = cm0 + ni * 16 + fr;
                        const int phys = (cm + ((row >> 2) & 3) * 16 + (row & 3) * 4) & 63;
                        Sf[row * 64 + phys] = acc[mi][ni][r] * WDESCALE + bmv[ni];
                    }
                }
            }
        }
        __syncthreads();
        // read phase: 8 contiguous cols per thread
        const int rsw = ((erow >> 2) & 3) * 16 + (erow & 3) * 4;
        float z[8];
#pragma unroll
        for (int j = 0; j < 2; j++) {
            const int phys = (ecg * 8 + j * 4 + rsw) & 63;
            *(float4*)&z[j * 4] = *(const float4*)&Sf[erow * 64 + phys];
        }
        const int colBase = col0 + p * 64 + ecg * 8;
        const size_t idx0 = (size_t)(row0 + erow) * O_DIM + colBase;
        const uint4 lh4 = *(const uint4*)(Lhp + idx0);
        const uint4 ll4 = *(const uint4*)(Llp + idx0);
        float ov[8];
#pragma unroll
        for (int m = 0; m < 8; m++) {
            const uint hu = ((const uint*)&lh4)[m >> 1];
            const uint lu = ((const uint*)&ll4)[m >> 1];
            const ushort hs = (m & 1) ? (ushort)(hu >> 16) : (ushort)(hu & 0xffff);
            const ushort ls = (m & 1) ? (ushort)(lu >> 16) : (ushort)(lu & 0xffff);
            const float l1 = h2f(hs) + h2f(ls);
            const float zm = z[m];
            const float ea = expf(-zm);
            const float d = l1 * (1.0f + ea) - 0.01f;
            ov[m] = d > 0.0f ? 1.0f : 0.0f;
            const float tol = 2e-4f + 1e-4f * ea * (1.0f + fabsf(l1));
            if (fabsf(d) < tol) {
                const uint pos = atomicAdd(cnt, 1u);
                if (pos < cap) list[pos] = (uint)(idx0 + m);
            }
        }
#pragma unroll
        for (int j = 0; j < 2; j++)
            *(float4*)(out + idx0 + j * 4) = *(const float4*)&ov[j * 4];
    }
}

// ===========================================================================
// Stage-2 SLOW path (general inputs) — unchanged.
// ===========================================================================
__global__ __launch_bounds__(512)
void stage2_slow(const ushort* __restrict__ Lhp, const ushort* __restrict__ Llp,
                 const float* __restrict__ u_t, const float* __restrict__ b_t,
                 const float* __restrict__ spk,
                 const float* __restrict__ WTm, const float* __restrict__ bTm,
                 const float* __restrict__ WTa, const float* __restrict__ bTa,
                 float* __restrict__ out, const uint* __restrict__ flag,
                 uint* __restrict__ cnt, uint* __restrict__ list, uint cap) {
    if (*flag == 0) return;

    __shared__ uint A1h[128][20], A1l[128][20], A2h[128][20], A2l[128][20];
    __shared__ uint Mh[128][20],  Ml[128][20],  Gh[128][20],  Gl[128][20];

    const int tid = threadIdx.x;
    const int lane = tid & 63;
    const int wid = tid >> 6;
    const int wm = wid >> 2;
    const int wn = wid & 3;

    int sid = blockIdx.x;
    sid = (sid & 7) * 64 + (sid >> 3);
    const int bx = sid & 15, by = sid >> 4;
    const int row0 = by * 128, col0 = bx * 128;

    const int srow = tid >> 2;
    const int skb = (tid & 3) * 8;
    const int swc = (tid & 3) * 4;

    const size_t aoff = (size_t)(row0 + srow) * O_DIM + skb;
    const float* pU = u_t + aoff;
    const float* pT = b_t + aoff;
    const float* pM = WTm + (size_t)(col0 + srow) * O_DIM + skb;
    const float* pG = WTa + (size_t)(col0 + srow) * O_DIM + skb;

    f32x4 accM[4][2], accA[4][2];
#pragma unroll
    for (int i = 0; i < 4; i++)
#pragma unroll
        for (int j = 0; j < 2; j++)
#pragma unroll
            for (int r = 0; r < 4; r++) { accM[i][j][r] = 0.0f; accA[i][j][r] = 0.0f; }

    float4 lq0, lq1;
    {
        const uint4 LH = *(const uint4*)(Lhp + aoff);
        const uint4 LL = *(const uint4*)(Llp + aoff);
        unpack8(LH, LL, lq0, lq1);
    }
    float4 uq0 = *(const float4*)(pU + 0), uq1 = *(const float4*)(pU + 4);
    float4 tq0 = *(const float4*)(pT + 0), tq1 = *(const float4*)(pT + 4);
    float4 mq0 = *(const float4*)(pM + 0), mq1 = *(const float4*)(pM + 4);
    float4 gq0 = *(const float4*)(pG + 0), gq1 = *(const float4*)(pG + 4);

    const int fr = lane & 15;
    const int kq = (lane >> 4) * 4;

    for (int t = 0; t < O_DIM / 32; t++) {
        uint4 A1hi, A1lo, A2hi, A2lo, Mhi, Mlo, Ghi, Glo;
        split8(add4(lq0, uq0), add4(lq1, uq1), A1hi, A1lo);
        split8(add4(lq0, tq0), add4(lq1, tq1), A2hi, A2lo);
        split8(mul64(mq0), mul64(mq1), Mhi, Mlo);
        split8(mul64(gq0), mul64(gq1), Ghi, Glo);
        __syncthreads();
        *(uint4*)&A1h[srow][swc] = A1hi;  *(uint4*)&A1l[srow][swc] = A1lo;
        *(uint4*)&A2h[srow][swc] = A2hi;  *(uint4*)&A2l[srow][swc] = A2lo;
        *(uint4*)&Mh[srow][swc]  = Mhi;   *(uint4*)&Ml[srow][swc]  = Mlo;
        *(uint4*)&Gh[srow][swc]  = Ghi;   *(uint4*)&Gl[srow][swc]  = Glo;
        __syncthreads();
        if (t + 1 < O_DIM / 32) {
            const int o = (t + 1) * 32;
            const uint4 LH = *(const uint4*)(Lhp + aoff + o);
            const uint4 LL = *(const uint4*)(Llp + aoff + o);
            unpack8(LH, LL, lq0, lq1);
            uq0 = *(const float4*)(pU + o);  uq1 = *(const float4*)(pU + o + 4);
            tq0 = *(const float4*)(pT + o);  tq1 = *(const float4*)(pT + o + 4);
            mq0 = *(const float4*)(pM + o);  mq1 = *(const float4*)(pM + o + 4);
            gq0 = *(const float4*)(pG + o);  gq1 = *(const float4*)(pG + o + 4);
        }
        {
            f16x8 ah_[4], al_[4], bh_[2], bl_[2];
#pragma unroll
            for (int mi = 0; mi < 4; mi++) {
                const int r = wm * 64 + mi * 16 + fr;
                ah_[mi] = *(const f16x8*)&A1h[r][kq];
                al_[mi] = *(const f16x8*)&A1l[r][kq];
            }
#pragma unroll
            for (int ni = 0; ni < 2; ni++) {
                const int r = wn * 32 + ni * 16 + fr;
                bh_[ni] = *(const f16x8*)&Mh[r][kq];
                bl_[ni] = *(const f16x8*)&Ml[r][kq];
            }
#pragma unroll
            for (int mi = 0; mi < 4; mi++)
#pragma unroll
                for (int ni = 0; ni < 2; ni++) {
                    accM[mi][ni] = __builtin_amdgcn_mfma_f32_16x16x32_f16(ah_[mi], bh_[ni], accM[mi][ni], 0, 0, 0);
                    accM[mi][ni] = __builtin_amdgcn_mfma_f32_16x16x32_f16(ah_[mi], bl_[ni], accM[mi][ni], 0, 0, 0);
                    accM[mi][ni] = __builtin_amdgcn_mfma_f32_16x16x32_f16(al_[mi], bh_[ni], accM[mi][ni], 0, 0, 0);
                }
        }
        {
            f16x8 ah_[4], al_[4], bh_[2], bl_[2];
#pragma unroll
            for (int mi = 0; mi < 4; mi++) {
                const int r = wm * 64 + mi * 16 + fr;
                ah_[mi] = *(const f16x8*)&A2h[r][kq];
                al_[mi] = *(const f16x8*)&A2l[r][kq];
            }
#pragma unroll
            for (int ni = 0; ni < 2; ni++) {
                const int r = wn * 32 + ni * 16 + fr;
                bh_[ni] = *(const f16x8*)&Gh[r][kq];
                bl_[ni] = *(const f16x8*)&Gl[r][kq];
            }
#pragma unroll
            for (int mi = 0; mi < 4; mi++)
#pragma unroll
                for (int ni = 0; ni < 2; ni++) {
                    accA[mi][ni] = __builtin_amdgcn_mfma_f32_16x16x32_f16(ah_[mi], bh_[ni], accA[mi][ni], 0, 0, 0);
                    accA[mi][ni] = __builtin_amdgcn_mfma_f32_16x16x32_f16(ah_[mi], bl_[ni], accA[mi][ni], 0, 0, 0);
                    accA[mi][ni] = __builtin_amdgcn_mfma_f32_16x16x32_f16(al_[mi], bh_[ni], accA[mi][ni], 0, 0, 0);
                }
        }
    }

#pragma unroll
    for (int ni = 0; ni < 2; ni++) {
        const int col = col0 + wn * 32 + ni * 16 + fr;
        const float bm = bTm[col], bg = bTa[col];
#pragma unroll
        for (int mi = 0; mi < 4; mi++) {
            const int rb = row0 + wm * 64 + mi * 16 + ((lane >> 4) << 2);
#pragma unroll
            for (int r = 0; r < 4; r++) {
                const size_t idx = (size_t)(rb + r) * O_DIM + col;
                const float zm = accM[mi][ni][r] * WDESCALE + bm;
                const float za = accA[mi][ni][r] * WDESCALE + bg;
                const float ut = u_t[idx], bt = b_t[idx];
                const float sp = spk[idx];
                const float l1 = h2f(Lhp[idx]) + h2f(Llp[idx]);
                const float ea  = expf(-zm);
                const float rho = 1.0f / (1.0f + expf(-za));
                const float bn  = sp + rho * (bt - sp);
                const float thr = 0.01f + 1.8f * bn;
                const float un  = ut + (l1 - ut) * (1.0f + ea);
                const float d   = un - thr;
                out[idx] = d > 0.0f ? 1.0f : 0.0f;
                const float tol = 2e-4f + 1e-4f * ea * (1.0f + fabsf(l1 - ut))
                                + 2e-4f * fabsf(bt - sp);
                if (fabsf(d) < tol) {
                    const uint pos = atomicAdd(cnt, 1u);
                    if (pos < cap) list[pos] = (uint)idx;
                }
            }
        }
    }
}

// ===========================================================================
__global__ __launch_bounds__(256)
void lsnn_fixup(const ushort* __restrict__ Lhp, const ushort* __restrict__ Llp,
                const float* __restrict__ X, const float* __restrict__ Wsyn,
                const float* __restrict__ bsyn,
                const float* __restrict__ u_t, const float* __restrict__ b_t,
                const float* __restrict__ spk,
                const float* __restrict__ WTm, const float* __restrict__ bTm,
                const float* __restrict__ WTa, const float* __restrict__ bTa,
                const uint* __restrict__ cnt, const uint* __restrict__ list,
                uint cap, float* __restrict__ out) {
    const uint nc = *cnt;
    const uint n = nc < cap ? nc : cap;
    const int lane = threadIdx.x & 63;
    const uint wid = (blockIdx.x * blockDim.x + threadIdx.x) >> 6;
    const uint nw = (gridDim.x * blockDim.x) >> 6;

    for (uint e = wid; e < n; e += nw) {
        const uint idx = list[e];
        const int b = idx >> 11;
        const int o = idx & (O_DIM - 1);

        double l1 = 0.0, zm = 0.0, za = 0.0;
        const float* xr = X + (size_t)b * I_DIM;
        const float* wr = Wsyn + (size_t)o * I_DIM;
        for (int k = lane; k < I_DIM; k += 64)
            l1 = fma((double)xr[k], (double)wr[k], l1);

        const ushort* lhr = Lhp + (size_t)b * O_DIM;
        const ushort* llr = Llp + (size_t)b * O_DIM;
        const float* ur = u_t + (size_t)b * O_DIM;
        const float* tr = b_t + (size_t)b * O_DIM;
        const float* mr = WTm + (size_t)o * O_DIM;
        const float* ar = WTa + (size_t)o * O_DIM;
        for (int k = lane; k < O_DIM; k += 64) {
            const double l = (double)(h2f(lhr[k]) + h2f(llr[k]));
            zm = fma(l + (double)ur[k], (double)mr[k], zm);
            za = fma(l + (double)tr[k], (double)ar[k], za);
        }
#pragma unroll
        for (int off = 32; off > 0; off >>= 1) {
            l1 += __shfl_down(l1, off);
            zm += __shfl_down(zm, off);
            za += __shfl_down(za, off);
        }
        if (lane == 0) {
            l1 += (double)bsyn[o];
            zm += (double)bTm[o];
            za += (double)bTa[o];
            const double inv_alpha = 1.0 + exp(-zm);
            const double rho = 1.0 / (1.0 + exp(-za));
            const double bt = (double)b_t[idx];
            const double sp = (double)spk[idx];
            const double ut = (double)u_t[idx];
            const double b_new = sp + rho * (bt - sp);
            const double thr = 0.01 + 1.8 * b_new;
            const double u_new = ut + (l1 - ut) * inv_alpha;
            out[idx] = (u_new - thr > 0.0) ? 1.0f : 0.0f;
        }
    }
}

// ===========================================================================
extern "C" void kernel_launch(void* const* d_in, const int* in_sizes, int n_in,
                              void* d_out, int out_size, void* d_ws, size_t ws_size,
                              hipStream_t stream) {
    const float* x    = (const float*)d_in[0];
    const float* u_t  = (const float*)d_in[1];
    const float* b_t  = (const float*)d_in[2];
    const float* spk  = (const float*)d_in[3];
    const float* Wsyn = (const float*)d_in[4];
    const float* bsyn = (const float*)d_in[5];
    const float* WTm  = (const float*)d_in[6];
    const float* bTm  = (const float*)d_in[7];
    const float* WTa  = (const float*)d_in[8];
    const float* bTa  = (const float*)d_in[9];
    float* out = (float*)d_out;

    char* ws = (char*)d_ws;
    ushort* Lhp = (ushort*)(ws + 0 * MBYTE);
    ushort* Llp = (ushort*)(ws + 16 * MBYTE);
    ushort* Mhp = (ushort*)(ws + 32 * MBYTE);
    ushort* Wsh = (ushort*)(ws + 40 * MBYTE);
    ushort* Wsl = (ushort*)(ws + 48 * MBYTE);

    const bool tierA = ws_size >= 91 * MBYTE;
    const size_t flag_off = tierA ? 88 * MBYTE : 56 * MBYTE;
    if (ws_size < flag_off + (1u << 16)) return;

    ushort* Xh = (ushort*)(ws + 56 * MBYTE);
    ushort* Xl = (ushort*)(ws + 72 * MBYTE);
    uint* flag = (uint*)(ws + flag_off);
    uint* cnt  = (uint*)(ws + flag_off + 4);
    uint* list = (uint*)(ws + flag_off + 256);
    const uint cap = (uint)((ws_size - flag_off - 256) / sizeof(uint));

    (void)hipMemsetAsync(ws + flag_off, 0, 8, stream);
    prep<<<dim3(2048), dim3(256), 0, stream>>>(x, Wsyn, WTm, u_t, b_t, spk,
                                               Xh, Xl, Wsh, Wsl, Mhp, flag,
                                               tierA ? 1 : 0);
    if (tierA) {
        gemm1_d<<<dim3(256), dim3(1024), 0, stream>>>(Xh, Xl, Wsh, Wsl, bsyn, Lhp, Llp);
    } else {
        gemm1_b<<<dim3(256), dim3(256), 0, stream>>>(x, Wsh, Wsl, bsyn, Lhp, Llp);
    }
    stage2_fast<<<dim3(256), dim3(1024), 0, stream>>>(Lhp, Llp, Mhp, bTm,
                                                      out, flag, cnt, list, cap);
    stage2_slow<<<dim3(512), dim3(512), 0, stream>>>(Lhp, Llp, u_t, b_t, spk,
                                                     WTm, bTm, WTa, bTa,
                                                     out, flag, cnt, list, cap);
    lsnn_fixup<<<dim3(256), dim3(256), 0, stream>>>(Lhp, Llp, x, Wsyn, bsyn,
                                                    u_t, b_t, spk,
                                                    WTm, bTm, WTa, bTa,
                                                    cnt, list, cap, out);
}